// Round 10
// baseline (645.368 us; speedup 1.0000x reference)
//
#include <hip/hip_runtime.h>
#include <hip/hip_bf16.h>
#include <math.h>

#define B_ 8
#define N_ 2000
#define C_ 32
#define T_ 12
#define K_ 3
#define FC_ 64
#define FT_ 64
#define PW 2048   // padded width (K and row pads, zero-filled)

typedef short bf16x8 __attribute__((ext_vector_type(8)));
typedef float f32x4 __attribute__((ext_vector_type(4)));

__device__ __forceinline__ float sigmoidf(float v) { return 1.0f / (1.0f + __expf(-v)); }
__device__ __forceinline__ float bf2f(unsigned short u) {
    union { unsigned int i; float f; } v; v.i = ((unsigned int)u) << 16; return v.f;
}
__device__ __forceinline__ unsigned short f2bf(float f) {
    union { __hip_bfloat16 h; unsigned short u; } v; v.h = __float2bfloat16(f); return v.u;
}
typedef const __attribute__((address_space(1))) void* gas_t;
typedef __attribute__((address_space(3))) void* las_t;
__device__ __forceinline__ void gload16(const unsigned short* g, unsigned short* l) {
    __builtin_amdgcn_global_load_lds((gas_t)g, (las_t)l, 16, 0, 0);
}

// ---------------- fused x-pass: lhs1 partials + rhsT ----------------
__global__ __launch_bounds__(256) void k_tprep(const float* __restrict__ x, const float* __restrict__ U1,
                                               const float* __restrict__ U3,
                                               float* __restrict__ rhsT, float* __restrict__ plh) {
    int b = blockIdx.y, chunk = blockIdx.x;
    int tid = threadIdx.x;
    int nl = tid >> 5, c = tid & 31;
    int w = tid >> 6;
    float u3 = U3[c];
    float plA[12];
#pragma unroll
    for (int t = 0; t < 12; ++t) plA[t] = 0.f;
    for (int it = 0; it < 5; ++it) {
        int n = chunk * 40 + it * 8 + nl;
        const float* xp = x + ((size_t)(b * 2000 + n) * 32 + c) * 12;
        float4 v0 = *(const float4*)xp, v1 = *(const float4*)(xp + 4), v2 = *(const float4*)(xp + 8);
        float xv[12] = {v0.x, v0.y, v0.z, v0.w, v1.x, v1.y, v1.z, v1.w, v2.x, v2.y, v2.z, v2.w};
        float rv[12];
#pragma unroll
        for (int t = 0; t < 12; ++t) rv[t] = u3 * xv[t];
#pragma unroll
        for (int off = 16; off >= 1; off >>= 1)
#pragma unroll
            for (int t = 0; t < 12; ++t) rv[t] += __shfl_xor(rv[t], off);
        if (c == 0) {
#pragma unroll
            for (int t = 0; t < 12; ++t) rhsT[(size_t)(b * 2000 + n) * 12 + t] = rv[t];
        }
        float u1 = U1[n];
#pragma unroll
        for (int t = 0; t < 12; ++t) plA[t] += u1 * xv[t];
    }
#pragma unroll
    for (int t = 0; t < 12; ++t) plA[t] += __shfl_xor(plA[t], 32);
    __shared__ float accs[4][32][12];
    if ((tid & 63) < 32) {
#pragma unroll
        for (int t = 0; t < 12; ++t) accs[w][c][t] = plA[t];
    }
    __syncthreads();
    if (tid < 384) {
        int c2 = tid / 12, t2 = tid % 12;
        float s = accs[0][c2][t2] + accs[1][c2][t2] + accs[2][c2][t2] + accs[3][c2][t2];
        plh[((size_t)(b * 50 + chunk)) * 384 + tid] = s;
    }
}

__global__ __launch_bounds__(256) void k_tred(const float* __restrict__ plh, float* __restrict__ lhs1) {
    int b = blockIdx.x;
    for (int q = threadIdx.x; q < 384; q += 256) {
        const float* p = plh + (size_t)b * 50 * 384 + q;
        float s = 0.f;
        for (int ch = 0; ch < 50; ++ch) s += p[(size_t)ch * 384];
        int c = q / 12, t = q % 12;
        lhs1[(b * 12 + t) * 32 + c] = s;
    }
}

__global__ __launch_bounds__(256) void k_lhsT(const float* __restrict__ lhs1, const float* __restrict__ U2,
                                              float* __restrict__ lhsT) {
    int gid = blockIdx.x * 256 + threadIdx.x;
    if (gid >= B_ * T_ * N_) return;
    int n = gid % N_;
    int bt = gid / N_;
    const float* l1 = lhs1 + bt * C_;
    float a = 0.f;
#pragma unroll
    for (int c = 0; c < C_; ++c) a += l1[c] * U2[c * N_ + n];
    lhsT[gid] = a;
}

__global__ __launch_bounds__(256) void k_tatt1(const float* __restrict__ lhsT, const float* __restrict__ rhsT,
                                               float* __restrict__ pP) {
    int b = blockIdx.y, ch = blockIdx.x;
    int tid = threadIdx.x;
    int n0 = ch * 125;
    __shared__ float sL[12][128];
    __shared__ float sR[128][12];
    for (int q = tid; q < 12 * 125; q += 256) {
        int t = q / 125, nn = q % 125;
        sL[t][nn] = lhsT[(size_t)(b * 12 + t) * 2000 + n0 + nn];
    }
    for (int q = tid; q < 125 * 12; q += 256) {
        int nn = q / 12, t = q % 12;
        sR[nn][t] = rhsT[(size_t)(b * 2000 + n0 + nn) * 12 + t];
    }
    __syncthreads();
    if (tid < 144) {
        int tP = tid / 12, uP = tid % 12;
        float a = 0.f;
#pragma unroll 5
        for (int nn = 0; nn < 125; ++nn) a += sL[tP][nn] * sR[nn][uP];
        pP[(size_t)(b * 16 + ch) * 144 + tid] = a;
    }
}

__global__ __launch_bounds__(256) void k_tatt2(const float* __restrict__ pP, const float* __restrict__ be,
                                               const float* __restrict__ Ve, float* __restrict__ At) {
    int b = blockIdx.x, tid = threadIdx.x;
    __shared__ float sp[144], sE[144], mk[12], sk[12];
    int tP = tid / 12, uP = tid % 12;
    if (tid < 144) {
        float a = 0.f;
#pragma unroll
        for (int ch = 0; ch < 16; ++ch) a += pP[(size_t)(b * 16 + ch) * 144 + tid];
        sp[tid] = sigmoidf(a + be[tid]);
    }
    __syncthreads();
    if (tid < 144) {
        float e = 0.f;
#pragma unroll
        for (int j = 0; j < 12; ++j) e += Ve[tP * 12 + j] * sp[j * 12 + uP];
        sE[tid] = e;
    }
    __syncthreads();
    if (tid < 12) {
        float m = -1e30f;
#pragma unroll
        for (int i = 0; i < 12; ++i) m = fmaxf(m, sE[i * 12 + tid]);
        float s = 0.f;
#pragma unroll
        for (int i = 0; i < 12; ++i) s += __expf(sE[i * 12 + tid] - m);
        mk[tid] = m; sk[tid] = 1.0f / s;
    }
    __syncthreads();
    if (tid < 144) At[b * 144 + tid] = __expf(sE[tid] - mk[uP]) * sk[uP];
}

__global__ __launch_bounds__(256) void k_xsp(const float* __restrict__ x, const float* __restrict__ At,
                                             const float* __restrict__ W1, const float* __restrict__ W2,
                                             const float* __restrict__ W3,
                                             float* __restrict__ lhs_s, float* __restrict__ rhs_s) {
    int b = blockIdx.y, chunk = blockIdx.x;
    int tid = threadIdx.x, nl = tid >> 5, c = tid & 31;
    int n = chunk * 8 + nl;
    __shared__ float atl[144];
    __shared__ float w2l[384];
    __shared__ float w1l[12];
    if (tid < 144) atl[tid] = At[b * 144 + tid];
    if (tid >= 144 && tid < 156) w1l[tid - 144] = W1[tid - 144];
    for (int q = tid; q < 384; q += 256) w2l[q] = W2[q];
    __syncthreads();
    const float* xp = x + ((size_t)(b * 2000 + n) * 32 + c) * 12;
    float4 v0 = *(const float4*)xp, v1 = *(const float4*)(xp + 4), v2 = *(const float4*)(xp + 8);
    float xv[12] = {v0.x, v0.y, v0.z, v0.w, v1.x, v1.y, v1.z, v1.w, v2.x, v2.y, v2.z, v2.w};
    float xa[12];
#pragma unroll
    for (int t = 0; t < 12; ++t) {
        float s = 0.f;
#pragma unroll
        for (int u = 0; u < 12; ++u) s += xv[u] * atl[u * 12 + t];
        xa[t] = s;
    }
    float w3 = W3[c];
    float rv[12], lv[12];
    float l1 = 0.f;
#pragma unroll
    for (int t = 0; t < 12; ++t) l1 += xa[t] * w1l[t];
#pragma unroll
    for (int t = 0; t < 12; ++t) { rv[t] = w3 * xa[t]; lv[t] = l1 * w2l[c * 12 + t]; }
#pragma unroll
    for (int off = 16; off >= 1; off >>= 1)
#pragma unroll
        for (int t = 0; t < 12; ++t) { rv[t] += __shfl_xor(rv[t], off); lv[t] += __shfl_xor(lv[t], off); }
    if (c == 0) {
#pragma unroll
        for (int t = 0; t < 12; ++t) rhs_s[(size_t)(b * 12 + t) * 2000 + n] = rv[t];
#pragma unroll
        for (int t = 0; t < 12; ++t) lhs_s[(size_t)(b * 2000 + n) * 12 + t] = lv[t];
    }
}

// ---------------- weight transposes ----------------
__global__ __launch_bounds__(256) void k_wprep(const float* __restrict__ tc_w, const float* __restrict__ rc_w,
                                               float* __restrict__ tcwT, float* __restrict__ rcwT) {
    int gid = blockIdx.x * 256 + threadIdx.x;
    if (gid < 12288) {
        int fi = gid / 192, rem = gid % 192, f = rem / 3, d = rem % 3;
        tcwT[gid] = tc_w[(f * 64 + fi) * 3 + d];
    } else if (gid < 14336) {
        int q = gid - 12288;
        int c = q >> 6, f = q & 63;
        rcwT[q] = rc_w[f * 32 + c];
    }
}

// ---------------- conversions / transposes (padded to PW, zero-filled) ----------------
__global__ __launch_bounds__(256) void k_vsb(const float* __restrict__ Vs, unsigned short* __restrict__ Vsb) {
    int gid = blockIdx.x * 256 + threadIdx.x;
    int row = gid >> 8, chunk = gid & 255;
    int p0 = chunk * 8;
    unsigned short o[8];
#pragma unroll
    for (int e = 0; e < 8; ++e) {
        int p = p0 + e;
        o[e] = (row < N_ && p < N_) ? f2bf(Vs[row * N_ + p]) : (unsigned short)0;
    }
    *(int4*)(Vsb + (size_t)row * PW + p0) = *(int4*)o;
}

__global__ __launch_bounds__(256) void k_chebT(const float* __restrict__ cheb, unsigned short* __restrict__ chebT) {
    int j0 = blockIdx.x * 64, i0 = blockIdx.y * 64, kk = blockIdx.z;
    __shared__ float Tl[64][65];
    int t = threadIdx.x;
    int rr = t >> 2, c0 = (t & 3) * 16;
    int j = j0 + rr;
#pragma unroll
    for (int e = 0; e < 16; ++e) {
        int i = i0 + c0 + e;
        Tl[rr][c0 + e] = (j < N_ && i < N_) ? cheb[(size_t)kk * 4000000 + (size_t)j * N_ + i] : 0.f;
    }
    __syncthreads();
    int l = t & 63, w = t >> 6;
    unsigned short o[16];
#pragma unroll
    for (int e = 0; e < 16; ++e) o[e] = f2bf(Tl[w * 16 + e][l]);
    unsigned short* dst = chebT + (size_t)kk * PW * PW + (size_t)(i0 + l) * PW + j0 + w * 16;
    *(int4*)dst = *(int4*)o;
    *(int4*)(dst + 8) = *(int4*)(o + 8);
}

__global__ __launch_bounds__(256) void k_xT(const float* __restrict__ x, unsigned short* __restrict__ xT) {
    int j0 = blockIdx.x * 64, r0 = blockIdx.y * 64, b = blockIdx.z;
    __shared__ float Tl[64][65];
    int t = threadIdx.x;
    int rr = t >> 2, c0 = (t & 3) * 16;
    int j = j0 + rr;
#pragma unroll
    for (int e = 0; e < 16; ++e) {
        int r = r0 + c0 + e;
        Tl[rr][c0 + e] = (j < N_) ? x[(size_t)(b * N_ + j) * 384 + r] : 0.f;
    }
    __syncthreads();
    int l = t & 63, w = t >> 6;
    unsigned short o[16];
#pragma unroll
    for (int e = 0; e < 16; ++e) o[e] = f2bf(Tl[w * 16 + e][l]);
    unsigned short* dst = xT + (size_t)b * 384 * PW + (size_t)(r0 + l) * PW + j0 + w * 16;
    *(int4*)dst = *(int4*)o;
    *(int4*)(dst + 8) = *(int4*)(o + 8);
}

__global__ __launch_bounds__(256) void k_sig(const float* __restrict__ lhs_s, const float* __restrict__ rhs_s,
                                             const float* __restrict__ bs, unsigned short* __restrict__ sigT) {
    int p0 = blockIdx.x * 64, i0 = blockIdx.y * 64, b = blockIdx.z;
    __shared__ float sL[64][12];
    __shared__ float sR[12][64];
    __shared__ float bsl[64][65];
    int t = threadIdx.x;
    for (int q = t; q < 768; q += 256) {
        int pp = q / 12, tt = q % 12;
        int p = p0 + pp;
        sL[pp][tt] = (p < N_) ? lhs_s[(b * N_ + p) * 12 + tt] : 0.f;
    }
    for (int q = t; q < 768; q += 256) {
        int tt = q >> 6, ii = q & 63;
        int i = i0 + ii;
        sR[tt][ii] = (i < N_) ? rhs_s[b * (T_ * N_) + tt * N_ + i] : 0.f;
    }
    {
        int pp = t >> 2, c0 = (t & 3) * 16;
        int p = p0 + pp;
        if (p < N_ && i0 + c0 + 15 < N_) {
            const float* src = bs + (size_t)p * N_ + i0 + c0;
#pragma unroll
            for (int e = 0; e < 16; e += 4) *(float4*)&bsl[pp][c0 + e] = *(const float4*)(src + e);
        } else {
#pragma unroll
            for (int e = 0; e < 16; ++e) {
                int i = i0 + c0 + e;
                bsl[pp][c0 + e] = (p < N_ && i < N_) ? bs[(size_t)p * N_ + i] : 0.f;
            }
        }
    }
    __syncthreads();
    int ii = t & 63, w = t >> 6;
    int i = i0 + ii;
    unsigned short o[16];
#pragma unroll
    for (int e = 0; e < 16; ++e) {
        int pl = w * 16 + e;
        int p = p0 + pl;
        float v = 0.f;
        if (p < N_ && i < N_) {
            float d = bsl[pl][ii];
#pragma unroll
            for (int tt = 0; tt < 12; ++tt) d += sL[pl][tt] * sR[tt][ii];
            v = sigmoidf(d);
        }
        o[e] = f2bf(v);
    }
    unsigned short* dst = sigT + (size_t)b * PW * PW + (size_t)i * PW + p0 + w * 16;
    *(int4*)dst = *(int4*)o;
    *(int4*)(dst + 8) = *(int4*)(o + 8);
}

// ---------------- MFMA GEMM 256x256 tile, BK=32, 4-slot depth-3 pipeline ----------------
// ST[i][j] = sum_p sigT[i][p] * Vsb[j][p]
__global__ __launch_bounds__(512) void k_gemm_S_mfma(const unsigned short* __restrict__ Vsb,
                                                     const unsigned short* __restrict__ sigT,
                                                     unsigned short* __restrict__ ST) {
    // bijective XCD swizzle: XCD k (= lid%8) works on batch b=k
    int lid = blockIdx.x + (blockIdx.y << 3) + (blockIdx.z << 6);
    int swz = (lid & 7) * 64 + (lid >> 3);
    int j0 = (swz & 7) * 256;
    int i0 = ((swz >> 3) & 7) * 256;
    int b = swz >> 6;
    const unsigned short* Ap = sigT + (size_t)b * PW * PW;
    __shared__ unsigned short As[4][8192];   // 4 slots x [256 rows][32 cols]
    __shared__ unsigned short Bs[4][8192];
    int t = threadIdx.x, lane = t & 63, w = t >> 6;
    int wr = w >> 2, wc = w & 3;             // wave tile: rows wr*128, cols wc*64
    f32x4 acc[8][4];
#pragma unroll
    for (int m = 0; m < 8; ++m)
#pragma unroll
        for (int n = 0; n < 4; ++n)
#pragma unroll
            for (int q = 0; q < 4; ++q) acc[m][n][q] = 0.f;
    // staging: thread t covers row (t>>2)+{0,128}, phys seg (t&3); global seg pre-swizzled
    int srow = t >> 2;
    int sseg = (t & 3) ^ (srow & 3);
    const unsigned short* gA = Ap + (size_t)(i0 + srow) * PW + sseg * 8;
    const unsigned short* gB = Vsb + (size_t)(j0 + srow) * PW + sseg * 8;
    int ldw = w * 512;   // wave-uniform LDS element base (HW adds lane*16B)
#define STG(slot, kt) do { \
    gload16(gA + (size_t)(kt) * 32, &As[slot][ldw]); \
    gload16(gA + (size_t)128 * PW + (size_t)(kt) * 32, &As[slot][4096 + ldw]); \
    gload16(gB + (size_t)(kt) * 32, &Bs[slot][ldw]); \
    gload16(gB + (size_t)128 * PW + (size_t)(kt) * 32, &Bs[slot][4096 + ldw]); \
} while (0)
    STG(0, 0); STG(1, 1); STG(2, 2);
    int l15 = lane & 15;
    int swr = ((lane >> 4) ^ (lane & 3)) * 8;    // read-side seg swizzle (row&3 == lane&3 for frags)
    int abase = (wr * 128 + l15) * 32 + swr;
    int bbase = (wc * 64 + l15) * 32 + swr;
    for (int kt = 0; kt < 64; ++kt) {
        if (kt < 62)       asm volatile("s_waitcnt vmcnt(8)" ::: "memory");
        else if (kt == 62) asm volatile("s_waitcnt vmcnt(4)" ::: "memory");
        else               asm volatile("s_waitcnt vmcnt(0)" ::: "memory");
        __builtin_amdgcn_s_barrier();          // collective: tile kt landed; slot (kt+3)&3 free
        __builtin_amdgcn_sched_barrier(0);     // pin ds_reads below the barrier
        if (kt + 3 < 64) STG((kt + 3) & 3, kt + 3);
        int slot = kt & 3;
        bf16x8 af[8], bfv[4];
#pragma unroll
        for (int m = 0; m < 8; ++m) af[m] = *(const bf16x8*)&As[slot][abase + m * 512];
#pragma unroll
        for (int n = 0; n < 4; ++n) bfv[n] = *(const bf16x8*)&Bs[slot][bbase + n * 512];
        __builtin_amdgcn_s_setprio(1);
#pragma unroll
        for (int m = 0; m < 8; ++m)
#pragma unroll
            for (int n = 0; n < 4; ++n)
                acc[m][n] = __builtin_amdgcn_mfma_f32_16x16x32_bf16(af[m], bfv[n], acc[m][n], 0, 0, 0);
        __builtin_amdgcn_s_setprio(0);
    }
#undef STG
    unsigned short* Sp = ST + (size_t)b * PW * PW;
#pragma unroll
    for (int m = 0; m < 8; ++m) {
        int row0 = i0 + wr * 128 + m * 16 + ((lane >> 4) << 2);
#pragma unroll
        for (int n = 0; n < 4; ++n) {
            int col = j0 + wc * 64 + n * 16 + (lane & 15);
#pragma unroll
            for (int q = 0; q < 4; ++q)
                Sp[(size_t)(row0 + q) * PW + col] = f2bf(acc[m][n][q]);
        }
    }
}

// ---- row softmax stats over ST rows ----
__global__ __launch_bounds__(256) void k_smrow(const unsigned short* __restrict__ ST,
                                               float* __restrict__ gm, float* __restrict__ gs) {
    int wid = threadIdx.x >> 6, lane = threadIdx.x & 63;
    int b = blockIdx.y;
    int i = blockIdx.x * 4 + wid;
    const unsigned short* rp = ST + (size_t)b * PW * PW + (size_t)i * PW;
    float vals[32];
    float m = -1e30f;
#pragma unroll
    for (int k = 0; k < 4; ++k) {
        int j0 = lane * 8 + k * 512;
        if (j0 < N_) {
            union { int4 v; unsigned short s[8]; } u;
            u.v = *(const int4*)(rp + j0);
#pragma unroll
            for (int e = 0; e < 8; ++e) {
                vals[k * 8 + e] = bf2f(u.s[e]);
                m = fmaxf(m, vals[k * 8 + e]);
            }
        } else {
#pragma unroll
            for (int e = 0; e < 8; ++e) vals[k * 8 + e] = -1e30f;
        }
    }
#pragma unroll
    for (int off = 32; off >= 1; off >>= 1) m = fmaxf(m, __shfl_xor(m, off));
    float s = 0.f;
#pragma unroll
    for (int k = 0; k < 32; ++k) s += __expf(vals[k] - m);
#pragma unroll
    for (int off = 32; off >= 1; off >>= 1) s += __shfl_xor(s, off);
    if (lane == 0) {
        gm[b * 2048 + i] = m;
        gs[b * 2048 + i] = 1.0f / s;
    }
}

// ---------------- MFMA GEMM (fused softmax-normalize in A-staging) ----------------
__global__ __launch_bounds__(512) void k_gemm_cheb_mfma(const unsigned short* __restrict__ chebT,
                                                        const unsigned short* __restrict__ ST,
                                                        const float* __restrict__ gm, const float* __restrict__ gs,
                                                        const unsigned short* __restrict__ xT,
                                                        unsigned short* __restrict__ h2) {
    int bk = blockIdx.y;
    int b = bk / 3, kk = bk % 3;
    int i0 = blockIdx.x * 128;
    const unsigned short* Ac = chebT + (size_t)kk * PW * PW;
    const unsigned short* Sa = ST + (size_t)b * PW * PW;
    const unsigned short* Bx = xT + (size_t)b * 384 * PW;
    __shared__ unsigned short As[2][4096];
    __shared__ unsigned short Bs[2][12288];
    int t = threadIdx.x, lane = t & 63, w = t >> 6;
    int wr = w >> 2, wc = w & 3;
    f32x4 acc[4][6];
#pragma unroll
    for (int a = 0; a < 4; ++a)
#pragma unroll
        for (int c = 0; c < 6; ++c)
#pragma unroll
            for (int q = 0; q < 4; ++q) acc[a][c][q] = 0.f;
    int arow = t >> 2, aq = t & 3;
    const unsigned short* gc = Ac + (size_t)(i0 + arow) * PW + aq * 8;
    const unsigned short* gsat = Sa + (size_t)(i0 + arow) * PW + aq * 8;
    float gmv = gm[b * 2048 + i0 + arow];
    float gsv = gs[b * 2048 + i0 + arow];
    int aoff = arow * 32 + (aq ^ (arow & 3)) * 8;
    int bseg = (t & 3) ^ ((t >> 2) & 3);
    const unsigned short* gB = Bx + (size_t)(t >> 2) * PW + bseg * 8;
    int ldso = w * 512;
#define STAGE_B(buf, p) do { \
    gload16(gB + (p), &Bs[buf][ldso]); \
    gload16(gB + 128 * PW + (p), &Bs[buf][4096 + ldso]); \
    gload16(gB + 256 * PW + (p), &Bs[buf][8192 + ldso]); \
} while (0)
    union U8 { int4 v; unsigned short s[8]; };
    U8 ca, sa;
    ca.v = *(const int4*)gc;
    sa.v = *(const int4*)gsat;
    STAGE_B(0, 0);
    {
        U8 o;
#pragma unroll
        for (int e = 0; e < 8; ++e) o.s[e] = f2bf(bf2f(ca.s[e]) * __expf(bf2f(sa.s[e]) - gmv) * gsv);
        *(int4*)&As[0][aoff] = o.v;
    }
    ca.v = *(const int4*)(gc + 32);
    sa.v = *(const int4*)(gsat + 32);
    __syncthreads();
    int cur = 0;
    int rswz = ((lane >> 4) ^ (lane & 3)) * 8;
    for (int p = 0; p < PW; p += 32) {
        if (p + 32 < PW) {
            STAGE_B(cur ^ 1, p + 32);
            U8 o;
#pragma unroll
            for (int e = 0; e < 8; ++e) o.s[e] = f2bf(bf2f(ca.s[e]) * __expf(bf2f(sa.s[e]) - gmv) * gsv);
            *(int4*)&As[cur ^ 1][aoff] = o.v;
            int pn = (p + 64 < PW) ? p + 64 : 0;
            ca.v = *(const int4*)(gc + pn);
            sa.v = *(const int4*)(gsat + pn);
        }
        bf16x8 af[4], bfr[6];
#pragma unroll
        for (int fm = 0; fm < 4; ++fm)
            af[fm] = *(const bf16x8*)&As[cur][(wr * 64 + fm * 16 + (lane & 15)) * 32 + rswz];
#pragma unroll
        for (int fn = 0; fn < 6; ++fn)
            bfr[fn] = *(const bf16x8*)&Bs[cur][(wc * 96 + fn * 16 + (lane & 15)) * 32 + rswz];
#pragma unroll
        for (int fm = 0; fm < 4; ++fm)
#pragma unroll
            for (int fn = 0; fn < 6; ++fn)
                acc[fm][fn] = __builtin_amdgcn_mfma_f32_16x16x32_bf16(af[fm], bfr[fn], acc[fm][fn], 0, 0, 0);
        __syncthreads();
        cur ^= 1;
    }
#undef STAGE_B
    unsigned short* hp = h2 + (size_t)bk * 768000;
#pragma unroll
    for (int fm = 0; fm < 4; ++fm) {
        int row0 = i0 + wr * 64 + fm * 16 + ((lane >> 4) << 2);
#pragma unroll
        for (int fn = 0; fn < 6; ++fn) {
            int col = wc * 96 + fn * 16 + (lane & 15);
#pragma unroll
            for (int q = 0; q < 4; ++q) {
                int row = row0 + q;
                if (row < N_) hp[(size_t)row * 384 + col] = f2bf(acc[fm][fn][q]);
            }
        }
    }
}

// ---------------- fused tail: theta mix + time conv + residual + relu + LayerNorm ----------------
__global__ __launch_bounds__(512) void k_final3(const float* __restrict__ x, const unsigned short* __restrict__ h2,
                                                const float* __restrict__ ThetaG,
                                                const float* __restrict__ tcwT, const float* __restrict__ tc_b,
                                                const float* __restrict__ rcwT, const float* __restrict__ rc_b,
                                                const float* __restrict__ ln_g, const float* __restrict__ ln_b,
                                                float* __restrict__ out) {
    __shared__ __align__(16) char smem[110848];
    unsigned int* gl = (unsigned int*)smem;
    unsigned short* th = (unsigned short*)(smem + 98560);
    float* red_s = (float*)(smem + 98560);
    float* red_q = red_s + 64 * 13;

    int tid = threadIdx.x;
    int n_l = tid & 63, fg = tid >> 6;
    int b = blockIdx.y;
    int node = blockIdx.x * 64 + n_l;
    bool ok = node < N_;
    int nd = ok ? node : N_ - 1;

    for (int q = tid; q < 6144; q += 512) th[q] = f2bf(ThetaG[q]);
    __syncthreads();

    float acc[8][12];
#pragma unroll
    for (int ff = 0; ff < 8; ++ff)
#pragma unroll
        for (int t = 0; t < 12; ++t) acc[ff][t] = 0.f;
    const unsigned short* hb = h2 + (size_t)b * 3 * 768000 + (size_t)nd * 384;
#pragma unroll
    for (int kk = 0; kk < 3; ++kk) {
        const unsigned short* hp = hb + (size_t)kk * 768000;
#pragma unroll 2
        for (int c = 0; c < 32; ++c) {
            const unsigned short* hq = hp + c * 12;
            uint2 u0 = *(const uint2*)(hq);
            uint2 u1 = *(const uint2*)(hq + 4);
            uint2 u2 = *(const uint2*)(hq + 8);
            float h[12];
            h[0] = bf2f((unsigned short)u0.x);  h[1] = bf2f((unsigned short)(u0.x >> 16));
            h[2] = bf2f((unsigned short)u0.y);  h[3] = bf2f((unsigned short)(u0.y >> 16));
            h[4] = bf2f((unsigned short)u1.x);  h[5] = bf2f((unsigned short)(u1.x >> 16));
            h[6] = bf2f((unsigned short)u1.y);  h[7] = bf2f((unsigned short)(u1.y >> 16));
            h[8] = bf2f((unsigned short)u2.x);  h[9] = bf2f((unsigned short)(u2.x >> 16));
            h[10] = bf2f((unsigned short)u2.y); h[11] = bf2f((unsigned short)(u2.y >> 16));
            const unsigned short* wv = th + (kk * 32 + c) * 64 + fg * 8;
            uint2 w01 = *(const uint2*)wv;
            uint2 w23 = *(const uint2*)(wv + 4);
            float wf[8];
            wf[0] = bf2f((unsigned short)w01.x); wf[1] = bf2f((unsigned short)(w01.x >> 16));
            wf[2] = bf2f((unsigned short)w01.y); wf[3] = bf2f((unsigned short)(w01.y >> 16));
            wf[4] = bf2f((unsigned short)w23.x); wf[5] = bf2f((unsigned short)(w23.x >> 16));
            wf[6] = bf2f((unsigned short)w23.y); wf[7] = bf2f((unsigned short)(w23.y >> 16));
#pragma unroll
            for (int ff = 0; ff < 8; ++ff)
#pragma unroll
                for (int t = 0; t < 12; ++t) acc[ff][t] = fmaf(h[t], wf[ff], acc[ff][t]);
        }
    }
    unsigned int* gr = gl + n_l * 385 + fg * 48;
#pragma unroll
    for (int ff = 0; ff < 8; ++ff)
#pragma unroll
        for (int tp = 0; tp < 6; ++tp) {
            float a0 = fmaxf(acc[ff][2 * tp], 0.f), a1 = fmaxf(acc[ff][2 * tp + 1], 0.f);
            gr[ff * 6 + tp] = (unsigned int)f2bf(a0) | ((unsigned int)f2bf(a1) << 16);
        }
    __syncthreads();

    float z[8][12];
#pragma unroll
    for (int ff = 0; ff < 8; ++ff) {
        float bias = tc_b[fg * 8 + ff] + rc_b[fg * 8 + ff];
#pragma unroll
        for (int t = 0; t < 12; ++t) z[ff][t] = bias;
    }
    const float* xp = x + (size_t)(b * 2000 + nd) * 384;
#pragma unroll 2
    for (int c = 0; c < 32; ++c) {
        float4 x0 = *(const float4*)(xp + c * 12);
        float4 x1 = *(const float4*)(xp + c * 12 + 4);
        float4 x2 = *(const float4*)(xp + c * 12 + 8);
        float xv[12] = {x0.x, x0.y, x0.z, x0.w, x1.x, x1.y, x1.z, x1.w, x2.x, x2.y, x2.z, x2.w};
        float4 r0 = *(const float4*)(rcwT + c * 64 + fg * 8);
        float4 r1 = *(const float4*)(rcwT + c * 64 + fg * 8 + 4);
        float rw[8] = {r0.x, r0.y, r0.z, r0.w, r1.x, r1.y, r1.z, r1.w};
#pragma unroll
        for (int ff = 0; ff < 8; ++ff)
#pragma unroll
            for (int t = 0; t < 12; ++t) z[ff][t] = fmaf(xv[t], rw[ff], z[ff][t]);
    }
    const unsigned int* grow = gl + n_l * 385;
    for (int fi = 0; fi < 64; ++fi) {
        float g[12];
#pragma unroll
        for (int j = 0; j < 6; ++j) {
            unsigned int u = grow[fi * 6 + j];
            g[2 * j] = bf2f((unsigned short)u);
            g[2 * j + 1] = bf2f((unsigned short)(u >> 16));
        }
        const float* wp = tcwT + (fi * 64 + fg * 8) * 3;
        float4 w0 = *(const float4*)(wp);
        float4 w1 = *(const float4*)(wp + 4);
        float4 w2 = *(const float4*)(wp + 8);
        float4 w3 = *(const float4*)(wp + 12);
        float4 w4 = *(const float4*)(wp + 16);
        float4 w5 = *(const float4*)(wp + 20);
        float wb[24] = {w0.x, w0.y, w0.z, w0.w, w1.x, w1.y, w1.z, w1.w,
                        w2.x, w2.y, w2.z, w2.w, w3.x, w3.y, w3.z, w3.w,
                        w4.x, w4.y, w4.z, w4.w, w5.x, w5.y, w5.z, w5.w};
#pragma unroll
        for (int ff = 0; ff < 8; ++ff) {
            float a0 = wb[ff * 3], a1 = wb[ff * 3 + 1], a2 = wb[ff * 3 + 2];
            z[ff][0] = fmaf(g[0], a1, fmaf(g[1], a2, z[ff][0]));
#pragma unroll
            for (int t = 1; t < 11; ++t)
                z[ff][t] = fmaf(g[t - 1], a0, fmaf(g[t], a1, fmaf(g[t + 1], a2, z[ff][t])));
            z[ff][11] = fmaf(g[10], a0, fmaf(g[11], a1, z[ff][11]));
        }
    }
#pragma unroll
    for (int ff = 0; ff < 8; ++ff)
#pragma unroll
        for (int t = 0; t < 12; ++t) z[ff][t] = fmaxf(z[ff][t], 0.f);

    float s[12], q[12];
#pragma unroll
    for (int t = 0; t < 12; ++t) { s[t] = 0.f; q[t] = 0.f; }
#pragma unroll
    for (int ff = 0; ff < 8; ++ff)
#pragma unroll
        for (int t = 0; t < 12; ++t) { s[t] += z[ff][t]; q[t] += z[ff][t] * z[ff][t]; }
    __syncthreads();
    for (int g = 0; g < 8; ++g) {
        if (fg == g) {
            if (g == 0) {
#pragma unroll
                for (int t = 0; t < 12; ++t) { red_s[n_l * 13 + t] = s[t]; red_q[n_l * 13 + t] = q[t]; }
            } else {
#pragma unroll
                for (int t = 0; t < 12; ++t) { red_s[n_l * 13 + t] += s[t]; red_q[n_l * 13 + t] += q[t]; }
            }
        }
        __syncthreads();
    }
    float mu[12], rs[12];
#pragma unroll
    for (int t = 0; t < 12; ++t) {
        float m = red_s[n_l * 13 + t] * (1.0f / 64.0f);
        float v = red_q[n_l * 13 + t] * (1.0f / 64.0f) - m * m;
        mu[t] = m;
        rs[t] = rsqrtf(v + 1e-5f);
    }
    if (ok) {
        float* op = out + ((size_t)(b * 2000 + node) * 64 + fg * 8) * 12;
#pragma unroll
        for (int ff = 0; ff < 8; ++ff) {
            float lg = ln_g[fg * 8 + ff], lb = ln_b[fg * 8 + ff];
            float o[12];
#pragma unroll
            for (int t = 0; t < 12; ++t) o[t] = (z[ff][t] - mu[t]) * rs[t] * lg + lb;
#pragma unroll
            for (int tq = 0; tq < 3; ++tq)
                *(float4*)(op + ff * 12 + tq * 4) = make_float4(o[tq * 4], o[tq * 4 + 1], o[tq * 4 + 2], o[tq * 4 + 3]);
        }
    }
}

extern "C" void kernel_launch(void* const* d_in, const int* in_sizes, int n_in,
                              void* d_out, int out_size, void* d_ws, size_t ws_size,
                              hipStream_t stream) {
    const float* x     = (const float*)d_in[0];
    const float* cheb  = (const float*)d_in[1];
    const float* U1    = (const float*)d_in[2];
    const float* U2    = (const float*)d_in[3];
    const float* U3    = (const float*)d_in[4];
    const float* be    = (const float*)d_in[5];
    const float* Ve    = (const float*)d_in[6];
    const float* W1    = (const float*)d_in[7];
    const float* W2    = (const float*)d_in[8];
    const float* W3    = (const float*)d_in[9];
    const float* bs    = (const float*)d_in[10];
    const float* Vs    = (const float*)d_in[11];
    const float* Theta = (const float*)d_in[12];
    const float* tc_w  = (const float*)d_in[13];
    const float* tc_b  = (const float*)d_in[14];
    const float* rc_w  = (const float*)d_in[15];
    const float* rc_b  = (const float*)d_in[16];
    const float* ln_g  = (const float*)d_in[17];
    const float* ln_b  = (const float*)d_in[18];
    float* out = (float*)d_out;

    // ---- workspace layout (~184.3 MB) ----
    float* ws    = (float*)d_ws;
    float* At    = ws;                       // 1152      -> 1152
    float* lhs1  = ws + 1152;                // 3072      -> 4224
    float* lhsT  = ws + 4224;                // 192000    -> 196224
    float* rhsT  = ws + 196224;              // 192000    -> 388224
    float* lhs_s = ws + 388224;              // 192000    -> 580224
    float* rhs_s = ws + 580224;              // 192000    -> 772224
    float* gm    = ws + 772224;              // 16384     -> 788608
    float* gs    = ws + 788608;              // 16384     -> 804992
    float* tcwT  = ws + 804992;              // 12288     -> 817280
    float* rcwT  = ws + 817280;              // 2048      -> 819328
    float* plh   = ws + 819328;              // 153600    -> 972928
    float* pP    = ws + 972928;              // 18432     -> 991360
    unsigned short* Vsb   = (unsigned short*)(ws + 991360);    // -> 3,088,512
    unsigned short* chebT = (unsigned short*)(ws + 3088512);   // -> 9,379,968
    unsigned short* xT    = (unsigned short*)(ws + 9379968);   // -> 12,525,696
    unsigned short* sigT  = (unsigned short*)(ws + 12525696);  // -> 29,302,912 (dead after gemm_S)
    unsigned short* h2    = sigT;                              // reuse after gemm_S
    unsigned short* STb   = (unsigned short*)(ws + 29302912);  // -> 46,080,128

    // prep
    k_wprep<<<56, 256, 0, stream>>>(tc_w, rc_w, tcwT, rcwT);
    k_vsb<<<2048, 256, 0, stream>>>(Vs, Vsb);
    k_chebT<<<dim3(32, 32, 3), 256, 0, stream>>>(cheb, chebT);
    k_xT<<<dim3(32, 6, 8), 256, 0, stream>>>(x, xT);
    // temporal attention
    k_tprep<<<dim3(50, 8), 256, 0, stream>>>(x, U1, U3, rhsT, plh);
    k_tred<<<8, 256, 0, stream>>>(plh, lhs1);
    k_lhsT<<<750, 256, 0, stream>>>(lhs1, U2, lhsT);
    k_tatt1<<<dim3(16, 8), 256, 0, stream>>>(lhsT, rhsT, pP);
    k_tatt2<<<8, 256, 0, stream>>>(pP, be, Ve, At);
    k_xsp<<<dim3(250, 8), 256, 0, stream>>>(x, At, W1, W2, W3, lhs_s, rhs_s);
    // spatial attention (S^T directly)
    k_sig<<<dim3(32, 32, 8), 256, 0, stream>>>(lhs_s, rhs_s, bs, sigT);
    k_gemm_S_mfma<<<dim3(8, 8, 8), 512, 0, stream>>>(Vsb, sigT, STb);
    k_smrow<<<dim3(512, 8), 256, 0, stream>>>(STb, gm, gs);
    // chebyshev gcn with fused softmax normalization
    k_gemm_cheb_mfma<<<dim3(16, 24), 512, 0, stream>>>(chebT, STb, gm, gs, xT, h2);
    // fused theta + conv + LN tail
    k_final3<<<dim3(32, 8), 512, 0, stream>>>(x, h2, Theta, tcwT, tc_b, rcwT, rc_b, ln_g, ln_b, out);
}

// Round 11
// 637.424 us; speedup vs baseline: 1.0125x; 1.0125x over previous
//
#include <hip/hip_runtime.h>
#include <hip/hip_bf16.h>
#include <math.h>

#define B_ 8
#define N_ 2000
#define C_ 32
#define T_ 12
#define K_ 3
#define FC_ 64
#define FT_ 64
#define PW 2048   // padded width (K and row pads, zero-filled)

typedef short bf16x8 __attribute__((ext_vector_type(8)));
typedef float f32x4 __attribute__((ext_vector_type(4)));

__device__ __forceinline__ float sigmoidf(float v) { return 1.0f / (1.0f + __expf(-v)); }
__device__ __forceinline__ float bf2f(unsigned short u) {
    union { unsigned int i; float f; } v; v.i = ((unsigned int)u) << 16; return v.f;
}
__device__ __forceinline__ unsigned short f2bf(float f) {
    union { __hip_bfloat16 h; unsigned short u; } v; v.h = __float2bfloat16(f); return v.u;
}
typedef const __attribute__((address_space(1))) void* gas_t;
typedef __attribute__((address_space(3))) void* las_t;
__device__ __forceinline__ void gload16(const unsigned short* g, unsigned short* l) {
    __builtin_amdgcn_global_load_lds((gas_t)g, (las_t)l, 16, 0, 0);
}

// ---------------- fused x-pass: lhs1 partials + rhsT ----------------
__global__ __launch_bounds__(256) void k_tprep(const float* __restrict__ x, const float* __restrict__ U1,
                                               const float* __restrict__ U3,
                                               float* __restrict__ rhsT, float* __restrict__ plh) {
    int b = blockIdx.y, chunk = blockIdx.x;
    int tid = threadIdx.x;
    int nl = tid >> 5, c = tid & 31;
    int w = tid >> 6;
    float u3 = U3[c];
    float plA[12];
#pragma unroll
    for (int t = 0; t < 12; ++t) plA[t] = 0.f;
    for (int it = 0; it < 5; ++it) {
        int n = chunk * 40 + it * 8 + nl;
        const float* xp = x + ((size_t)(b * 2000 + n) * 32 + c) * 12;
        float4 v0 = *(const float4*)xp, v1 = *(const float4*)(xp + 4), v2 = *(const float4*)(xp + 8);
        float xv[12] = {v0.x, v0.y, v0.z, v0.w, v1.x, v1.y, v1.z, v1.w, v2.x, v2.y, v2.z, v2.w};
        float rv[12];
#pragma unroll
        for (int t = 0; t < 12; ++t) rv[t] = u3 * xv[t];
#pragma unroll
        for (int off = 16; off >= 1; off >>= 1)
#pragma unroll
            for (int t = 0; t < 12; ++t) rv[t] += __shfl_xor(rv[t], off);
        if (c == 0) {
#pragma unroll
            for (int t = 0; t < 12; ++t) rhsT[(size_t)(b * 2000 + n) * 12 + t] = rv[t];
        }
        float u1 = U1[n];
#pragma unroll
        for (int t = 0; t < 12; ++t) plA[t] += u1 * xv[t];
    }
#pragma unroll
    for (int t = 0; t < 12; ++t) plA[t] += __shfl_xor(plA[t], 32);
    __shared__ float accs[4][32][12];
    if ((tid & 63) < 32) {
#pragma unroll
        for (int t = 0; t < 12; ++t) accs[w][c][t] = plA[t];
    }
    __syncthreads();
    if (tid < 384) {
        int c2 = tid / 12, t2 = tid % 12;
        float s = accs[0][c2][t2] + accs[1][c2][t2] + accs[2][c2][t2] + accs[3][c2][t2];
        plh[((size_t)(b * 50 + chunk)) * 384 + tid] = s;
    }
}

__global__ __launch_bounds__(256) void k_tred(const float* __restrict__ plh, float* __restrict__ lhs1) {
    int b = blockIdx.x;
    for (int q = threadIdx.x; q < 384; q += 256) {
        const float* p = plh + (size_t)b * 50 * 384 + q;
        float s = 0.f;
        for (int ch = 0; ch < 50; ++ch) s += p[(size_t)ch * 384];
        int c = q / 12, t = q % 12;
        lhs1[(b * 12 + t) * 32 + c] = s;
    }
}

__global__ __launch_bounds__(256) void k_lhsT(const float* __restrict__ lhs1, const float* __restrict__ U2,
                                              float* __restrict__ lhsT) {
    int gid = blockIdx.x * 256 + threadIdx.x;
    if (gid >= B_ * T_ * N_) return;
    int n = gid % N_;
    int bt = gid / N_;
    const float* l1 = lhs1 + bt * C_;
    float a = 0.f;
#pragma unroll
    for (int c = 0; c < C_; ++c) a += l1[c] * U2[c * N_ + n];
    lhsT[gid] = a;
}

__global__ __launch_bounds__(256) void k_tatt1(const float* __restrict__ lhsT, const float* __restrict__ rhsT,
                                               float* __restrict__ pP) {
    int b = blockIdx.y, ch = blockIdx.x;
    int tid = threadIdx.x;
    int n0 = ch * 125;
    __shared__ float sL[12][128];
    __shared__ float sR[128][12];
    for (int q = tid; q < 12 * 125; q += 256) {
        int t = q / 125, nn = q % 125;
        sL[t][nn] = lhsT[(size_t)(b * 12 + t) * 2000 + n0 + nn];
    }
    for (int q = tid; q < 125 * 12; q += 256) {
        int nn = q / 12, t = q % 12;
        sR[nn][t] = rhsT[(size_t)(b * 2000 + n0 + nn) * 12 + t];
    }
    __syncthreads();
    if (tid < 144) {
        int tP = tid / 12, uP = tid % 12;
        float a = 0.f;
#pragma unroll 5
        for (int nn = 0; nn < 125; ++nn) a += sL[tP][nn] * sR[nn][uP];
        pP[(size_t)(b * 16 + ch) * 144 + tid] = a;
    }
}

__global__ __launch_bounds__(256) void k_tatt2(const float* __restrict__ pP, const float* __restrict__ be,
                                               const float* __restrict__ Ve, float* __restrict__ At) {
    int b = blockIdx.x, tid = threadIdx.x;
    __shared__ float sp[144], sE[144], mk[12], sk[12];
    int tP = tid / 12, uP = tid % 12;
    if (tid < 144) {
        float a = 0.f;
#pragma unroll
        for (int ch = 0; ch < 16; ++ch) a += pP[(size_t)(b * 16 + ch) * 144 + tid];
        sp[tid] = sigmoidf(a + be[tid]);
    }
    __syncthreads();
    if (tid < 144) {
        float e = 0.f;
#pragma unroll
        for (int j = 0; j < 12; ++j) e += Ve[tP * 12 + j] * sp[j * 12 + uP];
        sE[tid] = e;
    }
    __syncthreads();
    if (tid < 12) {
        float m = -1e30f;
#pragma unroll
        for (int i = 0; i < 12; ++i) m = fmaxf(m, sE[i * 12 + tid]);
        float s = 0.f;
#pragma unroll
        for (int i = 0; i < 12; ++i) s += __expf(sE[i * 12 + tid] - m);
        mk[tid] = m; sk[tid] = 1.0f / s;
    }
    __syncthreads();
    if (tid < 144) At[b * 144 + tid] = __expf(sE[tid] - mk[uP]) * sk[uP];
}

__global__ __launch_bounds__(256) void k_xsp(const float* __restrict__ x, const float* __restrict__ At,
                                             const float* __restrict__ W1, const float* __restrict__ W2,
                                             const float* __restrict__ W3,
                                             float* __restrict__ lhs_s, float* __restrict__ rhs_s) {
    int b = blockIdx.y, chunk = blockIdx.x;
    int tid = threadIdx.x, nl = tid >> 5, c = tid & 31;
    int n = chunk * 8 + nl;
    __shared__ float atl[144];
    __shared__ float w2l[384];
    __shared__ float w1l[12];
    if (tid < 144) atl[tid] = At[b * 144 + tid];
    if (tid >= 144 && tid < 156) w1l[tid - 144] = W1[tid - 144];
    for (int q = tid; q < 384; q += 256) w2l[q] = W2[q];
    __syncthreads();
    const float* xp = x + ((size_t)(b * 2000 + n) * 32 + c) * 12;
    float4 v0 = *(const float4*)xp, v1 = *(const float4*)(xp + 4), v2 = *(const float4*)(xp + 8);
    float xv[12] = {v0.x, v0.y, v0.z, v0.w, v1.x, v1.y, v1.z, v1.w, v2.x, v2.y, v2.z, v2.w};
    float xa[12];
#pragma unroll
    for (int t = 0; t < 12; ++t) {
        float s = 0.f;
#pragma unroll
        for (int u = 0; u < 12; ++u) s += xv[u] * atl[u * 12 + t];
        xa[t] = s;
    }
    float w3 = W3[c];
    float rv[12], lv[12];
    float l1 = 0.f;
#pragma unroll
    for (int t = 0; t < 12; ++t) l1 += xa[t] * w1l[t];
#pragma unroll
    for (int t = 0; t < 12; ++t) { rv[t] = w3 * xa[t]; lv[t] = l1 * w2l[c * 12 + t]; }
#pragma unroll
    for (int off = 16; off >= 1; off >>= 1)
#pragma unroll
        for (int t = 0; t < 12; ++t) { rv[t] += __shfl_xor(rv[t], off); lv[t] += __shfl_xor(lv[t], off); }
    if (c == 0) {
#pragma unroll
        for (int t = 0; t < 12; ++t) rhs_s[(size_t)(b * 12 + t) * 2000 + n] = rv[t];
#pragma unroll
        for (int t = 0; t < 12; ++t) lhs_s[(size_t)(b * 2000 + n) * 12 + t] = lv[t];
    }
}

// ---------------- weight transposes ----------------
__global__ __launch_bounds__(256) void k_wprep(const float* __restrict__ tc_w, const float* __restrict__ rc_w,
                                               float* __restrict__ tcwT, float* __restrict__ rcwT) {
    int gid = blockIdx.x * 256 + threadIdx.x;
    if (gid < 12288) {
        int fi = gid / 192, rem = gid % 192, f = rem / 3, d = rem % 3;
        tcwT[gid] = tc_w[(f * 64 + fi) * 3 + d];
    } else if (gid < 14336) {
        int q = gid - 12288;
        int c = q >> 6, f = q & 63;
        rcwT[q] = rc_w[f * 32 + c];
    }
}

// ---------------- conversions / transposes (padded to PW, zero-filled) ----------------
__global__ __launch_bounds__(256) void k_vsb(const float* __restrict__ Vs, unsigned short* __restrict__ Vsb) {
    int gid = blockIdx.x * 256 + threadIdx.x;
    int row = gid >> 8, chunk = gid & 255;
    int p0 = chunk * 8;
    unsigned short o[8];
#pragma unroll
    for (int e = 0; e < 8; ++e) {
        int p = p0 + e;
        o[e] = (row < N_ && p < N_) ? f2bf(Vs[row * N_ + p]) : (unsigned short)0;
    }
    *(int4*)(Vsb + (size_t)row * PW + p0) = *(int4*)o;
}

__global__ __launch_bounds__(256) void k_chebT(const float* __restrict__ cheb, unsigned short* __restrict__ chebT) {
    int j0 = blockIdx.x * 64, i0 = blockIdx.y * 64, kk = blockIdx.z;
    __shared__ float Tl[64][65];
    int t = threadIdx.x;
    int rr = t >> 2, c0 = (t & 3) * 16;
    int j = j0 + rr;
#pragma unroll
    for (int e = 0; e < 16; ++e) {
        int i = i0 + c0 + e;
        Tl[rr][c0 + e] = (j < N_ && i < N_) ? cheb[(size_t)kk * 4000000 + (size_t)j * N_ + i] : 0.f;
    }
    __syncthreads();
    int l = t & 63, w = t >> 6;
    unsigned short o[16];
#pragma unroll
    for (int e = 0; e < 16; ++e) o[e] = f2bf(Tl[w * 16 + e][l]);
    unsigned short* dst = chebT + (size_t)kk * PW * PW + (size_t)(i0 + l) * PW + j0 + w * 16;
    *(int4*)dst = *(int4*)o;
    *(int4*)(dst + 8) = *(int4*)(o + 8);
}

__global__ __launch_bounds__(256) void k_xT(const float* __restrict__ x, unsigned short* __restrict__ xT) {
    int j0 = blockIdx.x * 64, r0 = blockIdx.y * 64, b = blockIdx.z;
    __shared__ float Tl[64][65];
    int t = threadIdx.x;
    int rr = t >> 2, c0 = (t & 3) * 16;
    int j = j0 + rr;
#pragma unroll
    for (int e = 0; e < 16; ++e) {
        int r = r0 + c0 + e;
        Tl[rr][c0 + e] = (j < N_) ? x[(size_t)(b * N_ + j) * 384 + r] : 0.f;
    }
    __syncthreads();
    int l = t & 63, w = t >> 6;
    unsigned short o[16];
#pragma unroll
    for (int e = 0; e < 16; ++e) o[e] = f2bf(Tl[w * 16 + e][l]);
    unsigned short* dst = xT + (size_t)b * 384 * PW + (size_t)(r0 + l) * PW + j0 + w * 16;
    *(int4*)dst = *(int4*)o;
    *(int4*)(dst + 8) = *(int4*)(o + 8);
}

__global__ __launch_bounds__(256) void k_sig(const float* __restrict__ lhs_s, const float* __restrict__ rhs_s,
                                             const float* __restrict__ bs, unsigned short* __restrict__ sigT) {
    int p0 = blockIdx.x * 64, i0 = blockIdx.y * 64, b = blockIdx.z;
    __shared__ float sL[64][12];
    __shared__ float sR[12][64];
    __shared__ float bsl[64][65];
    int t = threadIdx.x;
    for (int q = t; q < 768; q += 256) {
        int pp = q / 12, tt = q % 12;
        int p = p0 + pp;
        sL[pp][tt] = (p < N_) ? lhs_s[(b * N_ + p) * 12 + tt] : 0.f;
    }
    for (int q = t; q < 768; q += 256) {
        int tt = q >> 6, ii = q & 63;
        int i = i0 + ii;
        sR[tt][ii] = (i < N_) ? rhs_s[b * (T_ * N_) + tt * N_ + i] : 0.f;
    }
    {
        int pp = t >> 2, c0 = (t & 3) * 16;
        int p = p0 + pp;
        if (p < N_ && i0 + c0 + 15 < N_) {
            const float* src = bs + (size_t)p * N_ + i0 + c0;
#pragma unroll
            for (int e = 0; e < 16; e += 4) *(float4*)&bsl[pp][c0 + e] = *(const float4*)(src + e);
        } else {
#pragma unroll
            for (int e = 0; e < 16; ++e) {
                int i = i0 + c0 + e;
                bsl[pp][c0 + e] = (p < N_ && i < N_) ? bs[(size_t)p * N_ + i] : 0.f;
            }
        }
    }
    __syncthreads();
    int ii = t & 63, w = t >> 6;
    int i = i0 + ii;
    unsigned short o[16];
#pragma unroll
    for (int e = 0; e < 16; ++e) {
        int pl = w * 16 + e;
        int p = p0 + pl;
        float v = 0.f;
        if (p < N_ && i < N_) {
            float d = bsl[pl][ii];
#pragma unroll
            for (int tt = 0; tt < 12; ++tt) d += sL[pl][tt] * sR[tt][ii];
            v = sigmoidf(d);
        }
        o[e] = f2bf(v);
    }
    unsigned short* dst = sigT + (size_t)b * PW * PW + (size_t)i * PW + p0 + w * 16;
    *(int4*)dst = *(int4*)o;
    *(int4*)(dst + 8) = *(int4*)(o + 8);
}

// ---------------- MFMA GEMM 256x256 tile, BK=64, 4-phase/K-tile, 128-B-row XOR swizzle ----------------
// ST[i][j] = sum_p sigT[i][p] * Vsb[j][p]
__global__ __launch_bounds__(512) void k_gemm_S_mfma(const unsigned short* __restrict__ Vsb,
                                                     const unsigned short* __restrict__ sigT,
                                                     unsigned short* __restrict__ ST) {
    int lid = blockIdx.x + (blockIdx.y << 3) + (blockIdx.z << 6);
    int swz = (lid & 7) * 64 + (lid >> 3);
    int j0 = (swz & 7) * 256;
    int i0 = ((swz >> 3) & 7) * 256;
    int b = swz >> 6;
    const unsigned short* Ap = sigT + (size_t)b * PW * PW;
    __shared__ unsigned short As[2][16384];   // [256 rows][64 elems] swizzled, 2 dbuf (64 KB)
    __shared__ unsigned short Bs[2][16384];   // 64 KB
    int t = threadIdx.x, lane = t & 63, w = t >> 6;
    int wr = w >> 2, wc = w & 3;              // wave tile: rows wr*128 (of 256), cols wc*64
    int l15 = lane & 15, kseg = lane >> 4;
    f32x4 acc[8][4];
#pragma unroll
    for (int m = 0; m < 8; ++m)
#pragma unroll
        for (int n = 0; n < 4; ++n)
#pragma unroll
            for (int q = 0; q < 4; ++q) acc[m][n][q] = 0.f;
    // staging: per gload inst 512 thr x 16B = 64 rows x 128B. thread t -> row rb+(t>>3), phys chunk t&7;
    // global logical chunk = (t&7) ^ (row&7)  (row&7 == (t>>3)&7 since rb % 64 == 0)
    int srow = t >> 3;
    int schunk = ((t & 7) ^ (srow & 7)) * 8;
    const unsigned short* gA = Ap + (size_t)(i0 + srow) * PW + schunk;
    const unsigned short* gB = Vsb + (size_t)(j0 + srow) * PW + schunk;
    int ldw = w * 512;   // wave-uniform LDS elem base (HW adds lane*16B)
#define SA_(buf_, kt_, h_) do { \
    gload16(gA + (size_t)((h_) * 128) * PW + (kt_) * 64, &As[buf_][(h_) * 8192 + ldw]); \
    gload16(gA + (size_t)((h_) * 128 + 64) * PW + (kt_) * 64, &As[buf_][(h_) * 8192 + 4096 + ldw]); \
} while (0)
#define SB_(buf_, kt_, h_) do { \
    gload16(gB + (size_t)((h_) * 128) * PW + (kt_) * 64, &Bs[buf_][(h_) * 8192 + ldw]); \
    gload16(gB + (size_t)((h_) * 128 + 64) * PW + (kt_) * 64, &Bs[buf_][(h_) * 8192 + 4096 + ldw]); \
} while (0)
#define RDA(dst, mh_, buf_) do { \
    _Pragma("unroll") for (int m = 0; m < 4; ++m) { \
        int R = wr * 128 + (mh_) * 64 + m * 16 + l15; \
        _Pragma("unroll") for (int kh = 0; kh < 2; ++kh) \
            dst[m][kh] = *(const bf16x8*)&As[buf_][R * 64 + (((kh * 4 + kseg) ^ (R & 7)) << 3)]; \
    } } while (0)
#define RDB(dst, nh_, buf_) do { \
    _Pragma("unroll") for (int n = 0; n < 2; ++n) { \
        int R = wc * 64 + (nh_) * 32 + n * 16 + l15; \
        _Pragma("unroll") for (int kh = 0; kh < 2; ++kh) \
            dst[n][kh] = *(const bf16x8*)&Bs[buf_][R * 64 + (((kh * 4 + kseg) ^ (R & 7)) << 3)]; \
    } } while (0)
#define LGKM0 do { asm volatile("s_waitcnt lgkmcnt(0)" ::: "memory"); __builtin_amdgcn_sched_barrier(0); } while (0)
#define MMA(av, bv, mh_, nh_) do { \
    __builtin_amdgcn_s_setprio(1); \
    _Pragma("unroll") for (int m = 0; m < 4; ++m) \
    _Pragma("unroll") for (int n = 0; n < 2; ++n) \
    _Pragma("unroll") for (int kh = 0; kh < 2; ++kh) \
        acc[m + (mh_) * 4][n + (nh_) * 2] = __builtin_amdgcn_mfma_f32_16x16x32_bf16( \
            av[m][kh], bv[n][kh], acc[m + (mh_) * 4][n + (nh_) * 2], 0, 0, 0); \
    __builtin_amdgcn_s_setprio(0); } while (0)
    // prologue: stage tile 0 fully
    SA_(0, 0, 0); SA_(0, 0, 1); SB_(0, 0, 0); SB_(0, 0, 1);
    for (int kt = 0; kt < 32; ++kt) {
        int buf = kt & 1, nbuf = buf ^ 1;
        bf16x8 aR[4][2], bR[2][2];
        // ---- phase 0: quadrant (mh0, nh0); stage next tile's A-halves ----
        asm volatile("s_waitcnt vmcnt(0)" ::: "memory");   // tile kt landed (kt+1 not yet issued)
        __builtin_amdgcn_s_barrier();
        __builtin_amdgcn_sched_barrier(0);
        if (kt + 1 < 32) { SA_(nbuf, kt + 1, 0); SA_(nbuf, kt + 1, 1); }
        RDA(aR, 0, buf); RDB(bR, 0, buf);
        LGKM0;
        MMA(aR, bR, 0, 0);
        // ---- phase 1: (mh0, nh1); stage next tile's B-halves ----
        __builtin_amdgcn_s_barrier();
        if (kt + 1 < 32) { SB_(nbuf, kt + 1, 0); SB_(nbuf, kt + 1, 1); }
        RDB(bR, 1, buf);
        LGKM0;
        MMA(aR, bR, 0, 1);
        // ---- phase 2: (mh1, nh0) ----
        __builtin_amdgcn_s_barrier();
        RDA(aR, 1, buf); RDB(bR, 0, buf);
        LGKM0;
        MMA(aR, bR, 1, 0);
        // ---- phase 3: (mh1, nh1) ----
        __builtin_amdgcn_s_barrier();
        RDB(bR, 1, buf);
        LGKM0;
        MMA(aR, bR, 1, 1);
    }
#undef SA_
#undef SB_
#undef RDA
#undef RDB
#undef LGKM0
#undef MMA
    unsigned short* Sp = ST + (size_t)b * PW * PW;
#pragma unroll
    for (int mi = 0; mi < 8; ++mi) {
        int row0 = i0 + wr * 128 + (mi >> 2) * 64 + (mi & 3) * 16 + (kseg << 2);
#pragma unroll
        for (int ni = 0; ni < 4; ++ni) {
            int col = j0 + wc * 64 + (ni >> 1) * 32 + (ni & 1) * 16 + l15;
#pragma unroll
            for (int q = 0; q < 4; ++q)
                Sp[(size_t)(row0 + q) * PW + col] = f2bf(acc[mi][ni][q]);
        }
    }
}

// ---- row softmax stats over ST rows ----
__global__ __launch_bounds__(256) void k_smrow(const unsigned short* __restrict__ ST,
                                               float* __restrict__ gm, float* __restrict__ gs) {
    int wid = threadIdx.x >> 6, lane = threadIdx.x & 63;
    int b = blockIdx.y;
    int i = blockIdx.x * 4 + wid;
    const unsigned short* rp = ST + (size_t)b * PW * PW + (size_t)i * PW;
    float vals[32];
    float m = -1e30f;
#pragma unroll
    for (int k = 0; k < 4; ++k) {
        int j0 = lane * 8 + k * 512;
        if (j0 < N_) {
            union { int4 v; unsigned short s[8]; } u;
            u.v = *(const int4*)(rp + j0);
#pragma unroll
            for (int e = 0; e < 8; ++e) {
                vals[k * 8 + e] = bf2f(u.s[e]);
                m = fmaxf(m, vals[k * 8 + e]);
            }
        } else {
#pragma unroll
            for (int e = 0; e < 8; ++e) vals[k * 8 + e] = -1e30f;
        }
    }
#pragma unroll
    for (int off = 32; off >= 1; off >>= 1) m = fmaxf(m, __shfl_xor(m, off));
    float s = 0.f;
#pragma unroll
    for (int k = 0; k < 32; ++k) s += __expf(vals[k] - m);
#pragma unroll
    for (int off = 32; off >= 1; off >>= 1) s += __shfl_xor(s, off);
    if (lane == 0) {
        gm[b * 2048 + i] = m;
        gs[b * 2048 + i] = 1.0f / s;
    }
}

// ---------------- MFMA GEMM (fused softmax-normalize in A-staging) ----------------
__global__ __launch_bounds__(512) void k_gemm_cheb_mfma(const unsigned short* __restrict__ chebT,
                                                        const unsigned short* __restrict__ ST,
                                                        const float* __restrict__ gm, const float* __restrict__ gs,
                                                        const unsigned short* __restrict__ xT,
                                                        unsigned short* __restrict__ h2) {
    int bk = blockIdx.y;
    int b = bk / 3, kk = bk % 3;
    int i0 = blockIdx.x * 128;
    const unsigned short* Ac = chebT + (size_t)kk * PW * PW;
    const unsigned short* Sa = ST + (size_t)b * PW * PW;
    const unsigned short* Bx = xT + (size_t)b * 384 * PW;
    __shared__ unsigned short As[2][4096];
    __shared__ unsigned short Bs[2][12288];
    int t = threadIdx.x, lane = t & 63, w = t >> 6;
    int wr = w >> 2, wc = w & 3;
    f32x4 acc[4][6];
#pragma unroll
    for (int a = 0; a < 4; ++a)
#pragma unroll
        for (int c = 0; c < 6; ++c)
#pragma unroll
            for (int q = 0; q < 4; ++q) acc[a][c][q] = 0.f;
    int arow = t >> 2, aq = t & 3;
    const unsigned short* gc = Ac + (size_t)(i0 + arow) * PW + aq * 8;
    const unsigned short* gsat = Sa + (size_t)(i0 + arow) * PW + aq * 8;
    float gmv = gm[b * 2048 + i0 + arow];
    float gsv = gs[b * 2048 + i0 + arow];
    int aoff = arow * 32 + (aq ^ (arow & 3)) * 8;
    int bseg = (t & 3) ^ ((t >> 2) & 3);
    const unsigned short* gB = Bx + (size_t)(t >> 2) * PW + bseg * 8;
    int ldso = w * 512;
#define STAGE_B(buf, p) do { \
    gload16(gB + (p), &Bs[buf][ldso]); \
    gload16(gB + 128 * PW + (p), &Bs[buf][4096 + ldso]); \
    gload16(gB + 256 * PW + (p), &Bs[buf][8192 + ldso]); \
} while (0)
    union U8 { int4 v; unsigned short s[8]; };
    U8 ca, sa;
    ca.v = *(const int4*)gc;
    sa.v = *(const int4*)gsat;
    STAGE_B(0, 0);
    {
        U8 o;
#pragma unroll
        for (int e = 0; e < 8; ++e) o.s[e] = f2bf(bf2f(ca.s[e]) * __expf(bf2f(sa.s[e]) - gmv) * gsv);
        *(int4*)&As[0][aoff] = o.v;
    }
    ca.v = *(const int4*)(gc + 32);
    sa.v = *(const int4*)(gsat + 32);
    __syncthreads();
    int cur = 0;
    int rswz = ((lane >> 4) ^ (lane & 3)) * 8;
    for (int p = 0; p < PW; p += 32) {
        if (p + 32 < PW) {
            STAGE_B(cur ^ 1, p + 32);
            U8 o;
#pragma unroll
            for (int e = 0; e < 8; ++e) o.s[e] = f2bf(bf2f(ca.s[e]) * __expf(bf2f(sa.s[e]) - gmv) * gsv);
            *(int4*)&As[cur ^ 1][aoff] = o.v;
            int pn = (p + 64 < PW) ? p + 64 : 0;
            ca.v = *(const int4*)(gc + pn);
            sa.v = *(const int4*)(gsat + pn);
        }
        bf16x8 af[4], bfr[6];
#pragma unroll
        for (int fm = 0; fm < 4; ++fm)
            af[fm] = *(const bf16x8*)&As[cur][(wr * 64 + fm * 16 + (lane & 15)) * 32 + rswz];
#pragma unroll
        for (int fn = 0; fn < 6; ++fn)
            bfr[fn] = *(const bf16x8*)&Bs[cur][(wc * 96 + fn * 16 + (lane & 15)) * 32 + rswz];
#pragma unroll
        for (int fm = 0; fm < 4; ++fm)
#pragma unroll
            for (int fn = 0; fn < 6; ++fn)
                acc[fm][fn] = __builtin_amdgcn_mfma_f32_16x16x32_bf16(af[fm], bfr[fn], acc[fm][fn], 0, 0, 0);
        __syncthreads();
        cur ^= 1;
    }
#undef STAGE_B
    unsigned short* hp = h2 + (size_t)bk * 768000;
#pragma unroll
    for (int fm = 0; fm < 4; ++fm) {
        int row0 = i0 + wr * 64 + fm * 16 + ((lane >> 4) << 2);
#pragma unroll
        for (int fn = 0; fn < 6; ++fn) {
            int col = wc * 96 + fn * 16 + (lane & 15);
#pragma unroll
            for (int q = 0; q < 4; ++q) {
                int row = row0 + q;
                if (row < N_) hp[(size_t)row * 384 + col] = f2bf(acc[fm][fn][q]);
            }
        }
    }
}

// ---------------- fused tail: theta mix + time conv + residual + relu + LayerNorm ----------------
__global__ __launch_bounds__(512) void k_final3(const float* __restrict__ x, const unsigned short* __restrict__ h2,
                                                const float* __restrict__ ThetaG,
                                                const float* __restrict__ tcwT, const float* __restrict__ tc_b,
                                                const float* __restrict__ rcwT, const float* __restrict__ rc_b,
                                                const float* __restrict__ ln_g, const float* __restrict__ ln_b,
                                                float* __restrict__ out) {
    __shared__ __align__(16) char smem[110848];
    unsigned int* gl = (unsigned int*)smem;
    unsigned short* th = (unsigned short*)(smem + 98560);
    float* red_s = (float*)(smem + 98560);
    float* red_q = red_s + 64 * 13;

    int tid = threadIdx.x;
    int n_l = tid & 63, fg = tid >> 6;
    int b = blockIdx.y;
    int node = blockIdx.x * 64 + n_l;
    bool ok = node < N_;
    int nd = ok ? node : N_ - 1;

    for (int q = tid; q < 6144; q += 512) th[q] = f2bf(ThetaG[q]);
    __syncthreads();

    float acc[8][12];
#pragma unroll
    for (int ff = 0; ff < 8; ++ff)
#pragma unroll
        for (int t = 0; t < 12; ++t) acc[ff][t] = 0.f;
    const unsigned short* hb = h2 + (size_t)b * 3 * 768000 + (size_t)nd * 384;
#pragma unroll
    for (int kk = 0; kk < 3; ++kk) {
        const unsigned short* hp = hb + (size_t)kk * 768000;
#pragma unroll 2
        for (int c = 0; c < 32; ++c) {
            const unsigned short* hq = hp + c * 12;
            uint2 u0 = *(const uint2*)(hq);
            uint2 u1 = *(const uint2*)(hq + 4);
            uint2 u2 = *(const uint2*)(hq + 8);
            float h[12];
            h[0] = bf2f((unsigned short)u0.x);  h[1] = bf2f((unsigned short)(u0.x >> 16));
            h[2] = bf2f((unsigned short)u0.y);  h[3] = bf2f((unsigned short)(u0.y >> 16));
            h[4] = bf2f((unsigned short)u1.x);  h[5] = bf2f((unsigned short)(u1.x >> 16));
            h[6] = bf2f((unsigned short)u1.y);  h[7] = bf2f((unsigned short)(u1.y >> 16));
            h[8] = bf2f((unsigned short)u2.x);  h[9] = bf2f((unsigned short)(u2.x >> 16));
            h[10] = bf2f((unsigned short)u2.y); h[11] = bf2f((unsigned short)(u2.y >> 16));
            const unsigned short* wv = th + (kk * 32 + c) * 64 + fg * 8;
            uint2 w01 = *(const uint2*)wv;
            uint2 w23 = *(const uint2*)(wv + 4);
            float wf[8];
            wf[0] = bf2f((unsigned short)w01.x); wf[1] = bf2f((unsigned short)(w01.x >> 16));
            wf[2] = bf2f((unsigned short)w01.y); wf[3] = bf2f((unsigned short)(w01.y >> 16));
            wf[4] = bf2f((unsigned short)w23.x); wf[5] = bf2f((unsigned short)(w23.x >> 16));
            wf[6] = bf2f((unsigned short)w23.y); wf[7] = bf2f((unsigned short)(w23.y >> 16));
#pragma unroll
            for (int ff = 0; ff < 8; ++ff)
#pragma unroll
                for (int t = 0; t < 12; ++t) acc[ff][t] = fmaf(h[t], wf[ff], acc[ff][t]);
        }
    }
    unsigned int* gr = gl + n_l * 385 + fg * 48;
#pragma unroll
    for (int ff = 0; ff < 8; ++ff)
#pragma unroll
        for (int tp = 0; tp < 6; ++tp) {
            float a0 = fmaxf(acc[ff][2 * tp], 0.f), a1 = fmaxf(acc[ff][2 * tp + 1], 0.f);
            gr[ff * 6 + tp] = (unsigned int)f2bf(a0) | ((unsigned int)f2bf(a1) << 16);
        }
    __syncthreads();

    float z[8][12];
#pragma unroll
    for (int ff = 0; ff < 8; ++ff) {
        float bias = tc_b[fg * 8 + ff] + rc_b[fg * 8 + ff];
#pragma unroll
        for (int t = 0; t < 12; ++t) z[ff][t] = bias;
    }
    const float* xp = x + (size_t)(b * 2000 + nd) * 384;
#pragma unroll 2
    for (int c = 0; c < 32; ++c) {
        float4 x0 = *(const float4*)(xp + c * 12);
        float4 x1 = *(const float4*)(xp + c * 12 + 4);
        float4 x2 = *(const float4*)(xp + c * 12 + 8);
        float xv[12] = {x0.x, x0.y, x0.z, x0.w, x1.x, x1.y, x1.z, x1.w, x2.x, x2.y, x2.z, x2.w};
        float4 r0 = *(const float4*)(rcwT + c * 64 + fg * 8);
        float4 r1 = *(const float4*)(rcwT + c * 64 + fg * 8 + 4);
        float rw[8] = {r0.x, r0.y, r0.z, r0.w, r1.x, r1.y, r1.z, r1.w};
#pragma unroll
        for (int ff = 0; ff < 8; ++ff)
#pragma unroll
            for (int t = 0; t < 12; ++t) z[ff][t] = fmaf(xv[t], rw[ff], z[ff][t]);
    }
    const unsigned int* grow = gl + n_l * 385;
    for (int fi = 0; fi < 64; ++fi) {
        float g[12];
#pragma unroll
        for (int j = 0; j < 6; ++j) {
            unsigned int u = grow[fi * 6 + j];
            g[2 * j] = bf2f((unsigned short)u);
            g[2 * j + 1] = bf2f((unsigned short)(u >> 16));
        }
        const float* wp = tcwT + (fi * 64 + fg * 8) * 3;
        float4 w0 = *(const float4*)(wp);
        float4 w1 = *(const float4*)(wp + 4);
        float4 w2 = *(const float4*)(wp + 8);
        float4 w3 = *(const float4*)(wp + 12);
        float4 w4 = *(const float4*)(wp + 16);
        float4 w5 = *(const float4*)(wp + 20);
        float wb[24] = {w0.x, w0.y, w0.z, w0.w, w1.x, w1.y, w1.z, w1.w,
                        w2.x, w2.y, w2.z, w2.w, w3.x, w3.y, w3.z, w3.w,
                        w4.x, w4.y, w4.z, w4.w, w5.x, w5.y, w5.z, w5.w};
#pragma unroll
        for (int ff = 0; ff < 8; ++ff) {
            float a0 = wb[ff * 3], a1 = wb[ff * 3 + 1], a2 = wb[ff * 3 + 2];
            z[ff][0] = fmaf(g[0], a1, fmaf(g[1], a2, z[ff][0]));
#pragma unroll
            for (int t = 1; t < 11; ++t)
                z[ff][t] = fmaf(g[t - 1], a0, fmaf(g[t], a1, fmaf(g[t + 1], a2, z[ff][t])));
            z[ff][11] = fmaf(g[10], a0, fmaf(g[11], a1, z[ff][11]));
        }
    }
#pragma unroll
    for (int ff = 0; ff < 8; ++ff)
#pragma unroll
        for (int t = 0; t < 12; ++t) z[ff][t] = fmaxf(z[ff][t], 0.f);

    float s[12], q[12];
#pragma unroll
    for (int t = 0; t < 12; ++t) { s[t] = 0.f; q[t] = 0.f; }
#pragma unroll
    for (int ff = 0; ff < 8; ++ff)
#pragma unroll
        for (int t = 0; t < 12; ++t) { s[t] += z[ff][t]; q[t] += z[ff][t] * z[ff][t]; }
    __syncthreads();
    for (int g = 0; g < 8; ++g) {
        if (fg == g) {
            if (g == 0) {
#pragma unroll
                for (int t = 0; t < 12; ++t) { red_s[n_l * 13 + t] = s[t]; red_q[n_l * 13 + t] = q[t]; }
            } else {
#pragma unroll
                for (int t = 0; t < 12; ++t) { red_s[n_l * 13 + t] += s[t]; red_q[n_l * 13 + t] += q[t]; }
            }
        }
        __syncthreads();
    }
    float mu[12], rs[12];
#pragma unroll
    for (int t = 0; t < 12; ++t) {
        float m = red_s[n_l * 13 + t] * (1.0f / 64.0f);
        float v = red_q[n_l * 13 + t] * (1.0f / 64.0f) - m * m;
        mu[t] = m;
        rs[t] = rsqrtf(v + 1e-5f);
    }
    if (ok) {
        float* op = out + ((size_t)(b * 2000 + node) * 64 + fg * 8) * 12;
#pragma unroll
        for (int ff = 0; ff < 8; ++ff) {
            float lg = ln_g[fg * 8 + ff], lb = ln_b[fg * 8 + ff];
            float o[12];
#pragma unroll
            for (int t = 0; t < 12; ++t) o[t] = (z[ff][t] - mu[t]) * rs[t] * lg + lb;
#pragma unroll
            for (int tq = 0; tq < 3; ++tq)
                *(float4*)(op + ff * 12 + tq * 4) = make_float4(o[tq * 4], o[tq * 4 + 1], o[tq * 4 + 2], o[tq * 4 + 3]);
        }
    }
}

extern "C" void kernel_launch(void* const* d_in, const int* in_sizes, int n_in,
                              void* d_out, int out_size, void* d_ws, size_t ws_size,
                              hipStream_t stream) {
    const float* x     = (const float*)d_in[0];
    const float* cheb  = (const float*)d_in[1];
    const float* U1    = (const float*)d_in[2];
    const float* U2    = (const float*)d_in[3];
    const float* U3    = (const float*)d_in[4];
    const float* be    = (const float*)d_in[5];
    const float* Ve    = (const float*)d_in[6];
    const float* W1    = (const float*)d_in[7];
    const float* W2    = (const float*)d_in[8];
    const float* W3    = (const float*)d_in[9];
    const float* bs    = (const float*)d_in[10];
    const float* Vs    = (const float*)d_in[11];
    const float* Theta = (const float*)d_in[12];
    const float* tc_w  = (const float*)d_in[13];
    const float* tc_b  = (const float*)d_in[14];
    const float* rc_w  = (const float*)d_in[15];
    const float* rc_b  = (const float*)d_in[16];
    const float* ln_g  = (const float*)d_in[17];
    const float* ln_b  = (const float*)d_in[18];
    float* out = (float*)d_out;

    // ---- workspace layout (~184.3 MB, identical to round 8-10) ----
    float* ws    = (float*)d_ws;
    float* At    = ws;                       // 1152      -> 1152
    float* lhs1  = ws + 1152;                // 3072      -> 4224
    float* lhsT  = ws + 4224;                // 192000    -> 196224
    float* rhsT  = ws + 196224;              // 192000    -> 388224
    float* lhs_s = ws + 388224;              // 192000    -> 580224
    float* rhs_s = ws + 580224;              // 192000    -> 772224
    float* gm    = ws + 772224;              // 16384     -> 788608
    float* gs    = ws + 788608;              // 16384     -> 804992
    float* tcwT  = ws + 804992;              // 12288     -> 817280
    float* rcwT  = ws + 817280;              // 2048      -> 819328
    float* plh   = ws + 819328;              // 153600    -> 972928
    float* pP    = ws + 972928;              // 18432     -> 991360
    unsigned short* Vsb   = (unsigned short*)(ws + 991360);    // -> 3,088,512
    unsigned short* chebT = (unsigned short*)(ws + 3088512);   // -> 9,379,968
    unsigned short* xT    = (unsigned short*)(ws + 9379968);   // -> 12,525,696
    unsigned short* sigT  = (unsigned short*)(ws + 12525696);  // -> 29,302,912 (dead after gemm_S)
    unsigned short* h2    = sigT;                              // reuse after gemm_S
    unsigned short* STb   = (unsigned short*)(ws + 29302912);  // -> 46,080,128

    // prep
    k_wprep<<<56, 256, 0, stream>>>(tc_w, rc_w, tcwT, rcwT);
    k_vsb<<<2048, 256, 0, stream>>>(Vs, Vsb);
    k_chebT<<<dim3(32, 32, 3), 256, 0, stream>>>(cheb, chebT);
    k_xT<<<dim3(32, 6, 8), 256, 0, stream>>>(x, xT);
    // temporal attention
    k_tprep<<<dim3(50, 8), 256, 0, stream>>>(x, U1, U3, rhsT, plh);
    k_tred<<<8, 256, 0, stream>>>(plh, lhs1);
    k_lhsT<<<750, 256, 0, stream>>>(lhs1, U2, lhsT);
    k_tatt1<<<dim3(16, 8), 256, 0, stream>>>(lhsT, rhsT, pP);
    k_tatt2<<<8, 256, 0, stream>>>(pP, be, Ve, At);
    k_xsp<<<dim3(250, 8), 256, 0, stream>>>(x, At, W1, W2, W3, lhs_s, rhs_s);
    // spatial attention (S^T directly)
    k_sig<<<dim3(32, 32, 8), 256, 0, stream>>>(lhs_s, rhs_s, bs, sigT);
    k_gemm_S_mfma<<<dim3(8, 8, 8), 512, 0, stream>>>(Vsb, sigT, STb);
    k_smrow<<<dim3(512, 8), 256, 0, stream>>>(STb, gm, gs);
    // chebyshev gcn with fused softmax normalization
    k_gemm_cheb_mfma<<<dim3(16, 24), 512, 0, stream>>>(chebT, STb, gm, gs, xT, h2);
    // fused theta + conv + LN tail
    k_final3<<<dim3(32, 8), 512, 0, stream>>>(x, h2, Theta, tcwT, tc_b, rcwT, rc_b, ln_g, ln_b, out);
}

// Round 12
// 603.611 us; speedup vs baseline: 1.0692x; 1.0560x over previous
//
#include <hip/hip_runtime.h>
#include <hip/hip_bf16.h>
#include <math.h>

#define B_ 8
#define N_ 2000
#define C_ 32
#define T_ 12
#define K_ 3
#define FC_ 64
#define FT_ 64
#define PW 2048   // padded width (K and row pads, zero-filled)

typedef short bf16x8 __attribute__((ext_vector_type(8)));
typedef float f32x4 __attribute__((ext_vector_type(4)));

__device__ __forceinline__ float sigmoidf(float v) { return 1.0f / (1.0f + __expf(-v)); }
__device__ __forceinline__ float bf2f(unsigned short u) {
    union { unsigned int i; float f; } v; v.i = ((unsigned int)u) << 16; return v.f;
}
__device__ __forceinline__ unsigned short f2bf(float f) {
    union { __hip_bfloat16 h; unsigned short u; } v; v.h = __float2bfloat16(f); return v.u;
}
typedef const __attribute__((address_space(1))) void* gas_t;
typedef __attribute__((address_space(3))) void* las_t;
__device__ __forceinline__ void gload16(const unsigned short* g, unsigned short* l) {
    __builtin_amdgcn_global_load_lds((gas_t)g, (las_t)l, 16, 0, 0);
}

// ---------------- fused x-pass: lhs1 partials + rhsT ----------------
__global__ __launch_bounds__(256) void k_tprep(const float* __restrict__ x, const float* __restrict__ U1,
                                               const float* __restrict__ U3,
                                               float* __restrict__ rhsT, float* __restrict__ plh) {
    int b = blockIdx.y, chunk = blockIdx.x;
    int tid = threadIdx.x;
    int nl = tid >> 5, c = tid & 31;
    int w = tid >> 6;
    float u3 = U3[c];
    float plA[12];
#pragma unroll
    for (int t = 0; t < 12; ++t) plA[t] = 0.f;
    for (int it = 0; it < 5; ++it) {
        int n = chunk * 40 + it * 8 + nl;
        const float* xp = x + ((size_t)(b * 2000 + n) * 32 + c) * 12;
        float4 v0 = *(const float4*)xp, v1 = *(const float4*)(xp + 4), v2 = *(const float4*)(xp + 8);
        float xv[12] = {v0.x, v0.y, v0.z, v0.w, v1.x, v1.y, v1.z, v1.w, v2.x, v2.y, v2.z, v2.w};
        float rv[12];
#pragma unroll
        for (int t = 0; t < 12; ++t) rv[t] = u3 * xv[t];
#pragma unroll
        for (int off = 16; off >= 1; off >>= 1)
#pragma unroll
            for (int t = 0; t < 12; ++t) rv[t] += __shfl_xor(rv[t], off);
        if (c == 0) {
#pragma unroll
            for (int t = 0; t < 12; ++t) rhsT[(size_t)(b * 2000 + n) * 12 + t] = rv[t];
        }
        float u1 = U1[n];
#pragma unroll
        for (int t = 0; t < 12; ++t) plA[t] += u1 * xv[t];
    }
#pragma unroll
    for (int t = 0; t < 12; ++t) plA[t] += __shfl_xor(plA[t], 32);
    __shared__ float accs[4][32][12];
    if ((tid & 63) < 32) {
#pragma unroll
        for (int t = 0; t < 12; ++t) accs[w][c][t] = plA[t];
    }
    __syncthreads();
    if (tid < 384) {
        int c2 = tid / 12, t2 = tid % 12;
        float s = accs[0][c2][t2] + accs[1][c2][t2] + accs[2][c2][t2] + accs[3][c2][t2];
        plh[((size_t)(b * 50 + chunk)) * 384 + tid] = s;
    }
}

__global__ __launch_bounds__(256) void k_tred(const float* __restrict__ plh, float* __restrict__ lhs1) {
    int b = blockIdx.x;
    for (int q = threadIdx.x; q < 384; q += 256) {
        const float* p = plh + (size_t)b * 50 * 384 + q;
        float s = 0.f;
        for (int ch = 0; ch < 50; ++ch) s += p[(size_t)ch * 384];
        int c = q / 12, t = q % 12;
        lhs1[(b * 12 + t) * 32 + c] = s;
    }
}

__global__ __launch_bounds__(256) void k_lhsT(const float* __restrict__ lhs1, const float* __restrict__ U2,
                                              float* __restrict__ lhsT) {
    int gid = blockIdx.x * 256 + threadIdx.x;
    if (gid >= B_ * T_ * N_) return;
    int n = gid % N_;
    int bt = gid / N_;
    const float* l1 = lhs1 + bt * C_;
    float a = 0.f;
#pragma unroll
    for (int c = 0; c < C_; ++c) a += l1[c] * U2[c * N_ + n];
    lhsT[gid] = a;
}

__global__ __launch_bounds__(256) void k_tatt1(const float* __restrict__ lhsT, const float* __restrict__ rhsT,
                                               float* __restrict__ pP) {
    int b = blockIdx.y, ch = blockIdx.x;
    int tid = threadIdx.x;
    int n0 = ch * 125;
    __shared__ float sL[12][128];
    __shared__ float sR[128][12];
    for (int q = tid; q < 12 * 125; q += 256) {
        int t = q / 125, nn = q % 125;
        sL[t][nn] = lhsT[(size_t)(b * 12 + t) * 2000 + n0 + nn];
    }
    for (int q = tid; q < 125 * 12; q += 256) {
        int nn = q / 12, t = q % 12;
        sR[nn][t] = rhsT[(size_t)(b * 2000 + n0 + nn) * 12 + t];
    }
    __syncthreads();
    if (tid < 144) {
        int tP = tid / 12, uP = tid % 12;
        float a = 0.f;
#pragma unroll 5
        for (int nn = 0; nn < 125; ++nn) a += sL[tP][nn] * sR[nn][uP];
        pP[(size_t)(b * 16 + ch) * 144 + tid] = a;
    }
}

__global__ __launch_bounds__(256) void k_tatt2(const float* __restrict__ pP, const float* __restrict__ be,
                                               const float* __restrict__ Ve, float* __restrict__ At) {
    int b = blockIdx.x, tid = threadIdx.x;
    __shared__ float sp[144], sE[144], mk[12], sk[12];
    int tP = tid / 12, uP = tid % 12;
    if (tid < 144) {
        float a = 0.f;
#pragma unroll
        for (int ch = 0; ch < 16; ++ch) a += pP[(size_t)(b * 16 + ch) * 144 + tid];
        sp[tid] = sigmoidf(a + be[tid]);
    }
    __syncthreads();
    if (tid < 144) {
        float e = 0.f;
#pragma unroll
        for (int j = 0; j < 12; ++j) e += Ve[tP * 12 + j] * sp[j * 12 + uP];
        sE[tid] = e;
    }
    __syncthreads();
    if (tid < 12) {
        float m = -1e30f;
#pragma unroll
        for (int i = 0; i < 12; ++i) m = fmaxf(m, sE[i * 12 + tid]);
        float s = 0.f;
#pragma unroll
        for (int i = 0; i < 12; ++i) s += __expf(sE[i * 12 + tid] - m);
        mk[tid] = m; sk[tid] = 1.0f / s;
    }
    __syncthreads();
    if (tid < 144) At[b * 144 + tid] = __expf(sE[tid] - mk[uP]) * sk[uP];
}

__global__ __launch_bounds__(256) void k_xsp(const float* __restrict__ x, const float* __restrict__ At,
                                             const float* __restrict__ W1, const float* __restrict__ W2,
                                             const float* __restrict__ W3,
                                             float* __restrict__ lhs_s, float* __restrict__ rhs_s) {
    int b = blockIdx.y, chunk = blockIdx.x;
    int tid = threadIdx.x, nl = tid >> 5, c = tid & 31;
    int n = chunk * 8 + nl;
    __shared__ float atl[144];
    __shared__ float w2l[384];
    __shared__ float w1l[12];
    if (tid < 144) atl[tid] = At[b * 144 + tid];
    if (tid >= 144 && tid < 156) w1l[tid - 144] = W1[tid - 144];
    for (int q = tid; q < 384; q += 256) w2l[q] = W2[q];
    __syncthreads();
    const float* xp = x + ((size_t)(b * 2000 + n) * 32 + c) * 12;
    float4 v0 = *(const float4*)xp, v1 = *(const float4*)(xp + 4), v2 = *(const float4*)(xp + 8);
    float xv[12] = {v0.x, v0.y, v0.z, v0.w, v1.x, v1.y, v1.z, v1.w, v2.x, v2.y, v2.z, v2.w};
    float xa[12];
#pragma unroll
    for (int t = 0; t < 12; ++t) {
        float s = 0.f;
#pragma unroll
        for (int u = 0; u < 12; ++u) s += xv[u] * atl[u * 12 + t];
        xa[t] = s;
    }
    float w3 = W3[c];
    float rv[12], lv[12];
    float l1 = 0.f;
#pragma unroll
    for (int t = 0; t < 12; ++t) l1 += xa[t] * w1l[t];
#pragma unroll
    for (int t = 0; t < 12; ++t) { rv[t] = w3 * xa[t]; lv[t] = l1 * w2l[c * 12 + t]; }
#pragma unroll
    for (int off = 16; off >= 1; off >>= 1)
#pragma unroll
        for (int t = 0; t < 12; ++t) { rv[t] += __shfl_xor(rv[t], off); lv[t] += __shfl_xor(lv[t], off); }
    if (c == 0) {
#pragma unroll
        for (int t = 0; t < 12; ++t) rhs_s[(size_t)(b * 12 + t) * 2000 + n] = rv[t];
#pragma unroll
        for (int t = 0; t < 12; ++t) lhs_s[(size_t)(b * 2000 + n) * 12 + t] = lv[t];
    }
}

// ---------------- weight transposes ----------------
__global__ __launch_bounds__(256) void k_wprep(const float* __restrict__ tc_w, const float* __restrict__ rc_w,
                                               float* __restrict__ tcwT, float* __restrict__ rcwT) {
    int gid = blockIdx.x * 256 + threadIdx.x;
    if (gid < 12288) {
        int fi = gid / 192, rem = gid % 192, f = rem / 3, d = rem % 3;
        tcwT[gid] = tc_w[(f * 64 + fi) * 3 + d];
    } else if (gid < 14336) {
        int q = gid - 12288;
        int c = q >> 6, f = q & 63;
        rcwT[q] = rc_w[f * 32 + c];
    }
}

// ---------------- conversions / transposes (padded to PW, zero-filled) ----------------
__global__ __launch_bounds__(256) void k_vsb(const float* __restrict__ Vs, unsigned short* __restrict__ Vsb) {
    int gid = blockIdx.x * 256 + threadIdx.x;
    int row = gid >> 8, chunk = gid & 255;
    int p0 = chunk * 8;
    unsigned short o[8];
#pragma unroll
    for (int e = 0; e < 8; ++e) {
        int p = p0 + e;
        o[e] = (row < N_ && p < N_) ? f2bf(Vs[row * N_ + p]) : (unsigned short)0;
    }
    *(int4*)(Vsb + (size_t)row * PW + p0) = *(int4*)o;
}

__global__ __launch_bounds__(256) void k_chebT(const float* __restrict__ cheb, unsigned short* __restrict__ chebT) {
    int j0 = blockIdx.x * 64, i0 = blockIdx.y * 64, kk = blockIdx.z;
    __shared__ float Tl[64][65];
    int t = threadIdx.x;
    int rr = t >> 2, c0 = (t & 3) * 16;
    int j = j0 + rr;
#pragma unroll
    for (int e = 0; e < 16; ++e) {
        int i = i0 + c0 + e;
        Tl[rr][c0 + e] = (j < N_ && i < N_) ? cheb[(size_t)kk * 4000000 + (size_t)j * N_ + i] : 0.f;
    }
    __syncthreads();
    int l = t & 63, w = t >> 6;
    unsigned short o[16];
#pragma unroll
    for (int e = 0; e < 16; ++e) o[e] = f2bf(Tl[w * 16 + e][l]);
    unsigned short* dst = chebT + (size_t)kk * PW * PW + (size_t)(i0 + l) * PW + j0 + w * 16;
    *(int4*)dst = *(int4*)o;
    *(int4*)(dst + 8) = *(int4*)(o + 8);
}

__global__ __launch_bounds__(256) void k_xT(const float* __restrict__ x, unsigned short* __restrict__ xT) {
    int j0 = blockIdx.x * 64, r0 = blockIdx.y * 64, b = blockIdx.z;
    __shared__ float Tl[64][65];
    int t = threadIdx.x;
    int rr = t >> 2, c0 = (t & 3) * 16;
    int j = j0 + rr;
#pragma unroll
    for (int e = 0; e < 16; ++e) {
        int r = r0 + c0 + e;
        Tl[rr][c0 + e] = (j < N_) ? x[(size_t)(b * N_ + j) * 384 + r] : 0.f;
    }
    __syncthreads();
    int l = t & 63, w = t >> 6;
    unsigned short o[16];
#pragma unroll
    for (int e = 0; e < 16; ++e) o[e] = f2bf(Tl[w * 16 + e][l]);
    unsigned short* dst = xT + (size_t)b * 384 * PW + (size_t)(r0 + l) * PW + j0 + w * 16;
    *(int4*)dst = *(int4*)o;
    *(int4*)(dst + 8) = *(int4*)(o + 8);
}

__global__ __launch_bounds__(256) void k_sig(const float* __restrict__ lhs_s, const float* __restrict__ rhs_s,
                                             const float* __restrict__ bs, unsigned short* __restrict__ sigT) {
    int p0 = blockIdx.x * 64, i0 = blockIdx.y * 64, b = blockIdx.z;
    __shared__ float sL[64][12];
    __shared__ float sR[12][64];
    __shared__ float bsl[64][65];
    int t = threadIdx.x;
    for (int q = t; q < 768; q += 256) {
        int pp = q / 12, tt = q % 12;
        int p = p0 + pp;
        sL[pp][tt] = (p < N_) ? lhs_s[(b * N_ + p) * 12 + tt] : 0.f;
    }
    for (int q = t; q < 768; q += 256) {
        int tt = q >> 6, ii = q & 63;
        int i = i0 + ii;
        sR[tt][ii] = (i < N_) ? rhs_s[b * (T_ * N_) + tt * N_ + i] : 0.f;
    }
    {
        int pp = t >> 2, c0 = (t & 3) * 16;
        int p = p0 + pp;
        if (p < N_ && i0 + c0 + 15 < N_) {
            const float* src = bs + (size_t)p * N_ + i0 + c0;
#pragma unroll
            for (int e = 0; e < 16; e += 4) *(float4*)&bsl[pp][c0 + e] = *(const float4*)(src + e);
        } else {
#pragma unroll
            for (int e = 0; e < 16; ++e) {
                int i = i0 + c0 + e;
                bsl[pp][c0 + e] = (p < N_ && i < N_) ? bs[(size_t)p * N_ + i] : 0.f;
            }
        }
    }
    __syncthreads();
    int ii = t & 63, w = t >> 6;
    int i = i0 + ii;
    unsigned short o[16];
#pragma unroll
    for (int e = 0; e < 16; ++e) {
        int pl = w * 16 + e;
        int p = p0 + pl;
        float v = 0.f;
        if (p < N_ && i < N_) {
            float d = bsl[pl][ii];
#pragma unroll
            for (int tt = 0; tt < 12; ++tt) d += sL[pl][tt] * sR[tt][ii];
            v = sigmoidf(d);
        }
        o[e] = f2bf(v);
    }
    unsigned short* dst = sigT + (size_t)b * PW * PW + (size_t)i * PW + p0 + w * 16;
    *(int4*)dst = *(int4*)o;
    *(int4*)(dst + 8) = *(int4*)(o + 8);
}

// ---------------- MFMA GEMM 256x256, BK=64, K-half staged, counted vmcnt(4) pipeline ----------------
// ST[i][j] = sum_p sigT[i][p] * Vsb[j][p]
#define FR_(R) (((R) ^ ((R) >> 2)) & 3)
__global__ __launch_bounds__(512) void k_gemm_S_mfma(const unsigned short* __restrict__ Vsb,
                                                     const unsigned short* __restrict__ sigT,
                                                     unsigned short* __restrict__ ST) {
    int lid = blockIdx.x + (blockIdx.y << 3) + (blockIdx.z << 6);
    int swz = (lid & 7) * 64 + (lid >> 3);
    int j0 = (swz & 7) * 256;
    int i0 = ((swz >> 3) & 7) * 256;
    int b = swz >> 6;
    const unsigned short* Ap = sigT + (size_t)b * PW * PW;
    __shared__ unsigned short As[2][2][8192];   // [buf][khalf][256 rows x 32 elems]
    __shared__ unsigned short Bs[2][2][8192];
    int t = threadIdx.x, lane = t & 63, w = t >> 6;
    int wr = w >> 2, wc = w & 3;                // wave: rows wr*128, cols wc*64
    int l15 = lane & 15, kseg = lane >> 4;
    f32x4 acc[8][4];
#pragma unroll
    for (int m = 0; m < 8; ++m)
#pragma unroll
        for (int n = 0; n < 4; ++n)
#pragma unroll
            for (int q = 0; q < 4; ++q) acc[m][n][q] = 0.f;
    // staging: thread t -> local row t>>2 (+128 for 2nd gload), phys chunk t&3, global chunk pre-swizzled
    int srow = t >> 2;
    int gchunk = ((t & 3) ^ FR_(srow)) * 8;    // FR_(srow+128) == FR_(srow)
    const unsigned short* gA = Ap + (size_t)(i0 + srow) * PW + gchunk;
    const unsigned short* gB = Vsb + (size_t)(j0 + srow) * PW + gchunk;
    int ldw = w * 512;
#define SA_(buf_, kt_, kh_) do { \
    gload16(gA + (size_t)(kt_) * 64 + (kh_) * 32, &As[buf_][kh_][ldw]); \
    gload16(gA + (size_t)128 * PW + (size_t)(kt_) * 64 + (kh_) * 32, &As[buf_][kh_][4096 + ldw]); \
} while (0)
#define SB_(buf_, kt_, kh_) do { \
    gload16(gB + (size_t)(kt_) * 64 + (kh_) * 32, &Bs[buf_][kh_][ldw]); \
    gload16(gB + (size_t)128 * PW + (size_t)(kt_) * 64 + (kh_) * 32, &Bs[buf_][kh_][4096 + ldw]); \
} while (0)
#define RDA(kh_, buf_) { _Pragma("unroll") for (int m = 0; m < 8; ++m) { \
    int R = wr * 128 + m * 16 + l15; \
    aR[m] = *(const bf16x8*)&As[buf_][kh_][R * 32 + ((kseg ^ FR_(R)) << 3)]; } }
#define RDB(kh_, nh_, buf_) { _Pragma("unroll") for (int n = 0; n < 2; ++n) { \
    int R = wc * 64 + (nh_) * 32 + n * 16 + l15; \
    bR[n] = *(const bf16x8*)&Bs[buf_][kh_][R * 32 + ((kseg ^ FR_(R)) << 3)]; } }
#define LGKM0 do { asm volatile("s_waitcnt lgkmcnt(0)" ::: "memory"); __builtin_amdgcn_sched_barrier(0); } while (0)
#define MMA(nh_) do { __builtin_amdgcn_s_setprio(1); \
    _Pragma("unroll") for (int m = 0; m < 8; ++m) \
    _Pragma("unroll") for (int n = 0; n < 2; ++n) \
        acc[m][(nh_) * 2 + n] = __builtin_amdgcn_mfma_f32_16x16x32_bf16(aR[m], bR[n], acc[m][(nh_) * 2 + n], 0, 0, 0); \
    __builtin_amdgcn_s_setprio(0); } while (0)
    // prologue: tile0 full (buf0), tile1 khalf0 (buf1); counted wait leaves tile1 loads in flight
    SA_(0, 0, 0); SB_(0, 0, 0); SA_(0, 0, 1); SB_(0, 0, 1);
    SA_(1, 1, 0); SB_(1, 1, 0);
    asm volatile("s_waitcnt vmcnt(4)" ::: "memory");
    __builtin_amdgcn_s_barrier();
    for (int kt = 0; kt < 32; ++kt) {
        int cur = kt & 1, nb = cur ^ 1;
        bf16x8 aR[8], bR[2];
        // ---- ph(kh0, nh0): stage A[T+1]kh1 ----
        RDA(0, cur); RDB(0, 0, cur);
        if (kt + 1 < 32) SA_(nb, kt + 1, 1);
        __builtin_amdgcn_s_barrier();
        LGKM0;
        MMA(0);
        __builtin_amdgcn_s_barrier();
        // ---- ph(kh0, nh1): stage B[T+1]kh1 ----
        RDB(0, 1, cur);
        if (kt + 1 < 32) SB_(nb, kt + 1, 1);
        __builtin_amdgcn_s_barrier();
        LGKM0;
        MMA(1);
        __builtin_amdgcn_s_barrier();
        // ---- ph(kh1, nh0): stage A[T+2]kh0 into cur (freed after ph00) ----
        RDA(1, cur); RDB(1, 0, cur);
        if (kt + 2 < 32) SA_(cur, kt + 2, 0);
        __builtin_amdgcn_s_barrier();
        LGKM0;
        MMA(0);
        __builtin_amdgcn_s_barrier();
        // ---- ph(kh1, nh1): stage B[T+2]kh0 into cur (freed after ph01) ----
        RDB(1, 1, cur);
        if (kt + 2 < 32) SB_(cur, kt + 2, 0);
        __builtin_amdgcn_s_barrier();
        LGKM0;
        MMA(1);
        // per-tile checkpoint: counted, never drains (except tail)
        if (kt < 30) asm volatile("s_waitcnt vmcnt(4)" ::: "memory");
        else         asm volatile("s_waitcnt vmcnt(0)" ::: "memory");
        __builtin_amdgcn_s_barrier();
    }
#undef SA_
#undef SB_
#undef RDA
#undef RDB
#undef LGKM0
#undef MMA
    unsigned short* Sp = ST + (size_t)b * PW * PW;
#pragma unroll
    for (int m = 0; m < 8; ++m) {
        int row0 = i0 + wr * 128 + m * 16 + (kseg << 2);
#pragma unroll
        for (int n = 0; n < 4; ++n) {
            int col = j0 + wc * 64 + (n >> 1) * 32 + (n & 1) * 16 + l15;
#pragma unroll
            for (int q = 0; q < 4; ++q)
                Sp[(size_t)(row0 + q) * PW + col] = f2bf(acc[m][n][q]);
        }
    }
}

// ---- row softmax stats over ST rows ----
__global__ __launch_bounds__(256) void k_smrow(const unsigned short* __restrict__ ST,
                                               float* __restrict__ gm, float* __restrict__ gs) {
    int wid = threadIdx.x >> 6, lane = threadIdx.x & 63;
    int b = blockIdx.y;
    int i = blockIdx.x * 4 + wid;
    const unsigned short* rp = ST + (size_t)b * PW * PW + (size_t)i * PW;
    float vals[32];
    float m = -1e30f;
#pragma unroll
    for (int k = 0; k < 4; ++k) {
        int j0 = lane * 8 + k * 512;
        if (j0 < N_) {
            union { int4 v; unsigned short s[8]; } u;
            u.v = *(const int4*)(rp + j0);
#pragma unroll
            for (int e = 0; e < 8; ++e) {
                vals[k * 8 + e] = bf2f(u.s[e]);
                m = fmaxf(m, vals[k * 8 + e]);
            }
        } else {
#pragma unroll
            for (int e = 0; e < 8; ++e) vals[k * 8 + e] = -1e30f;
        }
    }
#pragma unroll
    for (int off = 32; off >= 1; off >>= 1) m = fmaxf(m, __shfl_xor(m, off));
    float s = 0.f;
#pragma unroll
    for (int k = 0; k < 32; ++k) s += __expf(vals[k] - m);
#pragma unroll
    for (int off = 32; off >= 1; off >>= 1) s += __shfl_xor(s, off);
    if (lane == 0) {
        gm[b * 2048 + i] = m;
        gs[b * 2048 + i] = 1.0f / s;
    }
}

// ---------------- MFMA GEMM (fused softmax-normalize in A-staging) ----------------
__global__ __launch_bounds__(512) void k_gemm_cheb_mfma(const unsigned short* __restrict__ chebT,
                                                        const unsigned short* __restrict__ ST,
                                                        const float* __restrict__ gm, const float* __restrict__ gs,
                                                        const unsigned short* __restrict__ xT,
                                                        unsigned short* __restrict__ h2) {
    int bk = blockIdx.y;
    int b = bk / 3, kk = bk % 3;
    int i0 = blockIdx.x * 128;
    const unsigned short* Ac = chebT + (size_t)kk * PW * PW;
    const unsigned short* Sa = ST + (size_t)b * PW * PW;
    const unsigned short* Bx = xT + (size_t)b * 384 * PW;
    __shared__ unsigned short As[2][4096];
    __shared__ unsigned short Bs[2][12288];
    int t = threadIdx.x, lane = t & 63, w = t >> 6;
    int wr = w >> 2, wc = w & 3;
    f32x4 acc[4][6];
#pragma unroll
    for (int a = 0; a < 4; ++a)
#pragma unroll
        for (int c = 0; c < 6; ++c)
#pragma unroll
            for (int q = 0; q < 4; ++q) acc[a][c][q] = 0.f;
    int arow = t >> 2, aq = t & 3;
    const unsigned short* gc = Ac + (size_t)(i0 + arow) * PW + aq * 8;
    const unsigned short* gsat = Sa + (size_t)(i0 + arow) * PW + aq * 8;
    float gmv = gm[b * 2048 + i0 + arow];
    float gsv = gs[b * 2048 + i0 + arow];
    int aoff = arow * 32 + (aq ^ (arow & 3)) * 8;
    int bseg = (t & 3) ^ ((t >> 2) & 3);
    const unsigned short* gB = Bx + (size_t)(t >> 2) * PW + bseg * 8;
    int ldso = w * 512;
#define STAGE_B(buf, p) do { \
    gload16(gB + (p), &Bs[buf][ldso]); \
    gload16(gB + 128 * PW + (p), &Bs[buf][4096 + ldso]); \
    gload16(gB + 256 * PW + (p), &Bs[buf][8192 + ldso]); \
} while (0)
    union U8 { int4 v; unsigned short s[8]; };
    U8 ca, sa;
    ca.v = *(const int4*)gc;
    sa.v = *(const int4*)gsat;
    STAGE_B(0, 0);
    {
        U8 o;
#pragma unroll
        for (int e = 0; e < 8; ++e) o.s[e] = f2bf(bf2f(ca.s[e]) * __expf(bf2f(sa.s[e]) - gmv) * gsv);
        *(int4*)&As[0][aoff] = o.v;
    }
    ca.v = *(const int4*)(gc + 32);
    sa.v = *(const int4*)(gsat + 32);
    __syncthreads();
    int cur = 0;
    int rswz = ((lane >> 4) ^ (lane & 3)) * 8;
    for (int p = 0; p < PW; p += 32) {
        if (p + 32 < PW) {
            STAGE_B(cur ^ 1, p + 32);
            U8 o;
#pragma unroll
            for (int e = 0; e < 8; ++e) o.s[e] = f2bf(bf2f(ca.s[e]) * __expf(bf2f(sa.s[e]) - gmv) * gsv);
            *(int4*)&As[cur ^ 1][aoff] = o.v;
            int pn = (p + 64 < PW) ? p + 64 : 0;
            ca.v = *(const int4*)(gc + pn);
            sa.v = *(const int4*)(gsat + pn);
        }
        bf16x8 af[4], bfr[6];
#pragma unroll
        for (int fm = 0; fm < 4; ++fm)
            af[fm] = *(const bf16x8*)&As[cur][(wr * 64 + fm * 16 + (lane & 15)) * 32 + rswz];
#pragma unroll
        for (int fn = 0; fn < 6; ++fn)
            bfr[fn] = *(const bf16x8*)&Bs[cur][(wc * 96 + fn * 16 + (lane & 15)) * 32 + rswz];
#pragma unroll
        for (int fm = 0; fm < 4; ++fm)
#pragma unroll
            for (int fn = 0; fn < 6; ++fn)
                acc[fm][fn] = __builtin_amdgcn_mfma_f32_16x16x32_bf16(af[fm], bfr[fn], acc[fm][fn], 0, 0, 0);
        __syncthreads();
        cur ^= 1;
    }
#undef STAGE_B
    unsigned short* hp = h2 + (size_t)bk * 768000;
#pragma unroll
    for (int fm = 0; fm < 4; ++fm) {
        int row0 = i0 + wr * 64 + fm * 16 + ((lane >> 4) << 2);
#pragma unroll
        for (int fn = 0; fn < 6; ++fn) {
            int col = wc * 96 + fn * 16 + (lane & 15);
#pragma unroll
            for (int q = 0; q < 4; ++q) {
                int row = row0 + q;
                if (row < N_) hp[(size_t)row * 384 + col] = f2bf(acc[fm][fn][q]);
            }
        }
    }
}

// ---------------- fused tail: theta mix + time conv + residual + relu + LayerNorm ----------------
__global__ __launch_bounds__(512) void k_final3(const float* __restrict__ x, const unsigned short* __restrict__ h2,
                                                const float* __restrict__ ThetaG,
                                                const float* __restrict__ tcwT, const float* __restrict__ tc_b,
                                                const float* __restrict__ rcwT, const float* __restrict__ rc_b,
                                                const float* __restrict__ ln_g, const float* __restrict__ ln_b,
                                                float* __restrict__ out) {
    __shared__ __align__(16) char smem[110848];
    unsigned int* gl = (unsigned int*)smem;
    unsigned short* th = (unsigned short*)(smem + 98560);
    float* red_s = (float*)(smem + 98560);
    float* red_q = red_s + 64 * 13;

    int tid = threadIdx.x;
    int n_l = tid & 63, fg = tid >> 6;
    int b = blockIdx.y;
    int node = blockIdx.x * 64 + n_l;
    bool ok = node < N_;
    int nd = ok ? node : N_ - 1;

    for (int q = tid; q < 6144; q += 512) th[q] = f2bf(ThetaG[q]);
    __syncthreads();

    float acc[8][12];
#pragma unroll
    for (int ff = 0; ff < 8; ++ff)
#pragma unroll
        for (int t = 0; t < 12; ++t) acc[ff][t] = 0.f;
    const unsigned short* hb = h2 + (size_t)b * 3 * 768000 + (size_t)nd * 384;
#pragma unroll
    for (int kk = 0; kk < 3; ++kk) {
        const unsigned short* hp = hb + (size_t)kk * 768000;
#pragma unroll 2
        for (int c = 0; c < 32; ++c) {
            const unsigned short* hq = hp + c * 12;
            uint2 u0 = *(const uint2*)(hq);
            uint2 u1 = *(const uint2*)(hq + 4);
            uint2 u2 = *(const uint2*)(hq + 8);
            float h[12];
            h[0] = bf2f((unsigned short)u0.x);  h[1] = bf2f((unsigned short)(u0.x >> 16));
            h[2] = bf2f((unsigned short)u0.y);  h[3] = bf2f((unsigned short)(u0.y >> 16));
            h[4] = bf2f((unsigned short)u1.x);  h[5] = bf2f((unsigned short)(u1.x >> 16));
            h[6] = bf2f((unsigned short)u1.y);  h[7] = bf2f((unsigned short)(u1.y >> 16));
            h[8] = bf2f((unsigned short)u2.x);  h[9] = bf2f((unsigned short)(u2.x >> 16));
            h[10] = bf2f((unsigned short)u2.y); h[11] = bf2f((unsigned short)(u2.y >> 16));
            const unsigned short* wv = th + (kk * 32 + c) * 64 + fg * 8;
            uint2 w01 = *(const uint2*)wv;
            uint2 w23 = *(const uint2*)(wv + 4);
            float wf[8];
            wf[0] = bf2f((unsigned short)w01.x); wf[1] = bf2f((unsigned short)(w01.x >> 16));
            wf[2] = bf2f((unsigned short)w01.y); wf[3] = bf2f((unsigned short)(w01.y >> 16));
            wf[4] = bf2f((unsigned short)w23.x); wf[5] = bf2f((unsigned short)(w23.x >> 16));
            wf[6] = bf2f((unsigned short)w23.y); wf[7] = bf2f((unsigned short)(w23.y >> 16));
#pragma unroll
            for (int ff = 0; ff < 8; ++ff)
#pragma unroll
                for (int t = 0; t < 12; ++t) acc[ff][t] = fmaf(h[t], wf[ff], acc[ff][t]);
        }
    }
    unsigned int* gr = gl + n_l * 385 + fg * 48;
#pragma unroll
    for (int ff = 0; ff < 8; ++ff)
#pragma unroll
        for (int tp = 0; tp < 6; ++tp) {
            float a0 = fmaxf(acc[ff][2 * tp], 0.f), a1 = fmaxf(acc[ff][2 * tp + 1], 0.f);
            gr[ff * 6 + tp] = (unsigned int)f2bf(a0) | ((unsigned int)f2bf(a1) << 16);
        }
    __syncthreads();

    float z[8][12];
#pragma unroll
    for (int ff = 0; ff < 8; ++ff) {
        float bias = tc_b[fg * 8 + ff] + rc_b[fg * 8 + ff];
#pragma unroll
        for (int t = 0; t < 12; ++t) z[ff][t] = bias;
    }
    const float* xp = x + (size_t)(b * 2000 + nd) * 384;
#pragma unroll 2
    for (int c = 0; c < 32; ++c) {
        float4 x0 = *(const float4*)(xp + c * 12);
        float4 x1 = *(const float4*)(xp + c * 12 + 4);
        float4 x2 = *(const float4*)(xp + c * 12 + 8);
        float xv[12] = {x0.x, x0.y, x0.z, x0.w, x1.x, x1.y, x1.z, x1.w, x2.x, x2.y, x2.z, x2.w};
        float4 r0 = *(const float4*)(rcwT + c * 64 + fg * 8);
        float4 r1 = *(const float4*)(rcwT + c * 64 + fg * 8 + 4);
        float rw[8] = {r0.x, r0.y, r0.z, r0.w, r1.x, r1.y, r1.z, r1.w};
#pragma unroll
        for (int ff = 0; ff < 8; ++ff)
#pragma unroll
            for (int t = 0; t < 12; ++t) z[ff][t] = fmaf(xv[t], rw[ff], z[ff][t]);
    }
    const unsigned int* grow = gl + n_l * 385;
    for (int fi = 0; fi < 64; ++fi) {
        float g[12];
#pragma unroll
        for (int j = 0; j < 6; ++j) {
            unsigned int u = grow[fi * 6 + j];
            g[2 * j] = bf2f((unsigned short)u);
            g[2 * j + 1] = bf2f((unsigned short)(u >> 16));
        }
        const float* wp = tcwT + (fi * 64 + fg * 8) * 3;
        float4 w0 = *(const float4*)(wp);
        float4 w1 = *(const float4*)(wp + 4);
        float4 w2 = *(const float4*)(wp + 8);
        float4 w3 = *(const float4*)(wp + 12);
        float4 w4 = *(const float4*)(wp + 16);
        float4 w5 = *(const float4*)(wp + 20);
        float wb[24] = {w0.x, w0.y, w0.z, w0.w, w1.x, w1.y, w1.z, w1.w,
                        w2.x, w2.y, w2.z, w2.w, w3.x, w3.y, w3.z, w3.w,
                        w4.x, w4.y, w4.z, w4.w, w5.x, w5.y, w5.z, w5.w};
#pragma unroll
        for (int ff = 0; ff < 8; ++ff) {
            float a0 = wb[ff * 3], a1 = wb[ff * 3 + 1], a2 = wb[ff * 3 + 2];
            z[ff][0] = fmaf(g[0], a1, fmaf(g[1], a2, z[ff][0]));
#pragma unroll
            for (int t = 1; t < 11; ++t)
                z[ff][t] = fmaf(g[t - 1], a0, fmaf(g[t], a1, fmaf(g[t + 1], a2, z[ff][t])));
            z[ff][11] = fmaf(g[10], a0, fmaf(g[11], a1, z[ff][11]));
        }
    }
#pragma unroll
    for (int ff = 0; ff < 8; ++ff)
#pragma unroll
        for (int t = 0; t < 12; ++t) z[ff][t] = fmaxf(z[ff][t], 0.f);

    float s[12], q[12];
#pragma unroll
    for (int t = 0; t < 12; ++t) { s[t] = 0.f; q[t] = 0.f; }
#pragma unroll
    for (int ff = 0; ff < 8; ++ff)
#pragma unroll
        for (int t = 0; t < 12; ++t) { s[t] += z[ff][t]; q[t] += z[ff][t] * z[ff][t]; }
    __syncthreads();
    for (int g = 0; g < 8; ++g) {
        if (fg == g) {
            if (g == 0) {
#pragma unroll
                for (int t = 0; t < 12; ++t) { red_s[n_l * 13 + t] = s[t]; red_q[n_l * 13 + t] = q[t]; }
            } else {
#pragma unroll
                for (int t = 0; t < 12; ++t) { red_s[n_l * 13 + t] += s[t]; red_q[n_l * 13 + t] += q[t]; }
            }
        }
        __syncthreads();
    }
    float mu[12], rs[12];
#pragma unroll
    for (int t = 0; t < 12; ++t) {
        float m = red_s[n_l * 13 + t] * (1.0f / 64.0f);
        float v = red_q[n_l * 13 + t] * (1.0f / 64.0f) - m * m;
        mu[t] = m;
        rs[t] = rsqrtf(v + 1e-5f);
    }
    if (ok) {
        float* op = out + ((size_t)(b * 2000 + node) * 64 + fg * 8) * 12;
#pragma unroll
        for (int ff = 0; ff < 8; ++ff) {
            float lg = ln_g[fg * 8 + ff], lb = ln_b[fg * 8 + ff];
            float o[12];
#pragma unroll
            for (int t = 0; t < 12; ++t) o[t] = (z[ff][t] - mu[t]) * rs[t] * lg + lb;
#pragma unroll
            for (int tq = 0; tq < 3; ++tq)
                *(float4*)(op + ff * 12 + tq * 4) = make_float4(o[tq * 4], o[tq * 4 + 1], o[tq * 4 + 2], o[tq * 4 + 3]);
        }
    }
}

extern "C" void kernel_launch(void* const* d_in, const int* in_sizes, int n_in,
                              void* d_out, int out_size, void* d_ws, size_t ws_size,
                              hipStream_t stream) {
    const float* x     = (const float*)d_in[0];
    const float* cheb  = (const float*)d_in[1];
    const float* U1    = (const float*)d_in[2];
    const float* U2    = (const float*)d_in[3];
    const float* U3    = (const float*)d_in[4];
    const float* be    = (const float*)d_in[5];
    const float* Ve    = (const float*)d_in[6];
    const float* W1    = (const float*)d_in[7];
    const float* W2    = (const float*)d_in[8];
    const float* W3    = (const float*)d_in[9];
    const float* bs    = (const float*)d_in[10];
    const float* Vs    = (const float*)d_in[11];
    const float* Theta = (const float*)d_in[12];
    const float* tc_w  = (const float*)d_in[13];
    const float* tc_b  = (const float*)d_in[14];
    const float* rc_w  = (const float*)d_in[15];
    const float* rc_b  = (const float*)d_in[16];
    const float* ln_g  = (const float*)d_in[17];
    const float* ln_b  = (const float*)d_in[18];
    float* out = (float*)d_out;

    // ---- workspace layout (~184.3 MB, identical to rounds 8-11) ----
    float* ws    = (float*)d_ws;
    float* At    = ws;
    float* lhs1  = ws + 1152;
    float* lhsT  = ws + 4224;
    float* rhsT  = ws + 196224;
    float* lhs_s = ws + 388224;
    float* rhs_s = ws + 580224;
    float* gm    = ws + 772224;
    float* gs    = ws + 788608;
    float* tcwT  = ws + 804992;
    float* rcwT  = ws + 817280;
    float* plh   = ws + 819328;
    float* pP    = ws + 972928;
    unsigned short* Vsb   = (unsigned short*)(ws + 991360);
    unsigned short* chebT = (unsigned short*)(ws + 3088512);
    unsigned short* xT    = (unsigned short*)(ws + 9379968);
    unsigned short* sigT  = (unsigned short*)(ws + 12525696);  // dead after gemm_S
    unsigned short* h2    = sigT;                              // reuse after gemm_S
    unsigned short* STb   = (unsigned short*)(ws + 29302912);

    // prep
    k_wprep<<<56, 256, 0, stream>>>(tc_w, rc_w, tcwT, rcwT);
    k_vsb<<<2048, 256, 0, stream>>>(Vs, Vsb);
    k_chebT<<<dim3(32, 32, 3), 256, 0, stream>>>(cheb, chebT);
    k_xT<<<dim3(32, 6, 8), 256, 0, stream>>>(x, xT);
    // temporal attention
    k_tprep<<<dim3(50, 8), 256, 0, stream>>>(x, U1, U3, rhsT, plh);
    k_tred<<<8, 256, 0, stream>>>(plh, lhs1);
    k_lhsT<<<750, 256, 0, stream>>>(lhs1, U2, lhsT);
    k_tatt1<<<dim3(16, 8), 256, 0, stream>>>(lhsT, rhsT, pP);
    k_tatt2<<<8, 256, 0, stream>>>(pP, be, Ve, At);
    k_xsp<<<dim3(250, 8), 256, 0, stream>>>(x, At, W1, W2, W3, lhs_s, rhs_s);
    // spatial attention (S^T directly)
    k_sig<<<dim3(32, 32, 8), 256, 0, stream>>>(lhs_s, rhs_s, bs, sigT);
    k_gemm_S_mfma<<<dim3(8, 8, 8), 512, 0, stream>>>(Vsb, sigT, STb);
    k_smrow<<<dim3(512, 8), 256, 0, stream>>>(STb, gm, gs);
    // chebyshev gcn with fused softmax normalization
    k_gemm_cheb_mfma<<<dim3(16, 24), 512, 0, stream>>>(chebT, STb, gm, gs, xT, h2);
    // fused theta + conv + LN tail
    k_final3<<<dim3(32, 8), 512, 0, stream>>>(x, h2, Theta, tcwT, tc_b, rcwT, rc_b, ln_g, ln_b, out);
}

// Round 13
// 602.269 us; speedup vs baseline: 1.0716x; 1.0022x over previous
//
#include <hip/hip_runtime.h>
#include <hip/hip_bf16.h>
#include <math.h>

#define B_ 8
#define N_ 2000
#define C_ 32
#define T_ 12
#define K_ 3
#define FC_ 64
#define FT_ 64
#define PW 2048   // padded width (K and row pads, zero-filled)

typedef short bf16x8 __attribute__((ext_vector_type(8)));
typedef float f32x4 __attribute__((ext_vector_type(4)));

__device__ __forceinline__ float sigmoidf(float v) { return 1.0f / (1.0f + __expf(-v)); }
__device__ __forceinline__ float bf2f(unsigned short u) {
    union { unsigned int i; float f; } v; v.i = ((unsigned int)u) << 16; return v.f;
}
__device__ __forceinline__ unsigned short f2bf(float f) {
    union { __hip_bfloat16 h; unsigned short u; } v; v.h = __float2bfloat16(f); return v.u;
}
typedef const __attribute__((address_space(1))) void* gas_t;
typedef __attribute__((address_space(3))) void* las_t;
__device__ __forceinline__ void gload16(const unsigned short* g, unsigned short* l) {
    __builtin_amdgcn_global_load_lds((gas_t)g, (las_t)l, 16, 0, 0);
}

// ---------------- fused x-pass: lhs1 partials + rhsT ----------------
__global__ __launch_bounds__(256) void k_tprep(const float* __restrict__ x, const float* __restrict__ U1,
                                               const float* __restrict__ U3,
                                               float* __restrict__ rhsT, float* __restrict__ plh) {
    int b = blockIdx.y, chunk = blockIdx.x;
    int tid = threadIdx.x;
    int nl = tid >> 5, c = tid & 31;
    int w = tid >> 6;
    float u3 = U3[c];
    float plA[12];
#pragma unroll
    for (int t = 0; t < 12; ++t) plA[t] = 0.f;
    for (int it = 0; it < 5; ++it) {
        int n = chunk * 40 + it * 8 + nl;
        const float* xp = x + ((size_t)(b * 2000 + n) * 32 + c) * 12;
        float4 v0 = *(const float4*)xp, v1 = *(const float4*)(xp + 4), v2 = *(const float4*)(xp + 8);
        float xv[12] = {v0.x, v0.y, v0.z, v0.w, v1.x, v1.y, v1.z, v1.w, v2.x, v2.y, v2.z, v2.w};
        float rv[12];
#pragma unroll
        for (int t = 0; t < 12; ++t) rv[t] = u3 * xv[t];
#pragma unroll
        for (int off = 16; off >= 1; off >>= 1)
#pragma unroll
            for (int t = 0; t < 12; ++t) rv[t] += __shfl_xor(rv[t], off);
        if (c == 0) {
#pragma unroll
            for (int t = 0; t < 12; ++t) rhsT[(size_t)(b * 2000 + n) * 12 + t] = rv[t];
        }
        float u1 = U1[n];
#pragma unroll
        for (int t = 0; t < 12; ++t) plA[t] += u1 * xv[t];
    }
#pragma unroll
    for (int t = 0; t < 12; ++t) plA[t] += __shfl_xor(plA[t], 32);
    __shared__ float accs[4][32][12];
    if ((tid & 63) < 32) {
#pragma unroll
        for (int t = 0; t < 12; ++t) accs[w][c][t] = plA[t];
    }
    __syncthreads();
    if (tid < 384) {
        int c2 = tid / 12, t2 = tid % 12;
        float s = accs[0][c2][t2] + accs[1][c2][t2] + accs[2][c2][t2] + accs[3][c2][t2];
        plh[((size_t)(b * 50 + chunk)) * 384 + tid] = s;
    }
}

__global__ __launch_bounds__(256) void k_tred(const float* __restrict__ plh, float* __restrict__ lhs1) {
    int b = blockIdx.x;
    for (int q = threadIdx.x; q < 384; q += 256) {
        const float* p = plh + (size_t)b * 50 * 384 + q;
        float s = 0.f;
        for (int ch = 0; ch < 50; ++ch) s += p[(size_t)ch * 384];
        int c = q / 12, t = q % 12;
        lhs1[(b * 12 + t) * 32 + c] = s;
    }
}

__global__ __launch_bounds__(256) void k_lhsT(const float* __restrict__ lhs1, const float* __restrict__ U2,
                                              float* __restrict__ lhsT) {
    int gid = blockIdx.x * 256 + threadIdx.x;
    if (gid >= B_ * T_ * N_) return;
    int n = gid % N_;
    int bt = gid / N_;
    const float* l1 = lhs1 + bt * C_;
    float a = 0.f;
#pragma unroll
    for (int c = 0; c < C_; ++c) a += l1[c] * U2[c * N_ + n];
    lhsT[gid] = a;
}

__global__ __launch_bounds__(256) void k_tatt1(const float* __restrict__ lhsT, const float* __restrict__ rhsT,
                                               float* __restrict__ pP) {
    int b = blockIdx.y, ch = blockIdx.x;
    int tid = threadIdx.x;
    int n0 = ch * 125;
    __shared__ float sL[12][128];
    __shared__ float sR[128][12];
    for (int q = tid; q < 12 * 125; q += 256) {
        int t = q / 125, nn = q % 125;
        sL[t][nn] = lhsT[(size_t)(b * 12 + t) * 2000 + n0 + nn];
    }
    for (int q = tid; q < 125 * 12; q += 256) {
        int nn = q / 12, t = q % 12;
        sR[nn][t] = rhsT[(size_t)(b * 2000 + n0 + nn) * 12 + t];
    }
    __syncthreads();
    if (tid < 144) {
        int tP = tid / 12, uP = tid % 12;
        float a = 0.f;
#pragma unroll 5
        for (int nn = 0; nn < 125; ++nn) a += sL[tP][nn] * sR[nn][uP];
        pP[(size_t)(b * 16 + ch) * 144 + tid] = a;
    }
}

__global__ __launch_bounds__(256) void k_tatt2(const float* __restrict__ pP, const float* __restrict__ be,
                                               const float* __restrict__ Ve, float* __restrict__ At) {
    int b = blockIdx.x, tid = threadIdx.x;
    __shared__ float sp[144], sE[144], mk[12], sk[12];
    int tP = tid / 12, uP = tid % 12;
    if (tid < 144) {
        float a = 0.f;
#pragma unroll
        for (int ch = 0; ch < 16; ++ch) a += pP[(size_t)(b * 16 + ch) * 144 + tid];
        sp[tid] = sigmoidf(a + be[tid]);
    }
    __syncthreads();
    if (tid < 144) {
        float e = 0.f;
#pragma unroll
        for (int j = 0; j < 12; ++j) e += Ve[tP * 12 + j] * sp[j * 12 + uP];
        sE[tid] = e;
    }
    __syncthreads();
    if (tid < 12) {
        float m = -1e30f;
#pragma unroll
        for (int i = 0; i < 12; ++i) m = fmaxf(m, sE[i * 12 + tid]);
        float s = 0.f;
#pragma unroll
        for (int i = 0; i < 12; ++i) s += __expf(sE[i * 12 + tid] - m);
        mk[tid] = m; sk[tid] = 1.0f / s;
    }
    __syncthreads();
    if (tid < 144) At[b * 144 + tid] = __expf(sE[tid] - mk[uP]) * sk[uP];
}

__global__ __launch_bounds__(256) void k_xsp(const float* __restrict__ x, const float* __restrict__ At,
                                             const float* __restrict__ W1, const float* __restrict__ W2,
                                             const float* __restrict__ W3,
                                             float* __restrict__ lhs_s, float* __restrict__ rhs_s) {
    int b = blockIdx.y, chunk = blockIdx.x;
    int tid = threadIdx.x, nl = tid >> 5, c = tid & 31;
    int n = chunk * 8 + nl;
    __shared__ float atl[144];
    __shared__ float w2l[384];
    __shared__ float w1l[12];
    if (tid < 144) atl[tid] = At[b * 144 + tid];
    if (tid >= 144 && tid < 156) w1l[tid - 144] = W1[tid - 144];
    for (int q = tid; q < 384; q += 256) w2l[q] = W2[q];
    __syncthreads();
    const float* xp = x + ((size_t)(b * 2000 + n) * 32 + c) * 12;
    float4 v0 = *(const float4*)xp, v1 = *(const float4*)(xp + 4), v2 = *(const float4*)(xp + 8);
    float xv[12] = {v0.x, v0.y, v0.z, v0.w, v1.x, v1.y, v1.z, v1.w, v2.x, v2.y, v2.z, v2.w};
    float xa[12];
#pragma unroll
    for (int t = 0; t < 12; ++t) {
        float s = 0.f;
#pragma unroll
        for (int u = 0; u < 12; ++u) s += xv[u] * atl[u * 12 + t];
        xa[t] = s;
    }
    float w3 = W3[c];
    float rv[12], lv[12];
    float l1 = 0.f;
#pragma unroll
    for (int t = 0; t < 12; ++t) l1 += xa[t] * w1l[t];
#pragma unroll
    for (int t = 0; t < 12; ++t) { rv[t] = w3 * xa[t]; lv[t] = l1 * w2l[c * 12 + t]; }
#pragma unroll
    for (int off = 16; off >= 1; off >>= 1)
#pragma unroll
        for (int t = 0; t < 12; ++t) { rv[t] += __shfl_xor(rv[t], off); lv[t] += __shfl_xor(lv[t], off); }
    if (c == 0) {
#pragma unroll
        for (int t = 0; t < 12; ++t) rhs_s[(size_t)(b * 12 + t) * 2000 + n] = rv[t];
#pragma unroll
        for (int t = 0; t < 12; ++t) lhs_s[(size_t)(b * 2000 + n) * 12 + t] = lv[t];
    }
}

// ---------------- weight transposes ----------------
__global__ __launch_bounds__(256) void k_wprep(const float* __restrict__ tc_w, const float* __restrict__ rc_w,
                                               float* __restrict__ tcwT, float* __restrict__ rcwT) {
    int gid = blockIdx.x * 256 + threadIdx.x;
    if (gid < 12288) {
        int fi = gid / 192, rem = gid % 192, f = rem / 3, d = rem % 3;
        tcwT[gid] = tc_w[(f * 64 + fi) * 3 + d];
    } else if (gid < 14336) {
        int q = gid - 12288;
        int c = q >> 6, f = q & 63;
        rcwT[q] = rc_w[f * 32 + c];
    }
}

// ---------------- conversions / transposes (padded to PW, zero-filled) ----------------
__global__ __launch_bounds__(256) void k_vsb(const float* __restrict__ Vs, unsigned short* __restrict__ Vsb) {
    int gid = blockIdx.x * 256 + threadIdx.x;
    int row = gid >> 8, chunk = gid & 255;
    int p0 = chunk * 8;
    unsigned short o[8];
#pragma unroll
    for (int e = 0; e < 8; ++e) {
        int p = p0 + e;
        o[e] = (row < N_ && p < N_) ? f2bf(Vs[row * N_ + p]) : (unsigned short)0;
    }
    *(int4*)(Vsb + (size_t)row * PW + p0) = *(int4*)o;
}

__global__ __launch_bounds__(256) void k_chebT(const float* __restrict__ cheb, unsigned short* __restrict__ chebT) {
    int j0 = blockIdx.x * 64, i0 = blockIdx.y * 64, kk = blockIdx.z;
    __shared__ float Tl[64][65];
    int t = threadIdx.x;
    int rr = t >> 2, c0 = (t & 3) * 16;
    int j = j0 + rr;
#pragma unroll
    for (int e = 0; e < 16; ++e) {
        int i = i0 + c0 + e;
        Tl[rr][c0 + e] = (j < N_ && i < N_) ? cheb[(size_t)kk * 4000000 + (size_t)j * N_ + i] : 0.f;
    }
    __syncthreads();
    int l = t & 63, w = t >> 6;
    unsigned short o[16];
#pragma unroll
    for (int e = 0; e < 16; ++e) o[e] = f2bf(Tl[w * 16 + e][l]);
    unsigned short* dst = chebT + (size_t)kk * PW * PW + (size_t)(i0 + l) * PW + j0 + w * 16;
    *(int4*)dst = *(int4*)o;
    *(int4*)(dst + 8) = *(int4*)(o + 8);
}

__global__ __launch_bounds__(256) void k_xT(const float* __restrict__ x, unsigned short* __restrict__ xT) {
    int j0 = blockIdx.x * 64, r0 = blockIdx.y * 64, b = blockIdx.z;
    __shared__ float Tl[64][65];
    int t = threadIdx.x;
    int rr = t >> 2, c0 = (t & 3) * 16;
    int j = j0 + rr;
#pragma unroll
    for (int e = 0; e < 16; ++e) {
        int r = r0 + c0 + e;
        Tl[rr][c0 + e] = (j < N_) ? x[(size_t)(b * N_ + j) * 384 + r] : 0.f;
    }
    __syncthreads();
    int l = t & 63, w = t >> 6;
    unsigned short o[16];
#pragma unroll
    for (int e = 0; e < 16; ++e) o[e] = f2bf(Tl[w * 16 + e][l]);
    unsigned short* dst = xT + (size_t)b * 384 * PW + (size_t)(r0 + l) * PW + j0 + w * 16;
    *(int4*)dst = *(int4*)o;
    *(int4*)(dst + 8) = *(int4*)(o + 8);
}

__global__ __launch_bounds__(256) void k_sig(const float* __restrict__ lhs_s, const float* __restrict__ rhs_s,
                                             const float* __restrict__ bs, unsigned short* __restrict__ sigT) {
    int p0 = blockIdx.x * 64, i0 = blockIdx.y * 64, b = blockIdx.z;
    __shared__ float sL[64][12];
    __shared__ float sR[12][64];
    __shared__ float bsl[64][65];
    int t = threadIdx.x;
    for (int q = t; q < 768; q += 256) {
        int pp = q / 12, tt = q % 12;
        int p = p0 + pp;
        sL[pp][tt] = (p < N_) ? lhs_s[(b * N_ + p) * 12 + tt] : 0.f;
    }
    for (int q = t; q < 768; q += 256) {
        int tt = q >> 6, ii = q & 63;
        int i = i0 + ii;
        sR[tt][ii] = (i < N_) ? rhs_s[b * (T_ * N_) + tt * N_ + i] : 0.f;
    }
    {
        int pp = t >> 2, c0 = (t & 3) * 16;
        int p = p0 + pp;
        if (p < N_ && i0 + c0 + 15 < N_) {
            const float* src = bs + (size_t)p * N_ + i0 + c0;
#pragma unroll
            for (int e = 0; e < 16; e += 4) *(float4*)&bsl[pp][c0 + e] = *(const float4*)(src + e);
        } else {
#pragma unroll
            for (int e = 0; e < 16; ++e) {
                int i = i0 + c0 + e;
                bsl[pp][c0 + e] = (p < N_ && i < N_) ? bs[(size_t)p * N_ + i] : 0.f;
            }
        }
    }
    __syncthreads();
    int ii = t & 63, w = t >> 6;
    int i = i0 + ii;
    unsigned short o[16];
#pragma unroll
    for (int e = 0; e < 16; ++e) {
        int pl = w * 16 + e;
        int p = p0 + pl;
        float v = 0.f;
        if (p < N_ && i < N_) {
            float d = bsl[pl][ii];
#pragma unroll
            for (int tt = 0; tt < 12; ++tt) d += sL[pl][tt] * sR[tt][ii];
            v = sigmoidf(d);
        }
        o[e] = f2bf(v);
    }
    unsigned short* dst = sigT + (size_t)b * PW * PW + (size_t)i * PW + p0 + w * 16;
    *(int4*)dst = *(int4*)o;
    *(int4*)(dst + 8) = *(int4*)(o + 8);
}

// ---------------- MFMA GEMM 256x256, BK=64, K-half staged, counted vmcnt pipeline ----------------
// ST[i][j] = sum_p sigT[i][p] * Vsb[j][p]
#define FR_(R) (((R) ^ ((R) >> 2)) & 3)
__global__ __launch_bounds__(512) void k_gemm_S_mfma(const unsigned short* __restrict__ Vsb,
                                                     const unsigned short* __restrict__ sigT,
                                                     unsigned short* __restrict__ ST) {
    int lid = blockIdx.x + (blockIdx.y << 3) + (blockIdx.z << 6);
    int swz = (lid & 7) * 64 + (lid >> 3);
    int j0 = (swz & 7) * 256;
    int i0 = ((swz >> 3) & 7) * 256;
    int b = swz >> 6;
    const unsigned short* Ap = sigT + (size_t)b * PW * PW;
    __shared__ unsigned short As[2][2][8192];   // [buf][khalf][256 rows x 32 elems]
    __shared__ unsigned short Bs[2][2][8192];
    int t = threadIdx.x, lane = t & 63, w = t >> 6;
    int wr = w >> 2, wc = w & 3;                // wave: rows wr*128, cols wc*64
    int l15 = lane & 15, kseg = lane >> 4;
    f32x4 acc[8][4];
#pragma unroll
    for (int m = 0; m < 8; ++m)
#pragma unroll
        for (int n = 0; n < 4; ++n)
#pragma unroll
            for (int q = 0; q < 4; ++q) acc[m][n][q] = 0.f;
    int srow = t >> 2;
    int gchunk = ((t & 3) ^ FR_(srow)) * 8;
    const unsigned short* gA = Ap + (size_t)(i0 + srow) * PW + gchunk;
    const unsigned short* gB = Vsb + (size_t)(j0 + srow) * PW + gchunk;
    int ldw = w * 512;
#define SA_(buf_, kt_, kh_) do { \
    gload16(gA + (size_t)(kt_) * 64 + (kh_) * 32, &As[buf_][kh_][ldw]); \
    gload16(gA + (size_t)128 * PW + (size_t)(kt_) * 64 + (kh_) * 32, &As[buf_][kh_][4096 + ldw]); \
} while (0)
#define SB_(buf_, kt_, kh_) do { \
    gload16(gB + (size_t)(kt_) * 64 + (kh_) * 32, &Bs[buf_][kh_][ldw]); \
    gload16(gB + (size_t)128 * PW + (size_t)(kt_) * 64 + (kh_) * 32, &Bs[buf_][kh_][4096 + ldw]); \
} while (0)
#define RDA(kh_, buf_) { _Pragma("unroll") for (int m = 0; m < 8; ++m) { \
    int R = wr * 128 + m * 16 + l15; \
    aR[m] = *(const bf16x8*)&As[buf_][kh_][R * 32 + ((kseg ^ FR_(R)) << 3)]; } }
#define RDB(kh_, nh_, buf_) { _Pragma("unroll") for (int n = 0; n < 2; ++n) { \
    int R = wc * 64 + (nh_) * 32 + n * 16 + l15; \
    bR[n] = *(const bf16x8*)&Bs[buf_][kh_][R * 32 + ((kseg ^ FR_(R)) << 3)]; } }
#define LGKM0 do { asm volatile("s_waitcnt lgkmcnt(0)" ::: "memory"); __builtin_amdgcn_sched_barrier(0); } while (0)
#define MMA(nh_) do { __builtin_amdgcn_s_setprio(1); \
    _Pragma("unroll") for (int m = 0; m < 8; ++m) \
    _Pragma("unroll") for (int n = 0; n < 2; ++n) \
        acc[m][(nh_) * 2 + n] = __builtin_amdgcn_mfma_f32_16x16x32_bf16(aR[m], bR[n], acc[m][(nh_) * 2 + n], 0, 0, 0); \
    __builtin_amdgcn_s_setprio(0); } while (0)
    SA_(0, 0, 0); SB_(0, 0, 0); SA_(0, 0, 1); SB_(0, 0, 1);
    SA_(1, 1, 0); SB_(1, 1, 0);
    asm volatile("s_waitcnt vmcnt(4)" ::: "memory");
    __builtin_amdgcn_s_barrier();
    for (int kt = 0; kt < 32; ++kt) {
        int cur = kt & 1, nb = cur ^ 1;
        bf16x8 aR[8], bR[2];
        RDA(0, cur); RDB(0, 0, cur);
        if (kt + 1 < 32) SA_(nb, kt + 1, 1);
        __builtin_amdgcn_s_barrier();
        LGKM0;
        MMA(0);
        __builtin_amdgcn_s_barrier();
        RDB(0, 1, cur);
        if (kt + 1 < 32) SB_(nb, kt + 1, 1);
        __builtin_amdgcn_s_barrier();
        LGKM0;
        MMA(1);
        __builtin_amdgcn_s_barrier();
        RDA(1, cur); RDB(1, 0, cur);
        if (kt + 2 < 32) SA_(cur, kt + 2, 0);
        __builtin_amdgcn_s_barrier();
        LGKM0;
        MMA(0);
        __builtin_amdgcn_s_barrier();
        RDB(1, 1, cur);
        if (kt + 2 < 32) SB_(cur, kt + 2, 0);
        __builtin_amdgcn_s_barrier();
        LGKM0;
        MMA(1);
        if (kt < 30) asm volatile("s_waitcnt vmcnt(4)" ::: "memory");
        else         asm volatile("s_waitcnt vmcnt(0)" ::: "memory");
        __builtin_amdgcn_s_barrier();
    }
#undef SA_
#undef SB_
#undef RDA
#undef RDB
#undef LGKM0
#undef MMA
    unsigned short* Sp = ST + (size_t)b * PW * PW;
#pragma unroll
    for (int m = 0; m < 8; ++m) {
        int row0 = i0 + wr * 128 + m * 16 + (kseg << 2);
#pragma unroll
        for (int n = 0; n < 4; ++n) {
            int col = j0 + wc * 64 + (n >> 1) * 32 + (n & 1) * 16 + l15;
#pragma unroll
            for (int q = 0; q < 4; ++q)
                Sp[(size_t)(row0 + q) * PW + col] = f2bf(acc[m][n][q]);
        }
    }
}

// ---- row softmax stats over ST rows ----
__global__ __launch_bounds__(256) void k_smrow(const unsigned short* __restrict__ ST,
                                               float* __restrict__ gm, float* __restrict__ gs) {
    int wid = threadIdx.x >> 6, lane = threadIdx.x & 63;
    int b = blockIdx.y;
    int i = blockIdx.x * 4 + wid;
    const unsigned short* rp = ST + (size_t)b * PW * PW + (size_t)i * PW;
    float vals[32];
    float m = -1e30f;
#pragma unroll
    for (int k = 0; k < 4; ++k) {
        int j0 = lane * 8 + k * 512;
        if (j0 < N_) {
            union { int4 v; unsigned short s[8]; } u;
            u.v = *(const int4*)(rp + j0);
#pragma unroll
            for (int e = 0; e < 8; ++e) {
                vals[k * 8 + e] = bf2f(u.s[e]);
                m = fmaxf(m, vals[k * 8 + e]);
            }
        } else {
#pragma unroll
            for (int e = 0; e < 8; ++e) vals[k * 8 + e] = -1e30f;
        }
    }
#pragma unroll
    for (int off = 32; off >= 1; off >>= 1) m = fmaxf(m, __shfl_xor(m, off));
    float s = 0.f;
#pragma unroll
    for (int k = 0; k < 32; ++k) s += __expf(vals[k] - m);
#pragma unroll
    for (int off = 32; off >= 1; off >>= 1) s += __shfl_xor(s, off);
    if (lane == 0) {
        gm[b * 2048 + i] = m;
        gs[b * 2048 + i] = 1.0f / s;
    }
}

// ---------------- MFMA GEMM cheb: K-half counted pipeline, reg-staged A (exp-normalize fused) ----------------
// h2[i][r] = sum_j chebT[i][j]*exp(ST[i][j]-gm[i])*gs[i] * xT[r][j]
__global__ __launch_bounds__(512) void k_gemm_cheb_mfma(const unsigned short* __restrict__ chebT,
                                                        const unsigned short* __restrict__ ST,
                                                        const float* __restrict__ gm, const float* __restrict__ gs,
                                                        const unsigned short* __restrict__ xT,
                                                        unsigned short* __restrict__ h2) {
    int bk = blockIdx.y;
    int b = bk / 3, kk = bk % 3;
    int i0 = blockIdx.x * 128;
    const unsigned short* Ac = chebT + (size_t)kk * PW * PW;
    const unsigned short* Sa = ST + (size_t)b * PW * PW;
    const unsigned short* Bx = xT + (size_t)b * 384 * PW;
    __shared__ unsigned short As[2][2][4096];    // [buf][kh][128 x 32]  = 32 KB
    __shared__ unsigned short Bs[2][2][12288];   // [buf][kh][384 x 32]  = 96 KB
    int t = threadIdx.x, lane = t & 63, w = t >> 6;
    int wr = w >> 2, wc = w & 3;                 // wave: rows wr*64, cols wc*96
    int l15 = lane & 15, kseg = lane >> 4;
    f32x4 acc[4][6];
#pragma unroll
    for (int a = 0; a < 4; ++a)
#pragma unroll
        for (int c = 0; c < 6; ++c)
#pragma unroll
            for (int q = 0; q < 4; ++q) acc[a][c][q] = 0.f;
    // A reg-stage: thread slot row = t>>2, logical chunk = t&3
    int arow = t >> 2, achk = t & 3;
    const unsigned short* gac = Ac + (size_t)(i0 + arow) * PW + achk * 8;
    const unsigned short* gsa = Sa + (size_t)(i0 + arow) * PW + achk * 8;
    float gmv = gm[b * 2048 + i0 + arow];
    float gsv = gs[b * 2048 + i0 + arow];
    int awoff = arow * 32 + ((achk ^ FR_(arow)) << 3);
    // B gload: pre-swizzled global chunk
    int brow = t >> 2;
    int bchk = ((t & 3) ^ FR_(brow)) * 8;
    const unsigned short* gB = Bx + (size_t)brow * PW + bchk;
    int ldw = w * 512;
    union U8 { int4 v; unsigned short s[8]; };
#define SB_(buf_, kt_, kh_) do { \
    gload16(gB + (size_t)(kt_) * 64 + (kh_) * 32, &Bs[buf_][kh_][ldw]); \
    gload16(gB + (size_t)128 * PW + (size_t)(kt_) * 64 + (kh_) * 32, &Bs[buf_][kh_][4096 + ldw]); \
    gload16(gB + (size_t)256 * PW + (size_t)(kt_) * 64 + (kh_) * 32, &Bs[buf_][kh_][8192 + ldw]); \
} while (0)
#define WRA(buf_, kh_, cc, ss) do { U8 o_; \
    _Pragma("unroll") for (int e = 0; e < 8; ++e) \
        o_.s[e] = f2bf(bf2f((cc).s[e]) * __expf(bf2f((ss).s[e]) - gmv) * gsv); \
    *(int4*)&As[buf_][kh_][awoff] = o_.v; } while (0)
#define RDA(kh_, buf_) { _Pragma("unroll") for (int m = 0; m < 4; ++m) { \
    int R = wr * 64 + m * 16 + l15; \
    aR[m] = *(const bf16x8*)&As[buf_][kh_][R * 32 + ((kseg ^ FR_(R)) << 3)]; } }
#define RDB(kh_, nh_, buf_) { _Pragma("unroll") for (int n = 0; n < 3; ++n) { \
    int R = wc * 96 + (nh_) * 48 + n * 16 + l15; \
    bR[n] = *(const bf16x8*)&Bs[buf_][kh_][R * 32 + ((kseg ^ FR_(R)) << 3)]; } }
#define LGKM0 do { asm volatile("s_waitcnt lgkmcnt(0)" ::: "memory"); __builtin_amdgcn_sched_barrier(0); } while (0)
#define BAR __builtin_amdgcn_s_barrier()
#define MMA(nh_) do { __builtin_amdgcn_s_setprio(1); \
    _Pragma("unroll") for (int m = 0; m < 4; ++m) \
    _Pragma("unroll") for (int n = 0; n < 3; ++n) \
        acc[m][(nh_) * 3 + n] = __builtin_amdgcn_mfma_f32_16x16x32_bf16(aR[m], bR[n], acc[m][(nh_) * 3 + n], 0, 0, 0); \
    __builtin_amdgcn_s_setprio(0); } while (0)
    // prologue: A,B tiles 0 & 1
    {
        U8 cc, ss;
        cc.v = *(const int4*)(gac);      ss.v = *(const int4*)(gsa);      WRA(0, 0, cc, ss);
        cc.v = *(const int4*)(gac + 32); ss.v = *(const int4*)(gsa + 32); WRA(0, 1, cc, ss);
        cc.v = *(const int4*)(gac + 64); ss.v = *(const int4*)(gsa + 64); WRA(1, 0, cc, ss);
        cc.v = *(const int4*)(gac + 96); ss.v = *(const int4*)(gsa + 96); WRA(1, 1, cc, ss);
    }
    SB_(0, 0, 0); SB_(0, 0, 1); SB_(1, 1, 0); SB_(1, 1, 1);
    asm volatile("s_waitcnt vmcnt(0) lgkmcnt(0)" ::: "memory");
    BAR;
    for (int kt = 0; kt < 32; ++kt) {
        int cur = kt & 1;
        bf16x8 aR[4], bR[3];
        U8 ca0, sa0, ca1, sa1;
        bool pf = (kt + 2 < 32);
        // ph00: issue A(T+2)kh0 reg-loads
        RDA(0, cur); RDB(0, 0, cur);
        if (pf) { ca0.v = *(const int4*)(gac + (size_t)(kt + 2) * 64); sa0.v = *(const int4*)(gsa + (size_t)(kt + 2) * 64); }
        BAR; LGKM0; MMA(0); BAR;
        // ph01: issue A(T+2)kh1 reg-loads
        RDB(0, 1, cur);
        if (pf) { ca1.v = *(const int4*)(gac + (size_t)(kt + 2) * 64 + 32); sa1.v = *(const int4*)(gsa + (size_t)(kt + 2) * 64 + 32); }
        BAR; LGKM0; MMA(1); BAR;
        // ph10: write A(T+2)kh0, stage B(T+2)kh0 (into cur; its kh0 reads are done)
        RDA(1, cur); RDB(1, 0, cur);
        if (pf) { WRA(cur, 0, ca0, sa0); SB_(cur, kt + 2, 0); }
        BAR; LGKM0; MMA(0); BAR;
        // ph11: write A(T+2)kh1, stage B(T+2)kh1
        RDB(1, 1, cur);
        if (pf) { WRA(cur, 1, ca1, sa1); SB_(cur, kt + 2, 1); }
        BAR; LGKM0; MMA(1); BAR;
    }
#undef SB_
#undef WRA
#undef RDA
#undef RDB
#undef LGKM0
#undef BAR
#undef MMA
    unsigned short* hp = h2 + (size_t)bk * 768000;
#pragma unroll
    for (int fm = 0; fm < 4; ++fm) {
        int row0 = i0 + wr * 64 + fm * 16 + (kseg << 2);
#pragma unroll
        for (int fn = 0; fn < 6; ++fn) {
            int col = wc * 96 + fn * 16 + l15;
#pragma unroll
            for (int q = 0; q < 4; ++q) {
                int row = row0 + q;
                if (row < N_) hp[(size_t)row * 384 + col] = f2bf(acc[fm][fn][q]);
            }
        }
    }
}

// ---------------- fused tail: theta mix + time conv + residual + relu + LayerNorm ----------------
__global__ __launch_bounds__(512) void k_final3(const float* __restrict__ x, const unsigned short* __restrict__ h2,
                                                const float* __restrict__ ThetaG,
                                                const float* __restrict__ tcwT, const float* __restrict__ tc_b,
                                                const float* __restrict__ rcwT, const float* __restrict__ rc_b,
                                                const float* __restrict__ ln_g, const float* __restrict__ ln_b,
                                                float* __restrict__ out) {
    __shared__ __align__(16) char smem[110848];
    unsigned int* gl = (unsigned int*)smem;
    unsigned short* th = (unsigned short*)(smem + 98560);
    float* red_s = (float*)(smem + 98560);
    float* red_q = red_s + 64 * 13;

    int tid = threadIdx.x;
    int n_l = tid & 63, fg = tid >> 6;
    int b = blockIdx.y;
    int node = blockIdx.x * 64 + n_l;
    bool ok = node < N_;
    int nd = ok ? node : N_ - 1;

    for (int q = tid; q < 6144; q += 512) th[q] = f2bf(ThetaG[q]);
    __syncthreads();

    float acc[8][12];
#pragma unroll
    for (int ff = 0; ff < 8; ++ff)
#pragma unroll
        for (int t = 0; t < 12; ++t) acc[ff][t] = 0.f;
    const unsigned short* hb = h2 + (size_t)b * 3 * 768000 + (size_t)nd * 384;
#pragma unroll
    for (int kk = 0; kk < 3; ++kk) {
        const unsigned short* hp = hb + (size_t)kk * 768000;
#pragma unroll 2
        for (int c = 0; c < 32; ++c) {
            const unsigned short* hq = hp + c * 12;
            uint2 u0 = *(const uint2*)(hq);
            uint2 u1 = *(const uint2*)(hq + 4);
            uint2 u2 = *(const uint2*)(hq + 8);
            float h[12];
            h[0] = bf2f((unsigned short)u0.x);  h[1] = bf2f((unsigned short)(u0.x >> 16));
            h[2] = bf2f((unsigned short)u0.y);  h[3] = bf2f((unsigned short)(u0.y >> 16));
            h[4] = bf2f((unsigned short)u1.x);  h[5] = bf2f((unsigned short)(u1.x >> 16));
            h[6] = bf2f((unsigned short)u1.y);  h[7] = bf2f((unsigned short)(u1.y >> 16));
            h[8] = bf2f((unsigned short)u2.x);  h[9] = bf2f((unsigned short)(u2.x >> 16));
            h[10] = bf2f((unsigned short)u2.y); h[11] = bf2f((unsigned short)(u2.y >> 16));
            const unsigned short* wv = th + (kk * 32 + c) * 64 + fg * 8;
            uint2 w01 = *(const uint2*)wv;
            uint2 w23 = *(const uint2*)(wv + 4);
            float wf[8];
            wf[0] = bf2f((unsigned short)w01.x); wf[1] = bf2f((unsigned short)(w01.x >> 16));
            wf[2] = bf2f((unsigned short)w01.y); wf[3] = bf2f((unsigned short)(w01.y >> 16));
            wf[4] = bf2f((unsigned short)w23.x); wf[5] = bf2f((unsigned short)(w23.x >> 16));
            wf[6] = bf2f((unsigned short)w23.y); wf[7] = bf2f((unsigned short)(w23.y >> 16));
#pragma unroll
            for (int ff = 0; ff < 8; ++ff)
#pragma unroll
                for (int t = 0; t < 12; ++t) acc[ff][t] = fmaf(h[t], wf[ff], acc[ff][t]);
        }
    }
    unsigned int* gr = gl + n_l * 385 + fg * 48;
#pragma unroll
    for (int ff = 0; ff < 8; ++ff)
#pragma unroll
        for (int tp = 0; tp < 6; ++tp) {
            float a0 = fmaxf(acc[ff][2 * tp], 0.f), a1 = fmaxf(acc[ff][2 * tp + 1], 0.f);
            gr[ff * 6 + tp] = (unsigned int)f2bf(a0) | ((unsigned int)f2bf(a1) << 16);
        }
    __syncthreads();

    float z[8][12];
#pragma unroll
    for (int ff = 0; ff < 8; ++ff) {
        float bias = tc_b[fg * 8 + ff] + rc_b[fg * 8 + ff];
#pragma unroll
        for (int t = 0; t < 12; ++t) z[ff][t] = bias;
    }
    const float* xp = x + (size_t)(b * 2000 + nd) * 384;
#pragma unroll 2
    for (int c = 0; c < 32; ++c) {
        float4 x0 = *(const float4*)(xp + c * 12);
        float4 x1 = *(const float4*)(xp + c * 12 + 4);
        float4 x2 = *(const float4*)(xp + c * 12 + 8);
        float xv[12] = {x0.x, x0.y, x0.z, x0.w, x1.x, x1.y, x1.z, x1.w, x2.x, x2.y, x2.z, x2.w};
        float4 r0 = *(const float4*)(rcwT + c * 64 + fg * 8);
        float4 r1 = *(const float4*)(rcwT + c * 64 + fg * 8 + 4);
        float rw[8] = {r0.x, r0.y, r0.z, r0.w, r1.x, r1.y, r1.z, r1.w};
#pragma unroll
        for (int ff = 0; ff < 8; ++ff)
#pragma unroll
            for (int t = 0; t < 12; ++t) z[ff][t] = fmaf(xv[t], rw[ff], z[ff][t]);
    }
    const unsigned int* grow = gl + n_l * 385;
    for (int fi = 0; fi < 64; ++fi) {
        float g[12];
#pragma unroll
        for (int j = 0; j < 6; ++j) {
            unsigned int u = grow[fi * 6 + j];
            g[2 * j] = bf2f((unsigned short)u);
            g[2 * j + 1] = bf2f((unsigned short)(u >> 16));
        }
        const float* wp = tcwT + (fi * 64 + fg * 8) * 3;
        float4 w0 = *(const float4*)(wp);
        float4 w1 = *(const float4*)(wp + 4);
        float4 w2 = *(const float4*)(wp + 8);
        float4 w3 = *(const float4*)(wp + 12);
        float4 w4 = *(const float4*)(wp + 16);
        float4 w5 = *(const float4*)(wp + 20);
        float wb[24] = {w0.x, w0.y, w0.z, w0.w, w1.x, w1.y, w1.z, w1.w,
                        w2.x, w2.y, w2.z, w2.w, w3.x, w3.y, w3.z, w3.w,
                        w4.x, w4.y, w4.z, w4.w, w5.x, w5.y, w5.z, w5.w};
#pragma unroll
        for (int ff = 0; ff < 8; ++ff) {
            float a0 = wb[ff * 3], a1 = wb[ff * 3 + 1], a2 = wb[ff * 3 + 2];
            z[ff][0] = fmaf(g[0], a1, fmaf(g[1], a2, z[ff][0]));
#pragma unroll
            for (int t = 1; t < 11; ++t)
                z[ff][t] = fmaf(g[t - 1], a0, fmaf(g[t], a1, fmaf(g[t + 1], a2, z[ff][t])));
            z[ff][11] = fmaf(g[10], a0, fmaf(g[11], a1, z[ff][11]));
        }
    }
#pragma unroll
    for (int ff = 0; ff < 8; ++ff)
#pragma unroll
        for (int t = 0; t < 12; ++t) z[ff][t] = fmaxf(z[ff][t], 0.f);

    float s[12], q[12];
#pragma unroll
    for (int t = 0; t < 12; ++t) { s[t] = 0.f; q[t] = 0.f; }
#pragma unroll
    for (int ff = 0; ff < 8; ++ff)
#pragma unroll
        for (int t = 0; t < 12; ++t) { s[t] += z[ff][t]; q[t] += z[ff][t] * z[ff][t]; }
    __syncthreads();
    for (int g = 0; g < 8; ++g) {
        if (fg == g) {
            if (g == 0) {
#pragma unroll
                for (int t = 0; t < 12; ++t) { red_s[n_l * 13 + t] = s[t]; red_q[n_l * 13 + t] = q[t]; }
            } else {
#pragma unroll
                for (int t = 0; t < 12; ++t) { red_s[n_l * 13 + t] += s[t]; red_q[n_l * 13 + t] += q[t]; }
            }
        }
        __syncthreads();
    }
    float mu[12], rs[12];
#pragma unroll
    for (int t = 0; t < 12; ++t) {
        float m = red_s[n_l * 13 + t] * (1.0f / 64.0f);
        float v = red_q[n_l * 13 + t] * (1.0f / 64.0f) - m * m;
        mu[t] = m;
        rs[t] = rsqrtf(v + 1e-5f);
    }
    if (ok) {
        float* op = out + ((size_t)(b * 2000 + node) * 64 + fg * 8) * 12;
#pragma unroll
        for (int ff = 0; ff < 8; ++ff) {
            float lg = ln_g[fg * 8 + ff], lb = ln_b[fg * 8 + ff];
            float o[12];
#pragma unroll
            for (int t = 0; t < 12; ++t) o[t] = (z[ff][t] - mu[t]) * rs[t] * lg + lb;
#pragma unroll
            for (int tq = 0; tq < 3; ++tq)
                *(float4*)(op + ff * 12 + tq * 4) = make_float4(o[tq * 4], o[tq * 4 + 1], o[tq * 4 + 2], o[tq * 4 + 3]);
        }
    }
}

extern "C" void kernel_launch(void* const* d_in, const int* in_sizes, int n_in,
                              void* d_out, int out_size, void* d_ws, size_t ws_size,
                              hipStream_t stream) {
    const float* x     = (const float*)d_in[0];
    const float* cheb  = (const float*)d_in[1];
    const float* U1    = (const float*)d_in[2];
    const float* U2    = (const float*)d_in[3];
    const float* U3    = (const float*)d_in[4];
    const float* be    = (const float*)d_in[5];
    const float* Ve    = (const float*)d_in[6];
    const float* W1    = (const float*)d_in[7];
    const float* W2    = (const float*)d_in[8];
    const float* W3    = (const float*)d_in[9];
    const float* bs    = (const float*)d_in[10];
    const float* Vs    = (const float*)d_in[11];
    const float* Theta = (const float*)d_in[12];
    const float* tc_w  = (const float*)d_in[13];
    const float* tc_b  = (const float*)d_in[14];
    const float* rc_w  = (const float*)d_in[15];
    const float* rc_b  = (const float*)d_in[16];
    const float* ln_g  = (const float*)d_in[17];
    const float* ln_b  = (const float*)d_in[18];
    float* out = (float*)d_out;

    // ---- workspace layout (~184.3 MB, identical to rounds 8-12) ----
    float* ws    = (float*)d_ws;
    float* At    = ws;
    float* lhs1  = ws + 1152;
    float* lhsT  = ws + 4224;
    float* rhsT  = ws + 196224;
    float* lhs_s = ws + 388224;
    float* rhs_s = ws + 580224;
    float* gm    = ws + 772224;
    float* gs    = ws + 788608;
    float* tcwT  = ws + 804992;
    float* rcwT  = ws + 817280;
    float* plh   = ws + 819328;
    float* pP    = ws + 972928;
    unsigned short* Vsb   = (unsigned short*)(ws + 991360);
    unsigned short* chebT = (unsigned short*)(ws + 3088512);
    unsigned short* xT    = (unsigned short*)(ws + 9379968);
    unsigned short* sigT  = (unsigned short*)(ws + 12525696);  // dead after gemm_S
    unsigned short* h2    = sigT;                              // reuse after gemm_S
    unsigned short* STb   = (unsigned short*)(ws + 29302912);

    // prep
    k_wprep<<<56, 256, 0, stream>>>(tc_w, rc_w, tcwT, rcwT);
    k_vsb<<<2048, 256, 0, stream>>>(Vs, Vsb);
    k_chebT<<<dim3(32, 32, 3), 256, 0, stream>>>(cheb, chebT);
    k_xT<<<dim3(32, 6, 8), 256, 0, stream>>>(x, xT);
    // temporal attention
    k_tprep<<<dim3(50, 8), 256, 0, stream>>>(x, U1, U3, rhsT, plh);
    k_tred<<<8, 256, 0, stream>>>(plh, lhs1);
    k_lhsT<<<750, 256, 0, stream>>>(lhs1, U2, lhsT);
    k_tatt1<<<dim3(16, 8), 256, 0, stream>>>(lhsT, rhsT, pP);
    k_tatt2<<<8, 256, 0, stream>>>(pP, be, Ve, At);
    k_xsp<<<dim3(250, 8), 256, 0, stream>>>(x, At, W1, W2, W3, lhs_s, rhs_s);
    // spatial attention (S^T directly)
    k_sig<<<dim3(32, 32, 8), 256, 0, stream>>>(lhs_s, rhs_s, bs, sigT);
    k_gemm_S_mfma<<<dim3(8, 8, 8), 512, 0, stream>>>(Vsb, sigT, STb);
    k_smrow<<<dim3(512, 8), 256, 0, stream>>>(STb, gm, gs);
    // chebyshev gcn with fused softmax normalization (counted pipeline)
    k_gemm_cheb_mfma<<<dim3(16, 24), 512, 0, stream>>>(chebT, STb, gm, gs, xT, h2);
    // fused theta + conv + LN tail
    k_final3<<<dim3(32, 8), 512, 0, stream>>>(x, h2, Theta, tcwT, tc_b, rcwT, rc_b, ln_g, ln_b, out);
}

// Round 14
// 595.910 us; speedup vs baseline: 1.0830x; 1.0107x over previous
//
#include <hip/hip_runtime.h>
#include <hip/hip_bf16.h>
#include <math.h>

#define B_ 8
#define N_ 2000
#define C_ 32
#define T_ 12
#define K_ 3
#define FC_ 64
#define FT_ 64
#define PW 2048   // padded width (K and row pads, zero-filled)

typedef short bf16x8 __attribute__((ext_vector_type(8)));
typedef float f32x4 __attribute__((ext_vector_type(4)));

__device__ __forceinline__ float sigmoidf(float v) { return 1.0f / (1.0f + __expf(-v)); }
__device__ __forceinline__ float bf2f(unsigned short u) {
    union { unsigned int i; float f; } v; v.i = ((unsigned int)u) << 16; return v.f;
}
__device__ __forceinline__ unsigned short f2bf(float f) {
    union { __hip_bfloat16 h; unsigned short u; } v; v.h = __float2bfloat16(f); return v.u;
}
typedef const __attribute__((address_space(1))) void* gas_t;
typedef __attribute__((address_space(3))) void* las_t;
__device__ __forceinline__ void gload16(const unsigned short* g, unsigned short* l) {
    __builtin_amdgcn_global_load_lds((gas_t)g, (las_t)l, 16, 0, 0);
}

// ---------------- fused x-pass: lhs1 partials + rhsT ----------------
__global__ __launch_bounds__(256) void k_tprep(const float* __restrict__ x, const float* __restrict__ U1,
                                               const float* __restrict__ U3,
                                               float* __restrict__ rhsT, float* __restrict__ plh) {
    int b = blockIdx.y, chunk = blockIdx.x;
    int tid = threadIdx.x;
    int nl = tid >> 5, c = tid & 31;
    int w = tid >> 6;
    float u3 = U3[c];
    float plA[12];
#pragma unroll
    for (int t = 0; t < 12; ++t) plA[t] = 0.f;
    for (int it = 0; it < 5; ++it) {
        int n = chunk * 40 + it * 8 + nl;
        const float* xp = x + ((size_t)(b * 2000 + n) * 32 + c) * 12;
        float4 v0 = *(const float4*)xp, v1 = *(const float4*)(xp + 4), v2 = *(const float4*)(xp + 8);
        float xv[12] = {v0.x, v0.y, v0.z, v0.w, v1.x, v1.y, v1.z, v1.w, v2.x, v2.y, v2.z, v2.w};
        float rv[12];
#pragma unroll
        for (int t = 0; t < 12; ++t) rv[t] = u3 * xv[t];
#pragma unroll
        for (int off = 16; off >= 1; off >>= 1)
#pragma unroll
            for (int t = 0; t < 12; ++t) rv[t] += __shfl_xor(rv[t], off);
        if (c == 0) {
#pragma unroll
            for (int t = 0; t < 12; ++t) rhsT[(size_t)(b * 2000 + n) * 12 + t] = rv[t];
        }
        float u1 = U1[n];
#pragma unroll
        for (int t = 0; t < 12; ++t) plA[t] += u1 * xv[t];
    }
#pragma unroll
    for (int t = 0; t < 12; ++t) plA[t] += __shfl_xor(plA[t], 32);
    __shared__ float accs[4][32][12];
    if ((tid & 63) < 32) {
#pragma unroll
        for (int t = 0; t < 12; ++t) accs[w][c][t] = plA[t];
    }
    __syncthreads();
    if (tid < 384) {
        int c2 = tid / 12, t2 = tid % 12;
        float s = accs[0][c2][t2] + accs[1][c2][t2] + accs[2][c2][t2] + accs[3][c2][t2];
        plh[((size_t)(b * 50 + chunk)) * 384 + tid] = s;
    }
}

__global__ __launch_bounds__(256) void k_tred(const float* __restrict__ plh, float* __restrict__ lhs1) {
    int b = blockIdx.x;
    for (int q = threadIdx.x; q < 384; q += 256) {
        const float* p = plh + (size_t)b * 50 * 384 + q;
        float s = 0.f;
        for (int ch = 0; ch < 50; ++ch) s += p[(size_t)ch * 384];
        int c = q / 12, t = q % 12;
        lhs1[(b * 12 + t) * 32 + c] = s;
    }
}

__global__ __launch_bounds__(256) void k_lhsT(const float* __restrict__ lhs1, const float* __restrict__ U2,
                                              float* __restrict__ lhsT) {
    int gid = blockIdx.x * 256 + threadIdx.x;
    if (gid >= B_ * T_ * N_) return;
    int n = gid % N_;
    int bt = gid / N_;
    const float* l1 = lhs1 + bt * C_;
    float a = 0.f;
#pragma unroll
    for (int c = 0; c < C_; ++c) a += l1[c] * U2[c * N_ + n];
    lhsT[gid] = a;
}

__global__ __launch_bounds__(256) void k_tatt1(const float* __restrict__ lhsT, const float* __restrict__ rhsT,
                                               float* __restrict__ pP) {
    int b = blockIdx.y, ch = blockIdx.x;
    int tid = threadIdx.x;
    int n0 = ch * 125;
    __shared__ float sL[12][128];
    __shared__ float sR[128][12];
    for (int q = tid; q < 12 * 125; q += 256) {
        int t = q / 125, nn = q % 125;
        sL[t][nn] = lhsT[(size_t)(b * 12 + t) * 2000 + n0 + nn];
    }
    for (int q = tid; q < 125 * 12; q += 256) {
        int nn = q / 12, t = q % 12;
        sR[nn][t] = rhsT[(size_t)(b * 2000 + n0 + nn) * 12 + t];
    }
    __syncthreads();
    if (tid < 144) {
        int tP = tid / 12, uP = tid % 12;
        float a = 0.f;
#pragma unroll 5
        for (int nn = 0; nn < 125; ++nn) a += sL[tP][nn] * sR[nn][uP];
        pP[(size_t)(b * 16 + ch) * 144 + tid] = a;
    }
}

__global__ __launch_bounds__(256) void k_tatt2(const float* __restrict__ pP, const float* __restrict__ be,
                                               const float* __restrict__ Ve, float* __restrict__ At) {
    int b = blockIdx.x, tid = threadIdx.x;
    __shared__ float sp[144], sE[144], mk[12], sk[12];
    int tP = tid / 12, uP = tid % 12;
    if (tid < 144) {
        float a = 0.f;
#pragma unroll
        for (int ch = 0; ch < 16; ++ch) a += pP[(size_t)(b * 16 + ch) * 144 + tid];
        sp[tid] = sigmoidf(a + be[tid]);
    }
    __syncthreads();
    if (tid < 144) {
        float e = 0.f;
#pragma unroll
        for (int j = 0; j < 12; ++j) e += Ve[tP * 12 + j] * sp[j * 12 + uP];
        sE[tid] = e;
    }
    __syncthreads();
    if (tid < 12) {
        float m = -1e30f;
#pragma unroll
        for (int i = 0; i < 12; ++i) m = fmaxf(m, sE[i * 12 + tid]);
        float s = 0.f;
#pragma unroll
        for (int i = 0; i < 12; ++i) s += __expf(sE[i * 12 + tid] - m);
        mk[tid] = m; sk[tid] = 1.0f / s;
    }
    __syncthreads();
    if (tid < 144) At[b * 144 + tid] = __expf(sE[tid] - mk[uP]) * sk[uP];
}

__global__ __launch_bounds__(256) void k_xsp(const float* __restrict__ x, const float* __restrict__ At,
                                             const float* __restrict__ W1, const float* __restrict__ W2,
                                             const float* __restrict__ W3,
                                             float* __restrict__ lhs_s, float* __restrict__ rhs_s) {
    int b = blockIdx.y, chunk = blockIdx.x;
    int tid = threadIdx.x, nl = tid >> 5, c = tid & 31;
    int n = chunk * 8 + nl;
    __shared__ float atl[144];
    __shared__ float w2l[384];
    __shared__ float w1l[12];
    if (tid < 144) atl[tid] = At[b * 144 + tid];
    if (tid >= 144 && tid < 156) w1l[tid - 144] = W1[tid - 144];
    for (int q = tid; q < 384; q += 256) w2l[q] = W2[q];
    __syncthreads();
    const float* xp = x + ((size_t)(b * 2000 + n) * 32 + c) * 12;
    float4 v0 = *(const float4*)xp, v1 = *(const float4*)(xp + 4), v2 = *(const float4*)(xp + 8);
    float xv[12] = {v0.x, v0.y, v0.z, v0.w, v1.x, v1.y, v1.z, v1.w, v2.x, v2.y, v2.z, v2.w};
    float xa[12];
#pragma unroll
    for (int t = 0; t < 12; ++t) {
        float s = 0.f;
#pragma unroll
        for (int u = 0; u < 12; ++u) s += xv[u] * atl[u * 12 + t];
        xa[t] = s;
    }
    float w3 = W3[c];
    float rv[12], lv[12];
    float l1 = 0.f;
#pragma unroll
    for (int t = 0; t < 12; ++t) l1 += xa[t] * w1l[t];
#pragma unroll
    for (int t = 0; t < 12; ++t) { rv[t] = w3 * xa[t]; lv[t] = l1 * w2l[c * 12 + t]; }
#pragma unroll
    for (int off = 16; off >= 1; off >>= 1)
#pragma unroll
        for (int t = 0; t < 12; ++t) { rv[t] += __shfl_xor(rv[t], off); lv[t] += __shfl_xor(lv[t], off); }
    if (c == 0) {
#pragma unroll
        for (int t = 0; t < 12; ++t) rhs_s[(size_t)(b * 12 + t) * 2000 + n] = rv[t];
#pragma unroll
        for (int t = 0; t < 12; ++t) lhs_s[(size_t)(b * 2000 + n) * 12 + t] = lv[t];
    }
}

// ---------------- weight transposes ----------------
__global__ __launch_bounds__(256) void k_wprep(const float* __restrict__ tc_w, const float* __restrict__ rc_w,
                                               float* __restrict__ tcwT, float* __restrict__ rcwT) {
    int gid = blockIdx.x * 256 + threadIdx.x;
    if (gid < 12288) {
        int fi = gid / 192, rem = gid % 192, f = rem / 3, d = rem % 3;
        tcwT[gid] = tc_w[(f * 64 + fi) * 3 + d];
    } else if (gid < 14336) {
        int q = gid - 12288;
        int c = q >> 6, f = q & 63;
        rcwT[q] = rc_w[f * 32 + c];
    }
}

// ---------------- conversions / transposes (padded to PW, zero-filled) ----------------
__global__ __launch_bounds__(256) void k_vsb(const float* __restrict__ Vs, unsigned short* __restrict__ Vsb) {
    int gid = blockIdx.x * 256 + threadIdx.x;
    int row = gid >> 8, chunk = gid & 255;
    int p0 = chunk * 8;
    unsigned short o[8];
#pragma unroll
    for (int e = 0; e < 8; ++e) {
        int p = p0 + e;
        o[e] = (row < N_ && p < N_) ? f2bf(Vs[row * N_ + p]) : (unsigned short)0;
    }
    *(int4*)(Vsb + (size_t)row * PW + p0) = *(int4*)o;
}

__global__ __launch_bounds__(256) void k_chebT(const float* __restrict__ cheb, unsigned short* __restrict__ chebT) {
    int j0 = blockIdx.x * 64, i0 = blockIdx.y * 64, kk = blockIdx.z;
    __shared__ float Tl[64][65];
    int t = threadIdx.x;
    int rr = t >> 2, c0 = (t & 3) * 16;
    int j = j0 + rr;
#pragma unroll
    for (int e = 0; e < 16; ++e) {
        int i = i0 + c0 + e;
        Tl[rr][c0 + e] = (j < N_ && i < N_) ? cheb[(size_t)kk * 4000000 + (size_t)j * N_ + i] : 0.f;
    }
    __syncthreads();
    int l = t & 63, w = t >> 6;
    unsigned short o[16];
#pragma unroll
    for (int e = 0; e < 16; ++e) o[e] = f2bf(Tl[w * 16 + e][l]);
    unsigned short* dst = chebT + (size_t)kk * PW * PW + (size_t)(i0 + l) * PW + j0 + w * 16;
    *(int4*)dst = *(int4*)o;
    *(int4*)(dst + 8) = *(int4*)(o + 8);
}

__global__ __launch_bounds__(256) void k_xT(const float* __restrict__ x, unsigned short* __restrict__ xT) {
    int j0 = blockIdx.x * 64, r0 = blockIdx.y * 64, b = blockIdx.z;
    __shared__ float Tl[64][65];
    int t = threadIdx.x;
    int rr = t >> 2, c0 = (t & 3) * 16;
    int j = j0 + rr;
#pragma unroll
    for (int e = 0; e < 16; ++e) {
        int r = r0 + c0 + e;
        Tl[rr][c0 + e] = (j < N_) ? x[(size_t)(b * N_ + j) * 384 + r] : 0.f;
    }
    __syncthreads();
    int l = t & 63, w = t >> 6;
    unsigned short o[16];
#pragma unroll
    for (int e = 0; e < 16; ++e) o[e] = f2bf(Tl[w * 16 + e][l]);
    unsigned short* dst = xT + (size_t)b * 384 * PW + (size_t)(r0 + l) * PW + j0 + w * 16;
    *(int4*)dst = *(int4*)o;
    *(int4*)(dst + 8) = *(int4*)(o + 8);
}

__global__ __launch_bounds__(256) void k_sig(const float* __restrict__ lhs_s, const float* __restrict__ rhs_s,
                                             const float* __restrict__ bs, unsigned short* __restrict__ sigT) {
    int p0 = blockIdx.x * 64, i0 = blockIdx.y * 64, b = blockIdx.z;
    __shared__ float sL[64][12];
    __shared__ float sR[12][64];
    __shared__ float bsl[64][65];
    int t = threadIdx.x;
    for (int q = t; q < 768; q += 256) {
        int pp = q / 12, tt = q % 12;
        int p = p0 + pp;
        sL[pp][tt] = (p < N_) ? lhs_s[(b * N_ + p) * 12 + tt] : 0.f;
    }
    for (int q = t; q < 768; q += 256) {
        int tt = q >> 6, ii = q & 63;
        int i = i0 + ii;
        sR[tt][ii] = (i < N_) ? rhs_s[b * (T_ * N_) + tt * N_ + i] : 0.f;
    }
    {
        int pp = t >> 2, c0 = (t & 3) * 16;
        int p = p0 + pp;
        if (p < N_ && i0 + c0 + 15 < N_) {
            const float* src = bs + (size_t)p * N_ + i0 + c0;
#pragma unroll
            for (int e = 0; e < 16; e += 4) *(float4*)&bsl[pp][c0 + e] = *(const float4*)(src + e);
        } else {
#pragma unroll
            for (int e = 0; e < 16; ++e) {
                int i = i0 + c0 + e;
                bsl[pp][c0 + e] = (p < N_ && i < N_) ? bs[(size_t)p * N_ + i] : 0.f;
            }
        }
    }
    __syncthreads();
    int ii = t & 63, w = t >> 6;
    int i = i0 + ii;
    unsigned short o[16];
#pragma unroll
    for (int e = 0; e < 16; ++e) {
        int pl = w * 16 + e;
        int p = p0 + pl;
        float v = 0.f;
        if (p < N_ && i < N_) {
            float d = bsl[pl][ii];
#pragma unroll
            for (int tt = 0; tt < 12; ++tt) d += sL[pl][tt] * sR[tt][ii];
            v = sigmoidf(d);
        }
        o[e] = f2bf(v);
    }
    unsigned short* dst = sigT + (size_t)b * PW * PW + (size_t)i * PW + p0 + w * 16;
    *(int4*)dst = *(int4*)o;
    *(int4*)(dst + 8) = *(int4*)(o + 8);
}

// ---------------- MFMA GEMM 256x256, BK=64, 2 fat phases/tile, counted vmcnt ----------------
// ST[i][j] = sum_p sigT[i][p] * Vsb[j][p]
#define FR_(R) (((R) ^ ((R) >> 2)) & 3)
__global__ __launch_bounds__(512) void k_gemm_S_mfma(const unsigned short* __restrict__ Vsb,
                                                     const unsigned short* __restrict__ sigT,
                                                     unsigned short* __restrict__ ST) {
    int lid = blockIdx.x + (blockIdx.y << 3) + (blockIdx.z << 6);
    int swz = (lid & 7) * 64 + (lid >> 3);
    int j0 = (swz & 7) * 256;
    int i0 = ((swz >> 3) & 7) * 256;
    int b = swz >> 6;
    const unsigned short* Ap = sigT + (size_t)b * PW * PW;
    __shared__ unsigned short As[2][2][8192];   // [buf][khalf][256 rows x 32 elems]
    __shared__ unsigned short Bs[2][2][8192];
    int t = threadIdx.x, lane = t & 63, w = t >> 6;
    int wr = w >> 2, wc = w & 3;                // wave: rows wr*128, cols wc*64
    int l15 = lane & 15, kseg = lane >> 4;
    f32x4 acc[8][4];
#pragma unroll
    for (int m = 0; m < 8; ++m)
#pragma unroll
        for (int n = 0; n < 4; ++n)
#pragma unroll
            for (int q = 0; q < 4; ++q) acc[m][n][q] = 0.f;
    int srow = t >> 2;
    int gchunk = ((t & 3) ^ FR_(srow)) * 8;
    const unsigned short* gA = Ap + (size_t)(i0 + srow) * PW + gchunk;
    const unsigned short* gB = Vsb + (size_t)(j0 + srow) * PW + gchunk;
    int ldw = w * 512;
#define SA_(buf_, kt_, kh_) do { \
    gload16(gA + (size_t)(kt_) * 64 + (kh_) * 32, &As[buf_][kh_][ldw]); \
    gload16(gA + (size_t)128 * PW + (size_t)(kt_) * 64 + (kh_) * 32, &As[buf_][kh_][4096 + ldw]); \
} while (0)
#define SB_(buf_, kt_, kh_) do { \
    gload16(gB + (size_t)(kt_) * 64 + (kh_) * 32, &Bs[buf_][kh_][ldw]); \
    gload16(gB + (size_t)128 * PW + (size_t)(kt_) * 64 + (kh_) * 32, &Bs[buf_][kh_][4096 + ldw]); \
} while (0)
#define RDA(kh_, buf_) { _Pragma("unroll") for (int m = 0; m < 8; ++m) { \
    int R = wr * 128 + m * 16 + l15; \
    aR[m] = *(const bf16x8*)&As[buf_][kh_][R * 32 + ((kseg ^ FR_(R)) << 3)]; } }
#define RDB(kh_, buf_) { _Pragma("unroll") for (int n = 0; n < 4; ++n) { \
    int R = wc * 64 + n * 16 + l15; \
    bR[n] = *(const bf16x8*)&Bs[buf_][kh_][R * 32 + ((kseg ^ FR_(R)) << 3)]; } }
#define LGKM0 do { asm volatile("s_waitcnt lgkmcnt(0)" ::: "memory"); __builtin_amdgcn_sched_barrier(0); } while (0)
#define MMA() do { __builtin_amdgcn_s_setprio(1); \
    _Pragma("unroll") for (int m = 0; m < 8; ++m) \
    _Pragma("unroll") for (int n = 0; n < 4; ++n) \
        acc[m][n] = __builtin_amdgcn_mfma_f32_16x16x32_bf16(aR[m], bR[n], acc[m][n], 0, 0, 0); \
    __builtin_amdgcn_s_setprio(0); } while (0)
    // prologue: tile0 full, tile1 kh0
    SA_(0, 0, 0); SB_(0, 0, 0);
    SA_(0, 0, 1); SB_(0, 0, 1);
    SA_(1, 1, 0); SB_(1, 1, 0);
    for (int kt = 0; kt < 32; ++kt) {
        int cur = kt & 1, nb = cur ^ 1;
        bf16x8 aR[8], bR[4];
        // ---- ph0: read cur kh0 (staged 1.5 tiles ago); stage (nb, kt+1, kh1) ----
        if (kt < 31) asm volatile("s_waitcnt vmcnt(8)" ::: "memory");
        else         asm volatile("s_waitcnt vmcnt(4)" ::: "memory");
        __builtin_amdgcn_s_barrier();
        __builtin_amdgcn_sched_barrier(0);
        RDA(0, cur); RDB(0, cur);
        if (kt + 1 < 32) { SA_(nb, kt + 1, 1); SB_(nb, kt + 1, 1); }
        LGKM0;
        MMA();
        // ---- ph1: read cur kh1; stage (cur, kt+2, kh0) ----
        if (kt < 31) asm volatile("s_waitcnt vmcnt(8)" ::: "memory");
        else         asm volatile("s_waitcnt vmcnt(0)" ::: "memory");
        __builtin_amdgcn_s_barrier();
        __builtin_amdgcn_sched_barrier(0);
        RDA(1, cur); RDB(1, cur);
        if (kt + 2 < 32) { SA_(cur, kt + 2, 0); SB_(cur, kt + 2, 0); }
        LGKM0;
        MMA();
    }
#undef SA_
#undef SB_
#undef RDA
#undef RDB
#undef LGKM0
#undef MMA
    unsigned short* Sp = ST + (size_t)b * PW * PW;
#pragma unroll
    for (int m = 0; m < 8; ++m) {
        int row0 = i0 + wr * 128 + m * 16 + (kseg << 2);
#pragma unroll
        for (int n = 0; n < 4; ++n) {
            int col = j0 + wc * 64 + n * 16 + l15;
#pragma unroll
            for (int q = 0; q < 4; ++q)
                Sp[(size_t)(row0 + q) * PW + col] = f2bf(acc[m][n][q]);
        }
    }
}

// ---- row softmax stats over ST rows ----
__global__ __launch_bounds__(256) void k_smrow(const unsigned short* __restrict__ ST,
                                               float* __restrict__ gm, float* __restrict__ gs) {
    int wid = threadIdx.x >> 6, lane = threadIdx.x & 63;
    int b = blockIdx.y;
    int i = blockIdx.x * 4 + wid;
    const unsigned short* rp = ST + (size_t)b * PW * PW + (size_t)i * PW;
    float vals[32];
    float m = -1e30f;
#pragma unroll
    for (int k = 0; k < 4; ++k) {
        int j0 = lane * 8 + k * 512;
        if (j0 < N_) {
            union { int4 v; unsigned short s[8]; } u;
            u.v = *(const int4*)(rp + j0);
#pragma unroll
            for (int e = 0; e < 8; ++e) {
                vals[k * 8 + e] = bf2f(u.s[e]);
                m = fmaxf(m, vals[k * 8 + e]);
            }
        } else {
#pragma unroll
            for (int e = 0; e < 8; ++e) vals[k * 8 + e] = -1e30f;
        }
    }
#pragma unroll
    for (int off = 32; off >= 1; off >>= 1) m = fmaxf(m, __shfl_xor(m, off));
    float s = 0.f;
#pragma unroll
    for (int k = 0; k < 32; ++k) s += __expf(vals[k] - m);
#pragma unroll
    for (int off = 32; off >= 1; off >>= 1) s += __shfl_xor(s, off);
    if (lane == 0) {
        gm[b * 2048 + i] = m;
        gs[b * 2048 + i] = 1.0f / s;
    }
}

// ---------------- MFMA GEMM cheb: 2 fat phases/tile, reg-staged A (exp-normalize fused) ----------------
// h2[i][r] = sum_j chebT[i][j]*exp(ST[i][j]-gm[i])*gs[i] * xT[r][j]
__global__ __launch_bounds__(512) void k_gemm_cheb_mfma(const unsigned short* __restrict__ chebT,
                                                        const unsigned short* __restrict__ ST,
                                                        const float* __restrict__ gm, const float* __restrict__ gs,
                                                        const unsigned short* __restrict__ xT,
                                                        unsigned short* __restrict__ h2) {
    int bk = blockIdx.y;
    int b = bk / 3, kk = bk % 3;
    int i0 = blockIdx.x * 128;
    const unsigned short* Ac = chebT + (size_t)kk * PW * PW;
    const unsigned short* Sa = ST + (size_t)b * PW * PW;
    const unsigned short* Bx = xT + (size_t)b * 384 * PW;
    __shared__ unsigned short As[2][2][4096];    // [buf][kh][128 x 32]
    __shared__ unsigned short Bs[2][2][12288];   // [buf][kh][384 x 32]
    int t = threadIdx.x, lane = t & 63, w = t >> 6;
    int wr = w >> 2, wc = w & 3;                 // wave: rows wr*64, cols wc*96
    int l15 = lane & 15, kseg = lane >> 4;
    f32x4 acc[4][6];
#pragma unroll
    for (int a = 0; a < 4; ++a)
#pragma unroll
        for (int c = 0; c < 6; ++c)
#pragma unroll
            for (int q = 0; q < 4; ++q) acc[a][c][q] = 0.f;
    int arow = t >> 2, achk = t & 3;
    const unsigned short* gac = Ac + (size_t)(i0 + arow) * PW + achk * 8;
    const unsigned short* gsa = Sa + (size_t)(i0 + arow) * PW + achk * 8;
    float gmv = gm[b * 2048 + i0 + arow];
    float gsv = gs[b * 2048 + i0 + arow];
    int awoff = arow * 32 + ((achk ^ FR_(arow)) << 3);
    int brow = t >> 2;
    int bchk = ((t & 3) ^ FR_(brow)) * 8;
    const unsigned short* gB = Bx + (size_t)brow * PW + bchk;
    int ldw = w * 512;
    union U8 { int4 v; unsigned short s[8]; };
#define SB_(buf_, kt_, kh_) do { \
    gload16(gB + (size_t)(kt_) * 64 + (kh_) * 32, &Bs[buf_][kh_][ldw]); \
    gload16(gB + (size_t)128 * PW + (size_t)(kt_) * 64 + (kh_) * 32, &Bs[buf_][kh_][4096 + ldw]); \
    gload16(gB + (size_t)256 * PW + (size_t)(kt_) * 64 + (kh_) * 32, &Bs[buf_][kh_][8192 + ldw]); \
} while (0)
#define WRA(buf_, kh_, cc, ss) do { U8 o_; \
    _Pragma("unroll") for (int e = 0; e < 8; ++e) \
        o_.s[e] = f2bf(bf2f((cc).s[e]) * __expf(bf2f((ss).s[e]) - gmv) * gsv); \
    *(int4*)&As[buf_][kh_][awoff] = o_.v; } while (0)
#define RDA(kh_, buf_) { _Pragma("unroll") for (int m = 0; m < 4; ++m) { \
    int R = wr * 64 + m * 16 + l15; \
    aR[m] = *(const bf16x8*)&As[buf_][kh_][R * 32 + ((kseg ^ FR_(R)) << 3)]; } }
#define RDB(kh_, buf_) { _Pragma("unroll") for (int n = 0; n < 6; ++n) { \
    int R = wc * 96 + n * 16 + l15; \
    bR[n] = *(const bf16x8*)&Bs[buf_][kh_][R * 32 + ((kseg ^ FR_(R)) << 3)]; } }
#define LGKM0 do { asm volatile("s_waitcnt lgkmcnt(0)" ::: "memory"); __builtin_amdgcn_sched_barrier(0); } while (0)
#define MMA() do { __builtin_amdgcn_s_setprio(1); \
    _Pragma("unroll") for (int m = 0; m < 4; ++m) \
    _Pragma("unroll") for (int n = 0; n < 6; ++n) \
        acc[m][n] = __builtin_amdgcn_mfma_f32_16x16x32_bf16(aR[m], bR[n], acc[m][n], 0, 0, 0); \
    __builtin_amdgcn_s_setprio(0); } while (0)
    // prologue: A(0) kh0+kh1 -> buf0; A(1) kh0 -> buf1; regs for A(1) kh1; B tile0 both kh
    U8 ca1, sa1;
    {
        U8 cc, ss;
        SB_(0, 0, 0); SB_(0, 0, 1);
        cc.v = *(const int4*)(gac);      ss.v = *(const int4*)(gsa);      WRA(0, 0, cc, ss);
        cc.v = *(const int4*)(gac + 32); ss.v = *(const int4*)(gsa + 32); WRA(0, 1, cc, ss);
        cc.v = *(const int4*)(gac + 64); ss.v = *(const int4*)(gsa + 64); WRA(1, 0, cc, ss);
        ca1.v = *(const int4*)(gac + 96); sa1.v = *(const int4*)(gsa + 96);
    }
    asm volatile("s_waitcnt vmcnt(0) lgkmcnt(0)" ::: "memory");
    __builtin_amdgcn_s_barrier();
    for (int kt = 0; kt < 32; ++kt) {
        int cur = kt & 1, nb = cur ^ 1;
        bf16x8 aR[4], bR[6];
        U8 ca0, sa0, nca1, nsa1;
        bool p1 = (kt + 1 < 32), p2 = (kt + 2 < 32);
        // ---- ph0: read cur kh0; stage B(nb,kt+1,both); write A(kt+1)kh1 (regs); load A(kt+2) regs ----
        RDA(0, cur); RDB(0, cur);
        if (p1) {
            SB_(nb, kt + 1, 0); SB_(nb, kt + 1, 1);
            WRA(nb, 1, ca1, sa1);
        }
        if (p2) {
            ca0.v = *(const int4*)(gac + (size_t)(kt + 2) * 64);
            sa0.v = *(const int4*)(gsa + (size_t)(kt + 2) * 64);
            nca1.v = *(const int4*)(gac + (size_t)(kt + 2) * 64 + 32);
            nsa1.v = *(const int4*)(gsa + (size_t)(kt + 2) * 64 + 32);
        }
        LGKM0;
        MMA();
        // ---- ph1: read cur kh1; write A(kt+2)kh0 into cur ----
        __builtin_amdgcn_s_barrier();
        __builtin_amdgcn_sched_barrier(0);
        RDA(1, cur); RDB(1, cur);
        if (p2) { WRA(cur, 0, ca0, sa0); ca1 = nca1; sa1 = nsa1; }
        LGKM0;
        MMA();
        __builtin_amdgcn_s_barrier();
        __builtin_amdgcn_sched_barrier(0);
    }
#undef SB_
#undef WRA
#undef RDA
#undef RDB
#undef LGKM0
#undef MMA
    unsigned short* hp = h2 + (size_t)bk * 768000;
#pragma unroll
    for (int fm = 0; fm < 4; ++fm) {
        int row0 = i0 + wr * 64 + fm * 16 + (kseg << 2);
#pragma unroll
        for (int fn = 0; fn < 6; ++fn) {
            int col = wc * 96 + fn * 16 + l15;
#pragma unroll
            for (int q = 0; q < 4; ++q) {
                int row = row0 + q;
                if (row < N_) hp[(size_t)row * 384 + col] = f2bf(acc[fm][fn][q]);
            }
        }
    }
}

// ---------------- fused tail: theta mix + time conv + residual + relu + LayerNorm ----------------
__global__ __launch_bounds__(512) void k_final3(const float* __restrict__ x, const unsigned short* __restrict__ h2,
                                                const float* __restrict__ ThetaG,
                                                const float* __restrict__ tcwT, const float* __restrict__ tc_b,
                                                const float* __restrict__ rcwT, const float* __restrict__ rc_b,
                                                const float* __restrict__ ln_g, const float* __restrict__ ln_b,
                                                float* __restrict__ out) {
    __shared__ __align__(16) char smem[110848];
    unsigned int* gl = (unsigned int*)smem;
    unsigned short* th = (unsigned short*)(smem + 98560);
    float* red_s = (float*)(smem + 98560);
    float* red_q = red_s + 64 * 13;

    int tid = threadIdx.x;
    int n_l = tid & 63, fg = tid >> 6;
    int b = blockIdx.y;
    int node = blockIdx.x * 64 + n_l;
    bool ok = node < N_;
    int nd = ok ? node : N_ - 1;

    for (int q = tid; q < 6144; q += 512) th[q] = f2bf(ThetaG[q]);
    __syncthreads();

    float acc[8][12];
#pragma unroll
    for (int ff = 0; ff < 8; ++ff)
#pragma unroll
        for (int t = 0; t < 12; ++t) acc[ff][t] = 0.f;
    const unsigned short* hb = h2 + (size_t)b * 3 * 768000 + (size_t)nd * 384;
#pragma unroll
    for (int kk = 0; kk < 3; ++kk) {
        const unsigned short* hp = hb + (size_t)kk * 768000;
#pragma unroll 2
        for (int c = 0; c < 32; ++c) {
            const unsigned short* hq = hp + c * 12;
            uint2 u0 = *(const uint2*)(hq);
            uint2 u1 = *(const uint2*)(hq + 4);
            uint2 u2 = *(const uint2*)(hq + 8);
            float h[12];
            h[0] = bf2f((unsigned short)u0.x);  h[1] = bf2f((unsigned short)(u0.x >> 16));
            h[2] = bf2f((unsigned short)u0.y);  h[3] = bf2f((unsigned short)(u0.y >> 16));
            h[4] = bf2f((unsigned short)u1.x);  h[5] = bf2f((unsigned short)(u1.x >> 16));
            h[6] = bf2f((unsigned short)u1.y);  h[7] = bf2f((unsigned short)(u1.y >> 16));
            h[8] = bf2f((unsigned short)u2.x);  h[9] = bf2f((unsigned short)(u2.x >> 16));
            h[10] = bf2f((unsigned short)u2.y); h[11] = bf2f((unsigned short)(u2.y >> 16));
            const unsigned short* wv = th + (kk * 32 + c) * 64 + fg * 8;
            uint2 w01 = *(const uint2*)wv;
            uint2 w23 = *(const uint2*)(wv + 4);
            float wf[8];
            wf[0] = bf2f((unsigned short)w01.x); wf[1] = bf2f((unsigned short)(w01.x >> 16));
            wf[2] = bf2f((unsigned short)w01.y); wf[3] = bf2f((unsigned short)(w01.y >> 16));
            wf[4] = bf2f((unsigned short)w23.x); wf[5] = bf2f((unsigned short)(w23.x >> 16));
            wf[6] = bf2f((unsigned short)w23.y); wf[7] = bf2f((unsigned short)(w23.y >> 16));
#pragma unroll
            for (int ff = 0; ff < 8; ++ff)
#pragma unroll
                for (int t = 0; t < 12; ++t) acc[ff][t] = fmaf(h[t], wf[ff], acc[ff][t]);
        }
    }
    unsigned int* gr = gl + n_l * 385 + fg * 48;
#pragma unroll
    for (int ff = 0; ff < 8; ++ff)
#pragma unroll
        for (int tp = 0; tp < 6; ++tp) {
            float a0 = fmaxf(acc[ff][2 * tp], 0.f), a1 = fmaxf(acc[ff][2 * tp + 1], 0.f);
            gr[ff * 6 + tp] = (unsigned int)f2bf(a0) | ((unsigned int)f2bf(a1) << 16);
        }
    __syncthreads();

    float z[8][12];
#pragma unroll
    for (int ff = 0; ff < 8; ++ff) {
        float bias = tc_b[fg * 8 + ff] + rc_b[fg * 8 + ff];
#pragma unroll
        for (int t = 0; t < 12; ++t) z[ff][t] = bias;
    }
    const float* xp = x + (size_t)(b * 2000 + nd) * 384;
#pragma unroll 2
    for (int c = 0; c < 32; ++c) {
        float4 x0 = *(const float4*)(xp + c * 12);
        float4 x1 = *(const float4*)(xp + c * 12 + 4);
        float4 x2 = *(const float4*)(xp + c * 12 + 8);
        float xv[12] = {x0.x, x0.y, x0.z, x0.w, x1.x, x1.y, x1.z, x1.w, x2.x, x2.y, x2.z, x2.w};
        float4 r0 = *(const float4*)(rcwT + c * 64 + fg * 8);
        float4 r1 = *(const float4*)(rcwT + c * 64 + fg * 8 + 4);
        float rw[8] = {r0.x, r0.y, r0.z, r0.w, r1.x, r1.y, r1.z, r1.w};
#pragma unroll
        for (int ff = 0; ff < 8; ++ff)
#pragma unroll
            for (int t = 0; t < 12; ++t) z[ff][t] = fmaf(xv[t], rw[ff], z[ff][t]);
    }
    const unsigned int* grow = gl + n_l * 385;
    for (int fi = 0; fi < 64; ++fi) {
        float g[12];
#pragma unroll
        for (int j = 0; j < 6; ++j) {
            unsigned int u = grow[fi * 6 + j];
            g[2 * j] = bf2f((unsigned short)u);
            g[2 * j + 1] = bf2f((unsigned short)(u >> 16));
        }
        const float* wp = tcwT + (fi * 64 + fg * 8) * 3;
        float4 w0 = *(const float4*)(wp);
        float4 w1 = *(const float4*)(wp + 4);
        float4 w2 = *(const float4*)(wp + 8);
        float4 w3 = *(const float4*)(wp + 12);
        float4 w4 = *(const float4*)(wp + 16);
        float4 w5 = *(const float4*)(wp + 20);
        float wb[24] = {w0.x, w0.y, w0.z, w0.w, w1.x, w1.y, w1.z, w1.w,
                        w2.x, w2.y, w2.z, w2.w, w3.x, w3.y, w3.z, w3.w,
                        w4.x, w4.y, w4.z, w4.w, w5.x, w5.y, w5.z, w5.w};
#pragma unroll
        for (int ff = 0; ff < 8; ++ff) {
            float a0 = wb[ff * 3], a1 = wb[ff * 3 + 1], a2 = wb[ff * 3 + 2];
            z[ff][0] = fmaf(g[0], a1, fmaf(g[1], a2, z[ff][0]));
#pragma unroll
            for (int t = 1; t < 11; ++t)
                z[ff][t] = fmaf(g[t - 1], a0, fmaf(g[t], a1, fmaf(g[t + 1], a2, z[ff][t])));
            z[ff][11] = fmaf(g[10], a0, fmaf(g[11], a1, z[ff][11]));
        }
    }
#pragma unroll
    for (int ff = 0; ff < 8; ++ff)
#pragma unroll
        for (int t = 0; t < 12; ++t) z[ff][t] = fmaxf(z[ff][t], 0.f);

    float s[12], q[12];
#pragma unroll
    for (int t = 0; t < 12; ++t) { s[t] = 0.f; q[t] = 0.f; }
#pragma unroll
    for (int ff = 0; ff < 8; ++ff)
#pragma unroll
        for (int t = 0; t < 12; ++t) { s[t] += z[ff][t]; q[t] += z[ff][t] * z[ff][t]; }
    __syncthreads();
    for (int g = 0; g < 8; ++g) {
        if (fg == g) {
            if (g == 0) {
#pragma unroll
                for (int t = 0; t < 12; ++t) { red_s[n_l * 13 + t] = s[t]; red_q[n_l * 13 + t] = q[t]; }
            } else {
#pragma unroll
                for (int t = 0; t < 12; ++t) { red_s[n_l * 13 + t] += s[t]; red_q[n_l * 13 + t] += q[t]; }
            }
        }
        __syncthreads();
    }
    float mu[12], rs[12];
#pragma unroll
    for (int t = 0; t < 12; ++t) {
        float m = red_s[n_l * 13 + t] * (1.0f / 64.0f);
        float v = red_q[n_l * 13 + t] * (1.0f / 64.0f) - m * m;
        mu[t] = m;
        rs[t] = rsqrtf(v + 1e-5f);
    }
    if (ok) {
        float* op = out + ((size_t)(b * 2000 + node) * 64 + fg * 8) * 12;
#pragma unroll
        for (int ff = 0; ff < 8; ++ff) {
            float lg = ln_g[fg * 8 + ff], lb = ln_b[fg * 8 + ff];
            float o[12];
#pragma unroll
            for (int t = 0; t < 12; ++t) o[t] = (z[ff][t] - mu[t]) * rs[t] * lg + lb;
#pragma unroll
            for (int tq = 0; tq < 3; ++tq)
                *(float4*)(op + ff * 12 + tq * 4) = make_float4(o[tq * 4], o[tq * 4 + 1], o[tq * 4 + 2], o[tq * 4 + 3]);
        }
    }
}

extern "C" void kernel_launch(void* const* d_in, const int* in_sizes, int n_in,
                              void* d_out, int out_size, void* d_ws, size_t ws_size,
                              hipStream_t stream) {
    const float* x     = (const float*)d_in[0];
    const float* cheb  = (const float*)d_in[1];
    const float* U1    = (const float*)d_in[2];
    const float* U2    = (const float*)d_in[3];
    const float* U3    = (const float*)d_in[4];
    const float* be    = (const float*)d_in[5];
    const float* Ve    = (const float*)d_in[6];
    const float* W1    = (const float*)d_in[7];
    const float* W2    = (const float*)d_in[8];
    const float* W3    = (const float*)d_in[9];
    const float* bs    = (const float*)d_in[10];
    const float* Vs    = (const float*)d_in[11];
    const float* Theta = (const float*)d_in[12];
    const float* tc_w  = (const float*)d_in[13];
    const float* tc_b  = (const float*)d_in[14];
    const float* rc_w  = (const float*)d_in[15];
    const float* rc_b  = (const float*)d_in[16];
    const float* ln_g  = (const float*)d_in[17];
    const float* ln_b  = (const float*)d_in[18];
    float* out = (float*)d_out;

    // ---- workspace layout (~184.3 MB, identical to rounds 8-13) ----
    float* ws    = (float*)d_ws;
    float* At    = ws;
    float* lhs1  = ws + 1152;
    float* lhsT  = ws + 4224;
    float* rhsT  = ws + 196224;
    float* lhs_s = ws + 388224;
    float* rhs_s = ws + 580224;
    float* gm    = ws + 772224;
    float* gs    = ws + 788608;
    float* tcwT  = ws + 804992;
    float* rcwT  = ws + 817280;
    float* plh   = ws + 819328;
    float* pP    = ws + 972928;
    unsigned short* Vsb   = (unsigned short*)(ws + 991360);
    unsigned short* chebT = (unsigned short*)(ws + 3088512);
    unsigned short* xT    = (unsigned short*)(ws + 9379968);
    unsigned short* sigT  = (unsigned short*)(ws + 12525696);  // dead after gemm_S
    unsigned short* h2    = sigT;                              // reuse after gemm_S
    unsigned short* STb   = (unsigned short*)(ws + 29302912);

    // prep
    k_wprep<<<56, 256, 0, stream>>>(tc_w, rc_w, tcwT, rcwT);
    k_vsb<<<2048, 256, 0, stream>>>(Vs, Vsb);
    k_chebT<<<dim3(32, 32, 3), 256, 0, stream>>>(cheb, chebT);
    k_xT<<<dim3(32, 6, 8), 256, 0, stream>>>(x, xT);
    // temporal attention
    k_tprep<<<dim3(50, 8), 256, 0, stream>>>(x, U1, U3, rhsT, plh);
    k_tred<<<8, 256, 0, stream>>>(plh, lhs1);
    k_lhsT<<<750, 256, 0, stream>>>(lhs1, U2, lhsT);
    k_tatt1<<<dim3(16, 8), 256, 0, stream>>>(lhsT, rhsT, pP);
    k_tatt2<<<8, 256, 0, stream>>>(pP, be, Ve, At);
    k_xsp<<<dim3(250, 8), 256, 0, stream>>>(x, At, W1, W2, W3, lhs_s, rhs_s);
    // spatial attention (S^T directly)
    k_sig<<<dim3(32, 32, 8), 256, 0, stream>>>(lhs_s, rhs_s, bs, sigT);
    k_gemm_S_mfma<<<dim3(8, 8, 8), 512, 0, stream>>>(Vsb, sigT, STb);
    k_smrow<<<dim3(512, 8), 256, 0, stream>>>(STb, gm, gs);
    // chebyshev gcn with fused softmax normalization (2-fat-phase pipeline)
    k_gemm_cheb_mfma<<<dim3(16, 24), 512, 0, stream>>>(chebT, STb, gm, gs, xT, h2);
    // fused theta + conv + LN tail
    k_final3<<<dim3(32, 8), 512, 0, stream>>>(x, h2, Theta, tcwT, tc_b, rcwT, rc_b, ln_g, ln_b, out);
}